// Round 16
// baseline (1534.076 us; speedup 1.0000x reference)
//
#include <hip/hip_runtime.h>
#include <hip/hip_bf16.h>
#include <cstddef>
#include <math.h>

#define kB 32
#define kN1 4096
#define kS1 512
#define kNS1 32
#define kS2 128
#define kNS2 64

// ---------------- fused weight folding for all 9 layers ----------------
struct FoldDesc {
  const float *W, *b, *g, *bt;
  float *Wout, *bout;
  int O, K, Kp, transposed;
};
struct FoldPack {
  FoldDesc d[9];
  int cum[10];
};

__global__ __launch_bounds__(256) void foldall_kernel(FoldPack p) {
  int blk = blockIdx.x;
  int L = 0;
#pragma unroll
  for (int i = 0; i < 9; ++i)
    if (blk >= p.cum[i + 1]) L = i + 1;
  FoldDesc d = p.d[L];
  int nb = p.cum[L + 1] - p.cum[L];
  int tid = (blk - p.cum[L]) * 256 + threadIdx.x;
  int stride = nb * 256;
  float inv = 1.0f / sqrtf(1.0f + 1e-5f);
  for (int i = tid; i < d.O * d.Kp; i += stride) {
    int o = i / d.Kp, k = i - o * d.Kp;
    float s = d.g[o] * inv;
    float w = (k < d.K) ? d.W[o * d.K + k] * s : 0.0f;
    if (d.transposed) d.Wout[k * d.O + o] = w;
    else d.Wout[o * d.Kp + k] = w;
  }
  for (int o = tid; o < d.O; o += stride) {
    d.bout[o] = d.b[o] * (d.g[o] * inv) + d.bt[o];
  }
}

// Canonical CDNA wave64 f32 max via DPP (VALU pipe only, no LDS/bpermute).
// Requires all inputs >= 0 (DPP 0-fill identity). Result broadcast via readlane.
// row_shr:N moves data toward HIGHER lanes -> accumulates at lane 63.
__device__ __forceinline__ float wave_max_f32_nonneg(float x) {
#define DPP_MAXSTEP(CTRL)                                                     \
  {                                                                           \
    int o = __builtin_amdgcn_update_dpp(0, __float_as_int(x), (CTRL), 0xf, 0xf, true); \
    x = fmaxf(x, __int_as_float(o));                                          \
  }
  DPP_MAXSTEP(0x111)  // row_shr:1
  DPP_MAXSTEP(0x112)  // row_shr:2
  DPP_MAXSTEP(0x114)  // row_shr:4
  DPP_MAXSTEP(0x118)  // row_shr:8
  DPP_MAXSTEP(0x142)  // row_bcast:15
  DPP_MAXSTEP(0x143)  // row_bcast:31
#undef DPP_MAXSTEP
  return __int_as_float(__builtin_amdgcn_readlane(__float_as_int(x), 63));
}

// Publish predicate: unique max lane, or (rare tie) lane holding the minimum
// owned index among tied lanes -> exact "first max" semantics.
__device__ __forceinline__ bool fps_pub_lane(float bestf, float wmax, int besti) {
  unsigned long long m = __ballot(bestf == wmax);
  if (__popcll(m) == 1) return bestf == wmax;
  unsigned long long mm = m;
  int bidx = 0x7fffffff;
  while (mm) {
    int l = __ffsll(mm) - 1;
    int bi = __shfl(besti, l, 64);
    bidx = min(bidx, bi);
    mm &= mm - 1;
  }
  return (bestf == wmax) && (besti == bidx);
}

// ---------------- farthest point sampling ----------------
// fps16 (R12 form -- best measured): coords in LDS as float4 GROUPS (thread
// owns points 4g..4g+3, dist phase = 12 ds_read_b128); dd state (16 floats,
// named float4s) register-resident. Winner slots hold ONLY the u64 key
// {dist_bits<<32 | ~idx}; centroid coords fetched by index via 3 broadcast
// ds_read_b32. DPP wave-max reduce. One barrier/iter.
#define FPS_E(V, C, XV, YV, ZV, I)                                           \
  {                                                                          \
    float dx = __fsub_rn((XV), cx);                                          \
    float dy = __fsub_rn((YV), cy);                                          \
    float dz = __fsub_rn((ZV), cz);                                          \
    float d = fmaf(dz, dz, fmaf(dy, dy, __fmul_rn(dx, dx)));                 \
    float nd = fminf(dd##V.C, d);                                            \
    dd##V.C = nd;                                                            \
    if (nd > bestf) { bestf = nd; besti = (I); }                             \
  }

#define FPS_GRP(V, R)                                                        \
  {                                                                          \
    float4 xg = sx4[t + (R) * T];                                            \
    float4 yg = sy4[t + (R) * T];                                            \
    float4 zg = sz4[t + (R) * T];                                            \
    int ibase = 4 * (t + (R) * T);                                           \
    FPS_E(V, x, xg.x, yg.x, zg.x, ibase)                                     \
    FPS_E(V, y, xg.y, yg.y, zg.y, ibase + 1)                                 \
    FPS_E(V, z, xg.z, yg.z, zg.z, ibase + 2)                                 \
    FPS_E(V, w, xg.w, yg.w, zg.w, ibase + 3)                                 \
  }

template <int N, int NP, int T>
__global__ __launch_bounds__(T, 1) void fps16_kernel(const float* __restrict__ xyz,
                                                     float* __restrict__ nx) {
  static_assert(N == 16 * T, "fps16: need exactly 16 points per thread");
  constexpr int W = T / 64;
  __shared__ float4 sx4[N / 4], sy4[N / 4], sz4[N / 4];
  __shared__ unsigned long long skey[2][W];
  __shared__ int fid[NP];
  int b = blockIdx.x, t = threadIdx.x;
  int w = t >> 6;
  const float* base = xyz + (size_t)b * 3 * N;
  float* sxf = (float*)sx4;
  float* syf = (float*)sy4;
  float* szf = (float*)sz4;
  for (int i = t; i < N; i += T) sxf[i] = base[i];
  for (int i = t; i < N; i += T) syf[i] = base[N + i];
  for (int i = t; i < N; i += T) szf[i] = base[2 * N + i];
  float4 dd0, dd1, dd2, dd3;
  dd0 = dd1 = dd2 = dd3 = make_float4(1e10f, 1e10f, 1e10f, 1e10f);
  if (t < W) skey[0][t] = (t == 0) ? ~0ull : 0ull;  // ~0ull decodes to idx 0
  if (t == 0) fid[0] = 0;
  int par = 0;
  __syncthreads();
  for (int it = 1; it < NP; ++it) {
    unsigned long long mk = skey[par][0];
#pragma unroll
    for (int w2 = 1; w2 < W; ++w2) {
      unsigned long long k2 = skey[par][w2];
      if (k2 > mk) mk = k2;
    }
    int wi = (int)(~(unsigned)mk);
    if (t == 0) fid[it - 1] = wi;
    float cx = sxf[wi], cy = syf[wi], cz = szf[wi];
    float bestf = -1.0f;
    int besti = 4 * t;
    FPS_GRP(0, 0)
    FPS_GRP(1, 1)
    FPS_GRP(2, 2)
    FPS_GRP(3, 3)
    float wmax = wave_max_f32_nonneg(bestf);
    if (fps_pub_lane(bestf, wmax, besti)) {
      skey[par ^ 1][w] =
          ((unsigned long long)__float_as_uint(wmax) << 32) | (unsigned)(~besti);
    }
    __syncthreads();
    par ^= 1;
  }
  {
    unsigned long long mk = skey[par][0];
#pragma unroll
    for (int w2 = 1; w2 < W; ++w2) {
      unsigned long long k2 = skey[par][w2];
      if (k2 > mk) mk = k2;
    }
    if (t == 0) fid[NP - 1] = (int)(~(unsigned)mk);
  }
  __syncthreads();
  for (int s = t; s < NP; s += T) {
    int f = fid[s];
    nx[(size_t)b * 3 * NP + s] = sxf[f];
    nx[(size_t)b * 3 * NP + NP + s] = syf[f];
    nx[(size_t)b * 3 * NP + 2 * NP + s] = szf[f];
  }
}

// fps4: R=4 register-resident variant (fps2: N=512, T=128). Proven VGPR=20 shape.
#define FPS_STEP(V, C, IDXOFF)                                               \
  {                                                                          \
    float dx = __fsub_rn(px##V.C, cx);                                       \
    float dy = __fsub_rn(py##V.C, cy);                                       \
    float dz = __fsub_rn(pz##V.C, cz);                                       \
    float d = fmaf(dz, dz, fmaf(dy, dy, __fmul_rn(dx, dx)));                 \
    float nd = fminf(dd##V.C, d);                                            \
    dd##V.C = nd;                                                            \
    if (nd > bestf) {                                                        \
      bestf = nd; besti = t + (IDXOFF); bx = px##V.C; by = py##V.C; bz = pz##V.C; \
    }                                                                        \
  }

#define FPS_LD4(arr, src, off) \
  arr = make_float4((src)[(off)], (src)[(off) + T], (src)[(off) + 2 * T], (src)[(off) + 3 * T])

template <int N, int NP, int T>
__global__ __launch_bounds__(T, 1) void fps4_kernel(const float* __restrict__ xyz,
                                                    float* __restrict__ nx) {
  static_assert(N == 4 * T, "fps4: need exactly 4 points per thread");
  constexpr int W = T / 64;
  __shared__ float4 sslot[2][W][2];
  __shared__ int fid[NP];
  int b = blockIdx.x, t = threadIdx.x;
  int w = t >> 6;
  const float* base = xyz + (size_t)b * 3 * N;
  float4 px0, py0, pz0, dd0;
  FPS_LD4(px0, base, t);
  FPS_LD4(py0, base + N, t);
  FPS_LD4(pz0, base + 2 * N, t);
  dd0 = make_float4(1e10f, 1e10f, 1e10f, 1e10f);
  if (t == 0) {
    fid[0] = 0;
    unsigned long long k0 = ~0ull;
    sslot[0][0][0] = make_float4(__uint_as_float((unsigned)k0),
                                 __uint_as_float((unsigned)(k0 >> 32)), px0.x, py0.x);
    sslot[0][0][1] = make_float4(pz0.x, 0.0f, 0.0f, 0.0f);
  }
  if (t >= 64 && (t & 63) == 0) {
    sslot[0][w][0] = make_float4(0.0f, 0.0f, 0.0f, 0.0f);
    sslot[0][w][1] = make_float4(0.0f, 0.0f, 0.0f, 0.0f);
  }
  int par = 0;
  __syncthreads();
  for (int it = 1; it < NP; ++it) {
    float4 q0 = sslot[par][0][0];
    float4 q1 = sslot[par][0][1];
    unsigned long long mk =
        ((unsigned long long)__float_as_uint(q0.y) << 32) | __float_as_uint(q0.x);
    float cx = q0.z, cy = q0.w, cz = q1.x;
#pragma unroll
    for (int w2 = 1; w2 < W; ++w2) {
      float4 p0 = sslot[par][w2][0];
      float4 p1 = sslot[par][w2][1];
      unsigned long long k2 =
          ((unsigned long long)__float_as_uint(p0.y) << 32) | __float_as_uint(p0.x);
      if (k2 > mk) { mk = k2; cx = p0.z; cy = p0.w; cz = p1.x; }
    }
    if (t == 0) fid[it - 1] = (int)(~(unsigned)mk);
    float bestf = -1.0f;
    int besti = t;
    float bx = px0.x, by = py0.x, bz = pz0.x;
    FPS_STEP(0, x, 0) FPS_STEP(0, y, T) FPS_STEP(0, z, 2 * T) FPS_STEP(0, w, 3 * T)
    float wmax = wave_max_f32_nonneg(bestf);
    if (fps_pub_lane(bestf, wmax, besti)) {
      unsigned long long key =
          ((unsigned long long)__float_as_uint(wmax) << 32) | (unsigned)(~besti);
      sslot[par ^ 1][w][0] = make_float4(__uint_as_float((unsigned)key),
                                         __uint_as_float((unsigned)(key >> 32)), bx, by);
      sslot[par ^ 1][w][1] = make_float4(bz, 0.0f, 0.0f, 0.0f);
    }
    __syncthreads();
    par ^= 1;
  }
  {
    float4 q0 = sslot[par][0][0];
    unsigned long long mk =
        ((unsigned long long)__float_as_uint(q0.y) << 32) | __float_as_uint(q0.x);
#pragma unroll
    for (int w2 = 1; w2 < W; ++w2) {
      float4 p0 = sslot[par][w2][0];
      unsigned long long k2 =
          ((unsigned long long)__float_as_uint(p0.y) << 32) | __float_as_uint(p0.x);
      if (k2 > mk) mk = k2;
    }
    if (t == 0) fid[NP - 1] = (int)(~(unsigned)mk);
  }
  __syncthreads();
  for (int s = t; s < NP; s += T) {
    int f = fid[s];
    nx[(size_t)b * 3 * NP + s] = base[f];
    nx[(size_t)b * 3 * NP + NP + s] = base[N + f];
    nx[(size_t)b * 3 * NP + 2 * NP + s] = base[2 * N + f];
  }
}

// ---------------- ball query ----------------
template <int NPTS, int NQ, int NS>
__global__ void bq_kernel(const float* __restrict__ pts, const float* __restrict__ qry,
                          float r2, int* __restrict__ gidx) {
  int gw = (blockIdx.x * blockDim.x + threadIdx.x) >> 6;
  int lane = threadIdx.x & 63;
  if (gw >= kB * NQ) return;
  int b = gw / NQ, s = gw - b * NQ;
  const float* pb = pts + (size_t)b * 3 * NPTS;
  float cx = qry[(size_t)b * 3 * NQ + s];
  float cy = qry[(size_t)b * 3 * NQ + NQ + s];
  float cz = qry[(size_t)b * 3 * NQ + 2 * NQ + s];
  float ss = fmaf(cz, cz, fmaf(cy, cy, __fmul_rn(cx, cx)));
  int* out = gidx + (size_t)gw * NS;
  int have = 0, first = 0;
  bool gotfirst = false;
  for (int n0 = 0; n0 < NPTS; n0 += 64) {
    int n = n0 + lane;
    float x = pb[n], y = pb[NPTS + n], z = pb[2 * NPTS + n];
    float dd = fmaf(z, z, fmaf(y, y, __fmul_rn(x, x)));
    float cross = fmaf(cz, z, fmaf(cy, y, __fmul_rn(cx, x)));
    float sqr = __fsub_rn(__fadd_rn(ss, dd), __fmul_rn(2.0f, cross));
    bool pred = !(sqr > r2);
    unsigned long long mask = __ballot(pred);
    if (!gotfirst && mask) { first = n0 + (__ffsll(mask) - 1); gotfirst = true; }
    if (pred) {
      int pos = have + __popcll(mask & ((1ull << lane) - 1ull));
      if (pos < NS) out[pos] = n;
    }
    have += __popcll(mask);
    if (have >= NS) break;
  }
  for (int slot = have + lane; slot < NS; slot += 64) out[slot] = first;
}

// ---------------- SA1 grouped MLP (3->64->64->128) + max over 32 samples ----------------
__global__ __launch_bounds__(256, 2) void sa1_mlp_kernel(
    const float* __restrict__ xyz, const float* __restrict__ nx1,
    const int* __restrict__ gidx,
    const float* __restrict__ W0f, const float* __restrict__ bf0,   // [64][4], [64]
    const float* __restrict__ WT1, const float* __restrict__ bf1,   // [64][64]
    const float* __restrict__ WT2, const float* __restrict__ bf2,   // [64][128]
    float* __restrict__ l1_pts) {
  __shared__ float XT[64 * 256];   // reused for X1 then X2
  int t = threadIdx.x;
  int qi = t >> 5, sm = t & 31;
  int q = blockIdx.x * 8 + qi;
  int b = q >> 9, s = q & 511;
  int idx = gidx[(size_t)q * kNS1 + sm];
  float cx = nx1[b * 1536 + s];
  float cy = nx1[b * 1536 + 512 + s];
  float cz = nx1[b * 1536 + 1024 + s];
  const float* pb = xyz + (size_t)b * 3 * kN1;
  float f0 = pb[idx] - cx, f1 = pb[kN1 + idx] - cy, f2 = pb[2 * kN1 + idx] - cz;
  for (int j = 0; j < 64; ++j) {
    float4 w = *(const float4*)&W0f[j * 4];
    float v = fmaf(f2, w.z, fmaf(f1, w.y, fmaf(f0, w.x, bf0[j])));
    XT[j * 256 + t] = fmaxf(v, 0.0f);
  }
  __syncthreads();
  float acc[64];
#pragma unroll
  for (int j = 0; j < 64; ++j) acc[j] = bf1[j];
  for (int k = 0; k < 64; ++k) {
    float xk = XT[k * 256 + t];
    const float* wr = WT1 + k * 64;
#pragma unroll
    for (int j = 0; j < 64; ++j) acc[j] = fmaf(xk, wr[j], acc[j]);
  }
  __syncthreads();
#pragma unroll
  for (int j = 0; j < 64; ++j) XT[j * 256 + t] = fmaxf(acc[j], 0.0f);
  __syncthreads();
  float* outp = l1_pts + (size_t)q * 128;
  for (int jp = 0; jp < 2; ++jp) {
#pragma unroll
    for (int j = 0; j < 64; ++j) acc[j] = bf2[jp * 64 + j];
    for (int k = 0; k < 64; ++k) {
      float xk = XT[k * 256 + t];
      const float* wr = WT2 + k * 128 + jp * 64;
#pragma unroll
      for (int j = 0; j < 64; ++j) acc[j] = fmaf(xk, wr[j], acc[j]);
    }
#pragma unroll
    for (int j = 0; j < 64; ++j) {
      float m = fmaxf(acc[j], 0.0f);
      m = fmaxf(m, __shfl_xor(m, 1, 64));
      m = fmaxf(m, __shfl_xor(m, 2, 64));
      m = fmaxf(m, __shfl_xor(m, 4, 64));
      m = fmaxf(m, __shfl_xor(m, 8, 64));
      m = fmaxf(m, __shfl_xor(m, 16, 64));
      if (sm == 0) outp[jp * 64 + j] = m;
    }
  }
}

// ---------------- SA2 grouped MLP (131->128->128->256) + max over 64 samples ----------------
// TRANSPOSED feature LDS fbT[c][lane] (128x64 f32 = 32768 B exactly -> 5 blocks/CU,
// 20 waves/CU). Reads at fixed c are lane-consecutive -> conflict-free, no swizzle.
// The 3 coord features live in registers (W-rows 0..2 applied first -> identical
// ascending-k accumulation order). Zero pad row 131 dropped (fmaf(0,w,acc)==acc).
__global__ __launch_bounds__(256, 5) void sa2_mlp_kernel(
    const float* __restrict__ nx1, const float* __restrict__ l1_pts,
    const float* __restrict__ nx2, const int* __restrict__ gidx2,
    const float* __restrict__ WT1, const float* __restrict__ bf1,   // [132][128]
    const float* __restrict__ WT2, const float* __restrict__ bf2,   // [128][128]
    const float* __restrict__ WT3, const float* __restrict__ bf3,   // [128][256]
    float* __restrict__ l2_pts) {
  __shared__ float fbT[128 * 64];
  int t = threadIdx.x;
  int lane = t & 63;
  int wg = __builtin_amdgcn_readfirstlane(t >> 6);
  int q = blockIdx.x;
  int b = q >> 7, s = q & 127;
  int idx = gidx2[(size_t)q * kNS2 + lane];
  const float* pr = l1_pts + ((size_t)(b * kS1) + idx) * 128;
  // gather: each (lane,wg) loads 32 of the 128 l1 features, scatters transposed
#pragma unroll
  for (int i = 0; i < 8; ++i) {
    float4 v = *(const float4*)&pr[wg * 32 + i * 4];
    int c = wg * 32 + i * 4;
    fbT[(c + 0) * 64 + lane] = v.x;
    fbT[(c + 1) * 64 + lane] = v.y;
    fbT[(c + 2) * 64 + lane] = v.z;
    fbT[(c + 3) * 64 + lane] = v.w;
  }
  // per-lane coord features in registers (every wave computes its own copy)
  float cx = nx2[b * 384 + s];
  float cy = nx2[b * 384 + 128 + s];
  float cz = nx2[b * 384 + 256 + s];
  float f0 = nx1[b * 1536 + idx] - cx;
  float f1 = nx1[b * 1536 + 512 + idx] - cy;
  float f2 = nx1[b * 1536 + 1024 + idx] - cz;
  __syncthreads();
  float acc[32];
  // layer1: bias, then W-rows 0..2 (coords), then feature rows 3..130 ascending
#pragma unroll
  for (int j = 0; j < 32; ++j) acc[j] = bf1[wg * 32 + j];
  {
    const float* w0 = WT1 + 0 * 128 + wg * 32;
    const float* w1 = WT1 + 1 * 128 + wg * 32;
    const float* w2 = WT1 + 2 * 128 + wg * 32;
#pragma unroll
    for (int j = 0; j < 32; ++j) acc[j] = fmaf(f0, w0[j], acc[j]);
#pragma unroll
    for (int j = 0; j < 32; ++j) acc[j] = fmaf(f1, w1[j], acc[j]);
#pragma unroll
    for (int j = 0; j < 32; ++j) acc[j] = fmaf(f2, w2[j], acc[j]);
  }
  for (int c = 0; c < 128; c += 2) {
    float x0 = fbT[c * 64 + lane];
    float x1 = fbT[(c + 1) * 64 + lane];
    const float* w0 = WT1 + (c + 3) * 128 + wg * 32;
    const float* w1 = WT1 + (c + 4) * 128 + wg * 32;
#pragma unroll
    for (int j = 0; j < 32; ++j) acc[j] = fmaf(x0, w0[j], acc[j]);
#pragma unroll
    for (int j = 0; j < 32; ++j) acc[j] = fmaf(x1, w1[j], acc[j]);
  }
  __syncthreads();   // all feature reads complete
#pragma unroll
  for (int j = 0; j < 32; ++j) fbT[(wg * 32 + j) * 64 + lane] = fmaxf(acc[j], 0.0f);
  __syncthreads();
  // layer2
#pragma unroll
  for (int j = 0; j < 32; ++j) acc[j] = bf2[wg * 32 + j];
  for (int c = 0; c < 128; c += 2) {
    float x0 = fbT[c * 64 + lane];
    float x1 = fbT[(c + 1) * 64 + lane];
    const float* w0 = WT2 + c * 128 + wg * 32;
    const float* w1 = WT2 + (c + 1) * 128 + wg * 32;
#pragma unroll
    for (int j = 0; j < 32; ++j) acc[j] = fmaf(x0, w0[j], acc[j]);
#pragma unroll
    for (int j = 0; j < 32; ++j) acc[j] = fmaf(x1, w1[j], acc[j]);
  }
  __syncthreads();
#pragma unroll
  for (int j = 0; j < 32; ++j) fbT[(wg * 32 + j) * 64 + lane] = fmaxf(acc[j], 0.0f);
  __syncthreads();
  // layer3: outs j = wg*64 .. +63, two passes of 32; max over 64 samples
  float* outp = l2_pts + (size_t)q * 256;
  for (int jp = 0; jp < 2; ++jp) {
    int j0 = wg * 64 + jp * 32;
#pragma unroll
    for (int j = 0; j < 32; ++j) acc[j] = bf3[j0 + j];
    for (int c = 0; c < 128; c += 2) {
      float x0 = fbT[c * 64 + lane];
      float x1 = fbT[(c + 1) * 64 + lane];
      const float* w0 = WT3 + c * 256 + j0;
      const float* w1 = WT3 + (c + 1) * 256 + j0;
#pragma unroll
      for (int j = 0; j < 32; ++j) acc[j] = fmaf(x0, w0[j], acc[j]);
#pragma unroll
      for (int j = 0; j < 32; ++j) acc[j] = fmaf(x1, w1[j], acc[j]);
    }
#pragma unroll
    for (int j = 0; j < 32; ++j) {
      float m = fmaxf(acc[j], 0.0f);
      m = fmaxf(m, __shfl_xor(m, 1, 64));
      m = fmaxf(m, __shfl_xor(m, 2, 64));
      m = fmaxf(m, __shfl_xor(m, 4, 64));
      m = fmaxf(m, __shfl_xor(m, 8, 64));
      m = fmaxf(m, __shfl_xor(m, 16, 64));
      m = fmaxf(m, __shfl_xor(m, 32, 64));
      if (lane == 0) outp[j0 + j] = m;
    }
  }
}

// ---------------- SA3 (group-all): 259->256->512->1024 -> max over 128 ----------------
__global__ __launch_bounds__(256, 2) void sa3_passA_kernel(
    const float* __restrict__ nx2, const float* __restrict__ l2_pts,
    const float* __restrict__ WT, const float* __restrict__ bf,
    float* __restrict__ Y) {   // O = 256
  __shared__ float sF[16 * 260];
  int stile = blockIdx.x, t = threadIdx.x;
  int j = t;
  for (int i = t; i < 16 * 260; i += 256) {
    int row = stile * 16 + i / 260, k = i - (i / 260) * 260;
    int b = row >> 7, s = row & 127;
    float v;
    if (k < 3) v = nx2[b * 384 + k * 128 + s];
    else if (k < 259) v = l2_pts[(size_t)row * 256 + (k - 3)];
    else v = 0.0f;
    sF[i] = v;
  }
  __syncthreads();
  float acc[16];
  float bj = bf[j];
#pragma unroll
  for (int s = 0; s < 16; ++s) acc[s] = bj;
  for (int k = 0; k < 260; k += 4) {
    float w0 = WT[(size_t)k * 256 + j];
    float w1 = WT[(size_t)(k + 1) * 256 + j];
    float w2 = WT[(size_t)(k + 2) * 256 + j];
    float w3 = WT[(size_t)(k + 3) * 256 + j];
#pragma unroll
    for (int s = 0; s < 16; ++s) {
      const float4 fv = *(const float4*)&sF[s * 260 + k];
      acc[s] = fmaf(fv.x, w0, acc[s]);
      acc[s] = fmaf(fv.y, w1, acc[s]);
      acc[s] = fmaf(fv.z, w2, acc[s]);
      acc[s] = fmaf(fv.w, w3, acc[s]);
    }
  }
  float* yb = Y + (size_t)stile * 16 * 256 + j;
#pragma unroll
  for (int s = 0; s < 16; ++s) yb[(size_t)s * 256] = fmaxf(acc[s], 0.0f);
}

template <int KP>
__global__ __launch_bounds__(256, 2) void mlp_pass_kernel(
    const float* __restrict__ X, const float* __restrict__ WT, const float* __restrict__ bf,
    int O, float* __restrict__ Y) {
  __shared__ float sF[16 * KP];
  int stile = blockIdx.x, t = threadIdx.x;
  int j = blockIdx.y * 256 + t;
  const float* xb = X + (size_t)stile * 16 * KP;
  for (int i = t; i < 16 * KP; i += 256) sF[i] = xb[i];
  __syncthreads();
  float acc[16];
  float bj = bf[j];
#pragma unroll
  for (int s = 0; s < 16; ++s) acc[s] = bj;
  for (int k = 0; k < KP; k += 4) {
    float w0 = WT[(size_t)k * O + j];
    float w1 = WT[(size_t)(k + 1) * O + j];
    float w2 = WT[(size_t)(k + 2) * O + j];
    float w3 = WT[(size_t)(k + 3) * O + j];
#pragma unroll
    for (int s = 0; s < 16; ++s) {
      const float4 fv = *(const float4*)&sF[s * KP + k];
      acc[s] = fmaf(fv.x, w0, acc[s]);
      acc[s] = fmaf(fv.y, w1, acc[s]);
      acc[s] = fmaf(fv.z, w2, acc[s]);
      acc[s] = fmaf(fv.w, w3, acc[s]);
    }
  }
  float* yb = Y + (size_t)stile * 16 * O + j;
#pragma unroll
  for (int s = 0; s < 16; ++s) yb[(size_t)s * O] = fmaxf(acc[s], 0.0f);
}

__global__ __launch_bounds__(256, 2) void sa3_final_kernel(
    const float* __restrict__ X2g, const float* __restrict__ WTc, const float* __restrict__ bfc,
    float* __restrict__ out) {
  __shared__ float sF[16 * 512];
  int b = blockIdx.x, t = threadIdx.x;
  int j = blockIdx.y * 256 + t;
  float m = 0.0f;
  float bj = bfc[j];
  for (int st = 0; st < 8; ++st) {
    const float* xb = X2g + ((size_t)b * 128 + st * 16) * 512;
    for (int i = t; i < 16 * 512; i += 256) sF[i] = xb[i];
    __syncthreads();
    float acc[16];
#pragma unroll
    for (int s = 0; s < 16; ++s) acc[s] = bj;
    for (int k = 0; k < 512; k += 4) {
      float w0 = WTc[(size_t)k * 1024 + j];
      float w1 = WTc[(size_t)(k + 1) * 1024 + j];
      float w2 = WTc[(size_t)(k + 2) * 1024 + j];
      float w3 = WTc[(size_t)(k + 3) * 1024 + j];
#pragma unroll
      for (int s = 0; s < 16; ++s) {
        const float4 fv = *(const float4*)&sF[s * 512 + k];
        acc[s] = fmaf(fv.x, w0, acc[s]);
        acc[s] = fmaf(fv.y, w1, acc[s]);
        acc[s] = fmaf(fv.z, w2, acc[s]);
        acc[s] = fmaf(fv.w, w3, acc[s]);
      }
    }
#pragma unroll
    for (int s = 0; s < 16; ++s) m = fmaxf(m, fmaxf(acc[s], 0.0f));
    __syncthreads();
  }
  out[(size_t)b * 1024 + j] = m;
}

// ---------------- launch ----------------
extern "C" void kernel_launch(void* const* d_in, const int* in_sizes, int n_in,
                              void* d_out, int out_size, void* d_ws, size_t ws_size,
                              hipStream_t stream) {
  (void)in_sizes; (void)n_in; (void)out_size; (void)ws_size;
  const float* xyz = (const float*)d_in[0];
  auto WP = [&](int layer, int part) -> const float* {
    return (const float*)d_in[1 + layer * 4 + part];
  };
  float* wsf = (float*)d_ws;
  size_t cur = 0;
  auto alloc = [&](size_t n) { size_t o = cur; cur += (n + 63) & ~(size_t)63; return o; };
  size_t o_nx1 = alloc((size_t)kB * 3 * kS1);
  size_t o_nx2 = alloc((size_t)kB * 3 * kS2);
  size_t o_l1pts = alloc((size_t)kB * kS1 * 128);
  size_t o_l2pts = alloc((size_t)kB * kS2 * 256);
  size_t o_X1g = alloc((size_t)kB * kS2 * 256);
  size_t o_X2g = alloc((size_t)kB * kS2 * 512);
  size_t o_s1w0 = alloc(64 * 4), o_s1b0 = alloc(64);
  size_t o_s1w1 = alloc(64 * 64), o_s1b1 = alloc(64);
  size_t o_s1wt2 = alloc(64 * 128), o_s1b2 = alloc(128);
  size_t o_s2w1 = alloc(132 * 128), o_s2b1 = alloc(128);
  size_t o_s2wt2 = alloc(128 * 128), o_s2b2 = alloc(128);
  size_t o_s2w3 = alloc(128 * 256), o_s2b3 = alloc(256);
  size_t o_s3wtA = alloc(260 * 256), o_s3bA = alloc(256);
  size_t o_s3wtB = alloc(256 * 512), o_s3bB = alloc(512);
  size_t o_s3wtC = alloc(512 * 1024), o_s3bC = alloc(1024);
  size_t o_gidx1 = alloc((size_t)kB * kS1 * kNS1);
  size_t o_gidx2 = alloc((size_t)kB * kS2 * kNS2);
  int* gidx1 = (int*)(wsf + o_gidx1);
  int* gidx2 = (int*)(wsf + o_gidx2);

  // fused fold of all 9 layers
  FoldPack fp;
  const int OKKp[9][3] = {{64, 3, 4},     {64, 64, 64},   {128, 64, 64},
                          {128, 131, 132}, {128, 128, 128}, {256, 128, 128},
                          {256, 259, 260}, {512, 256, 256}, {1024, 512, 512}};
  float* wouts[9] = {wsf + o_s1w0, wsf + o_s1w1, wsf + o_s1wt2,
                     wsf + o_s2w1, wsf + o_s2wt2, wsf + o_s2w3,
                     wsf + o_s3wtA, wsf + o_s3wtB, wsf + o_s3wtC};
  float* bouts[9] = {wsf + o_s1b0, wsf + o_s1b1, wsf + o_s1b2,
                     wsf + o_s2b1, wsf + o_s2b2, wsf + o_s2b3,
                     wsf + o_s3bA, wsf + o_s3bB, wsf + o_s3bC};
  const int nblk[9] = {1, 4, 8, 17, 16, 32, 65, 128, 512};
  fp.cum[0] = 0;
  for (int L = 0; L < 9; ++L) {
    fp.d[L].W = WP(L, 0);
    fp.d[L].b = WP(L, 1);
    fp.d[L].g = WP(L, 2);
    fp.d[L].bt = WP(L, 3);
    fp.d[L].Wout = wouts[L];
    fp.d[L].bout = bouts[L];
    fp.d[L].O = OKKp[L][0];
    fp.d[L].K = OKKp[L][1];
    fp.d[L].Kp = OKKp[L][2];
    fp.d[L].transposed = (L == 0) ? 0 : 1;
    fp.cum[L + 1] = fp.cum[L] + nblk[L];
  }
  foldall_kernel<<<fp.cum[9], 256, 0, stream>>>(fp);

  // SA1
  fps16_kernel<kN1, kS1, 256><<<kB, 256, 0, stream>>>(xyz, wsf + o_nx1);
  bq_kernel<kN1, kS1, kNS1><<<(kB * kS1) / 4, 256, 0, stream>>>(xyz, wsf + o_nx1, 0.04f, gidx1);
  sa1_mlp_kernel<<<(kB * kS1) / 8, 256, 0, stream>>>(
      xyz, wsf + o_nx1, gidx1,
      wsf + o_s1w0, wsf + o_s1b0, wsf + o_s1w1, wsf + o_s1b1, wsf + o_s1wt2, wsf + o_s1b2,
      wsf + o_l1pts);

  // SA2
  fps4_kernel<kS1, kS2, 128><<<kB, 128, 0, stream>>>(wsf + o_nx1, wsf + o_nx2);
  bq_kernel<kS1, kS2, kNS2><<<(kB * kS2) / 4, 256, 0, stream>>>(wsf + o_nx1, wsf + o_nx2, 0.16f, gidx2);
  sa2_mlp_kernel<<<kB * kS2, 256, 0, stream>>>(
      wsf + o_nx1, wsf + o_l1pts, wsf + o_nx2, gidx2,
      wsf + o_s2w1, wsf + o_s2b1, wsf + o_s2wt2, wsf + o_s2b2, wsf + o_s2w3, wsf + o_s2b3,
      wsf + o_l2pts);

  // SA3 (group all)
  sa3_passA_kernel<<<256, 256, 0, stream>>>(wsf + o_nx2, wsf + o_l2pts,
                                            wsf + o_s3wtA, wsf + o_s3bA, wsf + o_X1g);
  mlp_pass_kernel<256><<<dim3(256, 2), 256, 0, stream>>>(wsf + o_X1g, wsf + o_s3wtB, wsf + o_s3bB, 512, wsf + o_X2g);
  sa3_final_kernel<<<dim3(kB, 4), 256, 0, stream>>>(wsf + o_X2g, wsf + o_s3wtC, wsf + o_s3bC, (float*)d_out);
}

// Round 17
// 1506.527 us; speedup vs baseline: 1.0183x; 1.0183x over previous
//
#include <hip/hip_runtime.h>
#include <hip/hip_bf16.h>
#include <cstddef>
#include <math.h>

#define kB 32
#define kN1 4096
#define kS1 512
#define kNS1 32
#define kS2 128
#define kNS2 64

// ---------------- fused weight folding for all 9 layers ----------------
struct FoldDesc {
  const float *W, *b, *g, *bt;
  float *Wout, *bout;
  int O, K, Kp, transposed;
};
struct FoldPack {
  FoldDesc d[9];
  int cum[10];
};

__global__ __launch_bounds__(256) void foldall_kernel(FoldPack p) {
  int blk = blockIdx.x;
  int L = 0;
#pragma unroll
  for (int i = 0; i < 9; ++i)
    if (blk >= p.cum[i + 1]) L = i + 1;
  FoldDesc d = p.d[L];
  int nb = p.cum[L + 1] - p.cum[L];
  int tid = (blk - p.cum[L]) * 256 + threadIdx.x;
  int stride = nb * 256;
  float inv = 1.0f / sqrtf(1.0f + 1e-5f);
  for (int i = tid; i < d.O * d.Kp; i += stride) {
    int o = i / d.Kp, k = i - o * d.Kp;
    float s = d.g[o] * inv;
    float w = (k < d.K) ? d.W[o * d.K + k] * s : 0.0f;
    if (d.transposed) d.Wout[k * d.O + o] = w;
    else d.Wout[o * d.Kp + k] = w;
  }
  for (int o = tid; o < d.O; o += stride) {
    d.bout[o] = d.b[o] * (d.g[o] * inv) + d.bt[o];
  }
}

// Canonical CDNA wave64 f32 max via DPP (VALU pipe only, no LDS/bpermute).
// Requires all inputs >= 0 (DPP 0-fill identity). Result broadcast via readlane.
// row_shr:N moves data toward HIGHER lanes -> accumulates at lane 63.
__device__ __forceinline__ float wave_max_f32_nonneg(float x) {
#define DPP_MAXSTEP(CTRL)                                                     \
  {                                                                           \
    int o = __builtin_amdgcn_update_dpp(0, __float_as_int(x), (CTRL), 0xf, 0xf, true); \
    x = fmaxf(x, __int_as_float(o));                                          \
  }
  DPP_MAXSTEP(0x111)  // row_shr:1
  DPP_MAXSTEP(0x112)  // row_shr:2
  DPP_MAXSTEP(0x114)  // row_shr:4
  DPP_MAXSTEP(0x118)  // row_shr:8
  DPP_MAXSTEP(0x142)  // row_bcast:15
  DPP_MAXSTEP(0x143)  // row_bcast:31
#undef DPP_MAXSTEP
  return __int_as_float(__builtin_amdgcn_readlane(__float_as_int(x), 63));
}

// Publish predicate: unique max lane, or (rare tie) lane holding the minimum
// owned index among tied lanes -> exact "first max" semantics.
__device__ __forceinline__ bool fps_pub_lane(float bestf, float wmax, int besti) {
  unsigned long long m = __ballot(bestf == wmax);
  if (__popcll(m) == 1) return bestf == wmax;
  unsigned long long mm = m;
  int bidx = 0x7fffffff;
  while (mm) {
    int l = __ffsll(mm) - 1;
    int bi = __shfl(besti, l, 64);
    bidx = min(bidx, bi);
    mm &= mm - 1;
  }
  return (bestf == wmax) && (besti == bidx);
}

// ---------------- farthest point sampling ----------------
// fps16 (R12 form -- best measured): coords in LDS as float4 GROUPS (thread
// owns points 4g..4g+3, dist phase = 12 ds_read_b128); dd state (16 floats,
// named float4s) register-resident. Winner slots hold ONLY the u64 key
// {dist_bits<<32 | ~idx}; centroid coords fetched by index via 3 broadcast
// ds_read_b32. DPP wave-max reduce. One barrier/iter.
#define FPS_E(V, C, XV, YV, ZV, I)                                           \
  {                                                                          \
    float dx = __fsub_rn((XV), cx);                                          \
    float dy = __fsub_rn((YV), cy);                                          \
    float dz = __fsub_rn((ZV), cz);                                          \
    float d = fmaf(dz, dz, fmaf(dy, dy, __fmul_rn(dx, dx)));                 \
    float nd = fminf(dd##V.C, d);                                            \
    dd##V.C = nd;                                                            \
    if (nd > bestf) { bestf = nd; besti = (I); }                             \
  }

#define FPS_GRP(V, R)                                                        \
  {                                                                          \
    float4 xg = sx4[t + (R) * T];                                            \
    float4 yg = sy4[t + (R) * T];                                            \
    float4 zg = sz4[t + (R) * T];                                            \
    int ibase = 4 * (t + (R) * T);                                           \
    FPS_E(V, x, xg.x, yg.x, zg.x, ibase)                                     \
    FPS_E(V, y, xg.y, yg.y, zg.y, ibase + 1)                                 \
    FPS_E(V, z, xg.z, yg.z, zg.z, ibase + 2)                                 \
    FPS_E(V, w, xg.w, yg.w, zg.w, ibase + 3)                                 \
  }

template <int N, int NP, int T>
__global__ __launch_bounds__(T, 1) void fps16_kernel(const float* __restrict__ xyz,
                                                     float* __restrict__ nx) {
  static_assert(N == 16 * T, "fps16: need exactly 16 points per thread");
  constexpr int W = T / 64;
  __shared__ float4 sx4[N / 4], sy4[N / 4], sz4[N / 4];
  __shared__ unsigned long long skey[2][W];
  __shared__ int fid[NP];
  int b = blockIdx.x, t = threadIdx.x;
  int w = t >> 6;
  const float* base = xyz + (size_t)b * 3 * N;
  float* sxf = (float*)sx4;
  float* syf = (float*)sy4;
  float* szf = (float*)sz4;
  for (int i = t; i < N; i += T) sxf[i] = base[i];
  for (int i = t; i < N; i += T) syf[i] = base[N + i];
  for (int i = t; i < N; i += T) szf[i] = base[2 * N + i];
  float4 dd0, dd1, dd2, dd3;
  dd0 = dd1 = dd2 = dd3 = make_float4(1e10f, 1e10f, 1e10f, 1e10f);
  if (t < W) skey[0][t] = (t == 0) ? ~0ull : 0ull;  // ~0ull decodes to idx 0
  if (t == 0) fid[0] = 0;
  int par = 0;
  __syncthreads();
  for (int it = 1; it < NP; ++it) {
    unsigned long long mk = skey[par][0];
#pragma unroll
    for (int w2 = 1; w2 < W; ++w2) {
      unsigned long long k2 = skey[par][w2];
      if (k2 > mk) mk = k2;
    }
    int wi = (int)(~(unsigned)mk);
    if (t == 0) fid[it - 1] = wi;
    float cx = sxf[wi], cy = syf[wi], cz = szf[wi];
    float bestf = -1.0f;
    int besti = 4 * t;
    FPS_GRP(0, 0)
    FPS_GRP(1, 1)
    FPS_GRP(2, 2)
    FPS_GRP(3, 3)
    float wmax = wave_max_f32_nonneg(bestf);
    if (fps_pub_lane(bestf, wmax, besti)) {
      skey[par ^ 1][w] =
          ((unsigned long long)__float_as_uint(wmax) << 32) | (unsigned)(~besti);
    }
    __syncthreads();
    par ^= 1;
  }
  {
    unsigned long long mk = skey[par][0];
#pragma unroll
    for (int w2 = 1; w2 < W; ++w2) {
      unsigned long long k2 = skey[par][w2];
      if (k2 > mk) mk = k2;
    }
    if (t == 0) fid[NP - 1] = (int)(~(unsigned)mk);
  }
  __syncthreads();
  for (int s = t; s < NP; s += T) {
    int f = fid[s];
    nx[(size_t)b * 3 * NP + s] = sxf[f];
    nx[(size_t)b * 3 * NP + NP + s] = syf[f];
    nx[(size_t)b * 3 * NP + 2 * NP + s] = szf[f];
  }
}

// fps4: R=4 register-resident variant (fps2: N=512, T=128). Proven VGPR=20 shape.
#define FPS_STEP(V, C, IDXOFF)                                               \
  {                                                                          \
    float dx = __fsub_rn(px##V.C, cx);                                       \
    float dy = __fsub_rn(py##V.C, cy);                                       \
    float dz = __fsub_rn(pz##V.C, cz);                                       \
    float d = fmaf(dz, dz, fmaf(dy, dy, __fmul_rn(dx, dx)));                 \
    float nd = fminf(dd##V.C, d);                                            \
    dd##V.C = nd;                                                            \
    if (nd > bestf) {                                                        \
      bestf = nd; besti = t + (IDXOFF); bx = px##V.C; by = py##V.C; bz = pz##V.C; \
    }                                                                        \
  }

#define FPS_LD4(arr, src, off) \
  arr = make_float4((src)[(off)], (src)[(off) + T], (src)[(off) + 2 * T], (src)[(off) + 3 * T])

template <int N, int NP, int T>
__global__ __launch_bounds__(T, 1) void fps4_kernel(const float* __restrict__ xyz,
                                                    float* __restrict__ nx) {
  static_assert(N == 4 * T, "fps4: need exactly 4 points per thread");
  constexpr int W = T / 64;
  __shared__ float4 sslot[2][W][2];
  __shared__ int fid[NP];
  int b = blockIdx.x, t = threadIdx.x;
  int w = t >> 6;
  const float* base = xyz + (size_t)b * 3 * N;
  float4 px0, py0, pz0, dd0;
  FPS_LD4(px0, base, t);
  FPS_LD4(py0, base + N, t);
  FPS_LD4(pz0, base + 2 * N, t);
  dd0 = make_float4(1e10f, 1e10f, 1e10f, 1e10f);
  if (t == 0) {
    fid[0] = 0;
    unsigned long long k0 = ~0ull;
    sslot[0][0][0] = make_float4(__uint_as_float((unsigned)k0),
                                 __uint_as_float((unsigned)(k0 >> 32)), px0.x, py0.x);
    sslot[0][0][1] = make_float4(pz0.x, 0.0f, 0.0f, 0.0f);
  }
  if (t >= 64 && (t & 63) == 0) {
    sslot[0][w][0] = make_float4(0.0f, 0.0f, 0.0f, 0.0f);
    sslot[0][w][1] = make_float4(0.0f, 0.0f, 0.0f, 0.0f);
  }
  int par = 0;
  __syncthreads();
  for (int it = 1; it < NP; ++it) {
    float4 q0 = sslot[par][0][0];
    float4 q1 = sslot[par][0][1];
    unsigned long long mk =
        ((unsigned long long)__float_as_uint(q0.y) << 32) | __float_as_uint(q0.x);
    float cx = q0.z, cy = q0.w, cz = q1.x;
#pragma unroll
    for (int w2 = 1; w2 < W; ++w2) {
      float4 p0 = sslot[par][w2][0];
      float4 p1 = sslot[par][w2][1];
      unsigned long long k2 =
          ((unsigned long long)__float_as_uint(p0.y) << 32) | __float_as_uint(p0.x);
      if (k2 > mk) { mk = k2; cx = p0.z; cy = p0.w; cz = p1.x; }
    }
    if (t == 0) fid[it - 1] = (int)(~(unsigned)mk);
    float bestf = -1.0f;
    int besti = t;
    float bx = px0.x, by = py0.x, bz = pz0.x;
    FPS_STEP(0, x, 0) FPS_STEP(0, y, T) FPS_STEP(0, z, 2 * T) FPS_STEP(0, w, 3 * T)
    float wmax = wave_max_f32_nonneg(bestf);
    if (fps_pub_lane(bestf, wmax, besti)) {
      unsigned long long key =
          ((unsigned long long)__float_as_uint(wmax) << 32) | (unsigned)(~besti);
      sslot[par ^ 1][w][0] = make_float4(__uint_as_float((unsigned)key),
                                         __uint_as_float((unsigned)(key >> 32)), bx, by);
      sslot[par ^ 1][w][1] = make_float4(bz, 0.0f, 0.0f, 0.0f);
    }
    __syncthreads();
    par ^= 1;
  }
  {
    float4 q0 = sslot[par][0][0];
    unsigned long long mk =
        ((unsigned long long)__float_as_uint(q0.y) << 32) | __float_as_uint(q0.x);
#pragma unroll
    for (int w2 = 1; w2 < W; ++w2) {
      float4 p0 = sslot[par][w2][0];
      unsigned long long k2 =
          ((unsigned long long)__float_as_uint(p0.y) << 32) | __float_as_uint(p0.x);
      if (k2 > mk) mk = k2;
    }
    if (t == 0) fid[NP - 1] = (int)(~(unsigned)mk);
  }
  __syncthreads();
  for (int s = t; s < NP; s += T) {
    int f = fid[s];
    nx[(size_t)b * 3 * NP + s] = base[f];
    nx[(size_t)b * 3 * NP + NP + s] = base[N + f];
    nx[(size_t)b * 3 * NP + 2 * NP + s] = base[2 * N + f];
  }
}

// ---------------- ball query ----------------
template <int NPTS, int NQ, int NS>
__global__ void bq_kernel(const float* __restrict__ pts, const float* __restrict__ qry,
                          float r2, int* __restrict__ gidx) {
  int gw = (blockIdx.x * blockDim.x + threadIdx.x) >> 6;
  int lane = threadIdx.x & 63;
  if (gw >= kB * NQ) return;
  int b = gw / NQ, s = gw - b * NQ;
  const float* pb = pts + (size_t)b * 3 * NPTS;
  float cx = qry[(size_t)b * 3 * NQ + s];
  float cy = qry[(size_t)b * 3 * NQ + NQ + s];
  float cz = qry[(size_t)b * 3 * NQ + 2 * NQ + s];
  float ss = fmaf(cz, cz, fmaf(cy, cy, __fmul_rn(cx, cx)));
  int* out = gidx + (size_t)gw * NS;
  int have = 0, first = 0;
  bool gotfirst = false;
  for (int n0 = 0; n0 < NPTS; n0 += 64) {
    int n = n0 + lane;
    float x = pb[n], y = pb[NPTS + n], z = pb[2 * NPTS + n];
    float dd = fmaf(z, z, fmaf(y, y, __fmul_rn(x, x)));
    float cross = fmaf(cz, z, fmaf(cy, y, __fmul_rn(cx, x)));
    float sqr = __fsub_rn(__fadd_rn(ss, dd), __fmul_rn(2.0f, cross));
    bool pred = !(sqr > r2);
    unsigned long long mask = __ballot(pred);
    if (!gotfirst && mask) { first = n0 + (__ffsll(mask) - 1); gotfirst = true; }
    if (pred) {
      int pos = have + __popcll(mask & ((1ull << lane) - 1ull));
      if (pos < NS) out[pos] = n;
    }
    have += __popcll(mask);
    if (have >= NS) break;
  }
  for (int slot = have + lane; slot < NS; slot += 64) out[slot] = first;
}

// ---------------- SA1 grouped MLP (3->64->64->128) + max over 32 samples ----------------
__global__ __launch_bounds__(256, 2) void sa1_mlp_kernel(
    const float* __restrict__ xyz, const float* __restrict__ nx1,
    const int* __restrict__ gidx,
    const float* __restrict__ W0f, const float* __restrict__ bf0,   // [64][4], [64]
    const float* __restrict__ WT1, const float* __restrict__ bf1,   // [64][64]
    const float* __restrict__ WT2, const float* __restrict__ bf2,   // [64][128]
    float* __restrict__ l1_pts) {
  __shared__ float XT[64 * 256];   // reused for X1 then X2
  int t = threadIdx.x;
  int qi = t >> 5, sm = t & 31;
  int q = blockIdx.x * 8 + qi;
  int b = q >> 9, s = q & 511;
  int idx = gidx[(size_t)q * kNS1 + sm];
  float cx = nx1[b * 1536 + s];
  float cy = nx1[b * 1536 + 512 + s];
  float cz = nx1[b * 1536 + 1024 + s];
  const float* pb = xyz + (size_t)b * 3 * kN1;
  float f0 = pb[idx] - cx, f1 = pb[kN1 + idx] - cy, f2 = pb[2 * kN1 + idx] - cz;
  for (int j = 0; j < 64; ++j) {
    float4 w = *(const float4*)&W0f[j * 4];
    float v = fmaf(f2, w.z, fmaf(f1, w.y, fmaf(f0, w.x, bf0[j])));
    XT[j * 256 + t] = fmaxf(v, 0.0f);
  }
  __syncthreads();
  float acc[64];
#pragma unroll
  for (int j = 0; j < 64; ++j) acc[j] = bf1[j];
  for (int k = 0; k < 64; ++k) {
    float xk = XT[k * 256 + t];
    const float* wr = WT1 + k * 64;
#pragma unroll
    for (int j = 0; j < 64; ++j) acc[j] = fmaf(xk, wr[j], acc[j]);
  }
  __syncthreads();
#pragma unroll
  for (int j = 0; j < 64; ++j) XT[j * 256 + t] = fmaxf(acc[j], 0.0f);
  __syncthreads();
  float* outp = l1_pts + (size_t)q * 128;
  for (int jp = 0; jp < 2; ++jp) {
#pragma unroll
    for (int j = 0; j < 64; ++j) acc[j] = bf2[jp * 64 + j];
    for (int k = 0; k < 64; ++k) {
      float xk = XT[k * 256 + t];
      const float* wr = WT2 + k * 128 + jp * 64;
#pragma unroll
      for (int j = 0; j < 64; ++j) acc[j] = fmaf(xk, wr[j], acc[j]);
    }
#pragma unroll
    for (int j = 0; j < 64; ++j) {
      float m = fmaxf(acc[j], 0.0f);
      m = fmaxf(m, __shfl_xor(m, 1, 64));
      m = fmaxf(m, __shfl_xor(m, 2, 64));
      m = fmaxf(m, __shfl_xor(m, 4, 64));
      m = fmaxf(m, __shfl_xor(m, 8, 64));
      m = fmaxf(m, __shfl_xor(m, 16, 64));
      if (sm == 0) outp[jp * 64 + j] = m;
    }
  }
}

// ---------------- SA2 grouped MLP (131->128->128->256) + max over 64 samples ----------------
// R12 proven-best form: SGPR weight path + chunk-2 k-loop (2 rows / 64 SGPRs in
// flight per chunk -> SMEM latency amortized over 128 cyc of fma). fb[64][133]
// row-major, 34 KB -> 4 blocks/CU. Accumulation order per acc[j] unchanged.
#define F_STR 133
__global__ __launch_bounds__(256, 4) void sa2_mlp_kernel(
    const float* __restrict__ nx1, const float* __restrict__ l1_pts,
    const float* __restrict__ nx2, const int* __restrict__ gidx2,
    const float* __restrict__ WT1, const float* __restrict__ bf1,   // [132][128]
    const float* __restrict__ WT2, const float* __restrict__ bf2,   // [128][128]
    const float* __restrict__ WT3, const float* __restrict__ bf3,   // [128][256]
    float* __restrict__ l2_pts) {
  __shared__ float fb[64 * F_STR];
  int t = threadIdx.x;
  int lane = t & 63;
  int wg = __builtin_amdgcn_readfirstlane(t >> 6);
  int q = blockIdx.x;
  int b = q >> 7, s = q & 127;
  int idx = gidx2[(size_t)q * kNS2 + lane];
  const float* pr = l1_pts + ((size_t)(b * kS1) + idx) * 128;
  float* frow = fb + lane * F_STR;
#pragma unroll
  for (int i = 0; i < 8; ++i) {
    float4 v = *(const float4*)&pr[wg * 32 + i * 4];
    frow[3 + wg * 32 + i * 4 + 0] = v.x;
    frow[3 + wg * 32 + i * 4 + 1] = v.y;
    frow[3 + wg * 32 + i * 4 + 2] = v.z;
    frow[3 + wg * 32 + i * 4 + 3] = v.w;
  }
  if (wg == 0) {
    float cx = nx2[b * 384 + s];
    float cy = nx2[b * 384 + 128 + s];
    float cz = nx2[b * 384 + 256 + s];
    frow[0] = nx1[b * 1536 + idx] - cx;
    frow[1] = nx1[b * 1536 + 512 + idx] - cy;
    frow[2] = nx1[b * 1536 + 1024 + idx] - cz;
    frow[131] = 0.0f;
  }
  __syncthreads();
  float acc[32];
#pragma unroll
  for (int j = 0; j < 32; ++j) acc[j] = bf1[wg * 32 + j];
  for (int k = 0; k < 132; k += 2) {   // chunk-2: both rows + both xk issued first
    float x0 = frow[k];
    float x1 = frow[k + 1];
    const float* w0 = WT1 + k * 128 + wg * 32;
    const float* w1 = WT1 + (k + 1) * 128 + wg * 32;
#pragma unroll
    for (int j = 0; j < 32; ++j) acc[j] = fmaf(x0, w0[j], acc[j]);
#pragma unroll
    for (int j = 0; j < 32; ++j) acc[j] = fmaf(x1, w1[j], acc[j]);
  }
  __syncthreads();
#pragma unroll
  for (int j = 0; j < 32; ++j) frow[wg * 32 + j] = fmaxf(acc[j], 0.0f);
  __syncthreads();
#pragma unroll
  for (int j = 0; j < 32; ++j) acc[j] = bf2[wg * 32 + j];
  for (int k = 0; k < 128; k += 2) {
    float x0 = frow[k];
    float x1 = frow[k + 1];
    const float* w0 = WT2 + k * 128 + wg * 32;
    const float* w1 = WT2 + (k + 1) * 128 + wg * 32;
#pragma unroll
    for (int j = 0; j < 32; ++j) acc[j] = fmaf(x0, w0[j], acc[j]);
#pragma unroll
    for (int j = 0; j < 32; ++j) acc[j] = fmaf(x1, w1[j], acc[j]);
  }
  __syncthreads();
#pragma unroll
  for (int j = 0; j < 32; ++j) frow[wg * 32 + j] = fmaxf(acc[j], 0.0f);
  __syncthreads();
  float* outp = l2_pts + (size_t)q * 256;
  for (int jp = 0; jp < 2; ++jp) {
    int j0 = wg * 64 + jp * 32;
#pragma unroll
    for (int j = 0; j < 32; ++j) acc[j] = bf3[j0 + j];
    for (int k = 0; k < 128; k += 2) {
      float x0 = frow[k];
      float x1 = frow[k + 1];
      const float* w0 = WT3 + k * 256 + j0;
      const float* w1 = WT3 + (k + 1) * 256 + j0;
#pragma unroll
      for (int j = 0; j < 32; ++j) acc[j] = fmaf(x0, w0[j], acc[j]);
#pragma unroll
      for (int j = 0; j < 32; ++j) acc[j] = fmaf(x1, w1[j], acc[j]);
    }
#pragma unroll
    for (int j = 0; j < 32; ++j) {
      float m = fmaxf(acc[j], 0.0f);
      m = fmaxf(m, __shfl_xor(m, 1, 64));
      m = fmaxf(m, __shfl_xor(m, 2, 64));
      m = fmaxf(m, __shfl_xor(m, 4, 64));
      m = fmaxf(m, __shfl_xor(m, 8, 64));
      m = fmaxf(m, __shfl_xor(m, 16, 64));
      m = fmaxf(m, __shfl_xor(m, 32, 64));
      if (lane == 0) outp[j0 + j] = m;
    }
  }
}

// ---------------- SA3 (group-all): 259->256->512->1024 -> max over 128 ----------------
__global__ __launch_bounds__(256, 2) void sa3_passA_kernel(
    const float* __restrict__ nx2, const float* __restrict__ l2_pts,
    const float* __restrict__ WT, const float* __restrict__ bf,
    float* __restrict__ Y) {   // O = 256
  __shared__ float sF[16 * 260];
  int stile = blockIdx.x, t = threadIdx.x;
  int j = t;
  for (int i = t; i < 16 * 260; i += 256) {
    int row = stile * 16 + i / 260, k = i - (i / 260) * 260;
    int b = row >> 7, s = row & 127;
    float v;
    if (k < 3) v = nx2[b * 384 + k * 128 + s];
    else if (k < 259) v = l2_pts[(size_t)row * 256 + (k - 3)];
    else v = 0.0f;
    sF[i] = v;
  }
  __syncthreads();
  float acc[16];
  float bj = bf[j];
#pragma unroll
  for (int s = 0; s < 16; ++s) acc[s] = bj;
  for (int k = 0; k < 260; k += 4) {
    float w0 = WT[(size_t)k * 256 + j];
    float w1 = WT[(size_t)(k + 1) * 256 + j];
    float w2 = WT[(size_t)(k + 2) * 256 + j];
    float w3 = WT[(size_t)(k + 3) * 256 + j];
#pragma unroll
    for (int s = 0; s < 16; ++s) {
      const float4 fv = *(const float4*)&sF[s * 260 + k];
      acc[s] = fmaf(fv.x, w0, acc[s]);
      acc[s] = fmaf(fv.y, w1, acc[s]);
      acc[s] = fmaf(fv.z, w2, acc[s]);
      acc[s] = fmaf(fv.w, w3, acc[s]);
    }
  }
  float* yb = Y + (size_t)stile * 16 * 256 + j;
#pragma unroll
  for (int s = 0; s < 16; ++s) yb[(size_t)s * 256] = fmaxf(acc[s], 0.0f);
}

template <int KP>
__global__ __launch_bounds__(256, 2) void mlp_pass_kernel(
    const float* __restrict__ X, const float* __restrict__ WT, const float* __restrict__ bf,
    int O, float* __restrict__ Y) {
  __shared__ float sF[16 * KP];
  int stile = blockIdx.x, t = threadIdx.x;
  int j = blockIdx.y * 256 + t;
  const float* xb = X + (size_t)stile * 16 * KP;
  for (int i = t; i < 16 * KP; i += 256) sF[i] = xb[i];
  __syncthreads();
  float acc[16];
  float bj = bf[j];
#pragma unroll
  for (int s = 0; s < 16; ++s) acc[s] = bj;
  for (int k = 0; k < KP; k += 4) {
    float w0 = WT[(size_t)k * O + j];
    float w1 = WT[(size_t)(k + 1) * O + j];
    float w2 = WT[(size_t)(k + 2) * O + j];
    float w3 = WT[(size_t)(k + 3) * O + j];
#pragma unroll
    for (int s = 0; s < 16; ++s) {
      const float4 fv = *(const float4*)&sF[s * KP + k];
      acc[s] = fmaf(fv.x, w0, acc[s]);
      acc[s] = fmaf(fv.y, w1, acc[s]);
      acc[s] = fmaf(fv.z, w2, acc[s]);
      acc[s] = fmaf(fv.w, w3, acc[s]);
    }
  }
  float* yb = Y + (size_t)stile * 16 * O + j;
#pragma unroll
  for (int s = 0; s < 16; ++s) yb[(size_t)s * O] = fmaxf(acc[s], 0.0f);
}

__global__ __launch_bounds__(256, 2) void sa3_final_kernel(
    const float* __restrict__ X2g, const float* __restrict__ WTc, const float* __restrict__ bfc,
    float* __restrict__ out) {
  __shared__ float sF[16 * 512];
  int b = blockIdx.x, t = threadIdx.x;
  int j = blockIdx.y * 256 + t;
  float m = 0.0f;
  float bj = bfc[j];
  for (int st = 0; st < 8; ++st) {
    const float* xb = X2g + ((size_t)b * 128 + st * 16) * 512;
    for (int i = t; i < 16 * 512; i += 256) sF[i] = xb[i];
    __syncthreads();
    float acc[16];
#pragma unroll
    for (int s = 0; s < 16; ++s) acc[s] = bj;
    for (int k = 0; k < 512; k += 4) {
      float w0 = WTc[(size_t)k * 1024 + j];
      float w1 = WTc[(size_t)(k + 1) * 1024 + j];
      float w2 = WTc[(size_t)(k + 2) * 1024 + j];
      float w3 = WTc[(size_t)(k + 3) * 1024 + j];
#pragma unroll
      for (int s = 0; s < 16; ++s) {
        const float4 fv = *(const float4*)&sF[s * 512 + k];
        acc[s] = fmaf(fv.x, w0, acc[s]);
        acc[s] = fmaf(fv.y, w1, acc[s]);
        acc[s] = fmaf(fv.z, w2, acc[s]);
        acc[s] = fmaf(fv.w, w3, acc[s]);
      }
    }
#pragma unroll
    for (int s = 0; s < 16; ++s) m = fmaxf(m, fmaxf(acc[s], 0.0f));
    __syncthreads();
  }
  out[(size_t)b * 1024 + j] = m;
}

// ---------------- launch ----------------
extern "C" void kernel_launch(void* const* d_in, const int* in_sizes, int n_in,
                              void* d_out, int out_size, void* d_ws, size_t ws_size,
                              hipStream_t stream) {
  (void)in_sizes; (void)n_in; (void)out_size; (void)ws_size;
  const float* xyz = (const float*)d_in[0];
  auto WP = [&](int layer, int part) -> const float* {
    return (const float*)d_in[1 + layer * 4 + part];
  };
  float* wsf = (float*)d_ws;
  size_t cur = 0;
  auto alloc = [&](size_t n) { size_t o = cur; cur += (n + 63) & ~(size_t)63; return o; };
  size_t o_nx1 = alloc((size_t)kB * 3 * kS1);
  size_t o_nx2 = alloc((size_t)kB * 3 * kS2);
  size_t o_l1pts = alloc((size_t)kB * kS1 * 128);
  size_t o_l2pts = alloc((size_t)kB * kS2 * 256);
  size_t o_X1g = alloc((size_t)kB * kS2 * 256);
  size_t o_X2g = alloc((size_t)kB * kS2 * 512);
  size_t o_s1w0 = alloc(64 * 4), o_s1b0 = alloc(64);
  size_t o_s1w1 = alloc(64 * 64), o_s1b1 = alloc(64);
  size_t o_s1wt2 = alloc(64 * 128), o_s1b2 = alloc(128);
  size_t o_s2w1 = alloc(132 * 128), o_s2b1 = alloc(128);
  size_t o_s2wt2 = alloc(128 * 128), o_s2b2 = alloc(128);
  size_t o_s2w3 = alloc(128 * 256), o_s2b3 = alloc(256);
  size_t o_s3wtA = alloc(260 * 256), o_s3bA = alloc(256);
  size_t o_s3wtB = alloc(256 * 512), o_s3bB = alloc(512);
  size_t o_s3wtC = alloc(512 * 1024), o_s3bC = alloc(1024);
  size_t o_gidx1 = alloc((size_t)kB * kS1 * kNS1);
  size_t o_gidx2 = alloc((size_t)kB * kS2 * kNS2);
  int* gidx1 = (int*)(wsf + o_gidx1);
  int* gidx2 = (int*)(wsf + o_gidx2);

  // fused fold of all 9 layers
  FoldPack fp;
  const int OKKp[9][3] = {{64, 3, 4},     {64, 64, 64},   {128, 64, 64},
                          {128, 131, 132}, {128, 128, 128}, {256, 128, 128},
                          {256, 259, 260}, {512, 256, 256}, {1024, 512, 512}};
  float* wouts[9] = {wsf + o_s1w0, wsf + o_s1w1, wsf + o_s1wt2,
                     wsf + o_s2w1, wsf + o_s2wt2, wsf + o_s2w3,
                     wsf + o_s3wtA, wsf + o_s3wtB, wsf + o_s3wtC};
  float* bouts[9] = {wsf + o_s1b0, wsf + o_s1b1, wsf + o_s1b2,
                     wsf + o_s2b1, wsf + o_s2b2, wsf + o_s2b3,
                     wsf + o_s3bA, wsf + o_s3bB, wsf + o_s3bC};
  const int nblk[9] = {1, 4, 8, 17, 16, 32, 65, 128, 512};
  fp.cum[0] = 0;
  for (int L = 0; L < 9; ++L) {
    fp.d[L].W = WP(L, 0);
    fp.d[L].b = WP(L, 1);
    fp.d[L].g = WP(L, 2);
    fp.d[L].bt = WP(L, 3);
    fp.d[L].Wout = wouts[L];
    fp.d[L].bout = bouts[L];
    fp.d[L].O = OKKp[L][0];
    fp.d[L].K = OKKp[L][1];
    fp.d[L].Kp = OKKp[L][2];
    fp.d[L].transposed = (L == 0) ? 0 : 1;
    fp.cum[L + 1] = fp.cum[L] + nblk[L];
  }
  foldall_kernel<<<fp.cum[9], 256, 0, stream>>>(fp);

  // SA1
  fps16_kernel<kN1, kS1, 256><<<kB, 256, 0, stream>>>(xyz, wsf + o_nx1);
  bq_kernel<kN1, kS1, kNS1><<<(kB * kS1) / 4, 256, 0, stream>>>(xyz, wsf + o_nx1, 0.04f, gidx1);
  sa1_mlp_kernel<<<(kB * kS1) / 8, 256, 0, stream>>>(
      xyz, wsf + o_nx1, gidx1,
      wsf + o_s1w0, wsf + o_s1b0, wsf + o_s1w1, wsf + o_s1b1, wsf + o_s1wt2, wsf + o_s1b2,
      wsf + o_l1pts);

  // SA2
  fps4_kernel<kS1, kS2, 128><<<kB, 128, 0, stream>>>(wsf + o_nx1, wsf + o_nx2);
  bq_kernel<kS1, kS2, kNS2><<<(kB * kS2) / 4, 256, 0, stream>>>(wsf + o_nx1, wsf + o_nx2, 0.16f, gidx2);
  sa2_mlp_kernel<<<kB * kS2, 256, 0, stream>>>(
      wsf + o_nx1, wsf + o_l1pts, wsf + o_nx2, gidx2,
      wsf + o_s2w1, wsf + o_s2b1, wsf + o_s2wt2, wsf + o_s2b2, wsf + o_s2w3, wsf + o_s2b3,
      wsf + o_l2pts);

  // SA3 (group all)
  sa3_passA_kernel<<<256, 256, 0, stream>>>(wsf + o_nx2, wsf + o_l2pts,
                                            wsf + o_s3wtA, wsf + o_s3bA, wsf + o_X1g);
  mlp_pass_kernel<256><<<dim3(256, 2), 256, 0, stream>>>(wsf + o_X1g, wsf + o_s3wtB, wsf + o_s3bB, 512, wsf + o_X2g);
  sa3_final_kernel<<<dim3(kB, 4), 256, 0, stream>>>(wsf + o_X2g, wsf + o_s3wtC, wsf + o_s3bC, (float*)d_out);
}

// Round 18
// 1132.568 us; speedup vs baseline: 1.3545x; 1.3302x over previous
//
#include <hip/hip_runtime.h>
#include <hip/hip_bf16.h>
#include <cstddef>
#include <math.h>

#define kB 32
#define kN1 4096
#define kS1 512
#define kNS1 32
#define kS2 128
#define kNS2 64

typedef short bf16x8 __attribute__((ext_vector_type(8)));
typedef float f32x4 __attribute__((ext_vector_type(4)));

__device__ __forceinline__ short f2bf(float f) {   // RTN-even fp32 -> bf16 bits
  unsigned u = __float_as_uint(f);
  unsigned r = (u + 0x7fffu + ((u >> 16) & 1u)) >> 16;
  return (short)r;
}

// ---------------- fused weight folding for all 9 layers ----------------
struct FoldDesc {
  const float *W, *b, *g, *bt;
  float *Wout, *bout;
  int O, K, Kp, transposed;
};
struct FoldPack {
  FoldDesc d[9];
  int cum[10];
};

__global__ __launch_bounds__(256) void foldall_kernel(FoldPack p) {
  int blk = blockIdx.x;
  int L = 0;
#pragma unroll
  for (int i = 0; i < 9; ++i)
    if (blk >= p.cum[i + 1]) L = i + 1;
  FoldDesc d = p.d[L];
  int nb = p.cum[L + 1] - p.cum[L];
  int tid = (blk - p.cum[L]) * 256 + threadIdx.x;
  int stride = nb * 256;
  float inv = 1.0f / sqrtf(1.0f + 1e-5f);
  for (int i = tid; i < d.O * d.Kp; i += stride) {
    int o = i / d.Kp, k = i - o * d.Kp;
    float s = d.g[o] * inv;
    float w = (k < d.K) ? d.W[o * d.K + k] * s : 0.0f;
    if (d.transposed) d.Wout[k * d.O + o] = w;
    else d.Wout[o * d.Kp + k] = w;
  }
  for (int o = tid; o < d.O; o += stride) {
    d.bout[o] = d.b[o] * (d.g[o] * inv) + d.bt[o];
  }
}

// Pack folded fp32 k-major weights [K][O] into bf16 MFMA B-fragment order:
// dst[(tn*KT + tk)*512 + lane*8 + i] = W[kmap(tk*32 + (lane>>4)*8 + i)][tn*16 + (lane&15)]
// mode 1 = sa2 layer1 K-permutation (features 0..127 -> rows 3..130, coords -> rows 0..2, pad 0).
__global__ void sa2pack_kernel(const float* __restrict__ W, short* __restrict__ dst,
                               int O, int Kpad, int mode) {
  int e = blockIdx.x * 256 + threadIdx.x;
  int total = O * Kpad;
  if (e >= total) return;
  int i = e & 7, lane = (e >> 3) & 63, tile = e >> 9;
  int KT = Kpad / 32;
  int tn = tile / KT, tk = tile - tn * KT;
  int kk = tk * 32 + ((lane >> 4) & 3) * 8 + i;
  int n = tn * 16 + (lane & 15);
  float v;
  if (mode == 1) {
    int ok = (kk < 128) ? kk + 3 : ((kk < 131) ? kk - 128 : -1);
    v = (ok < 0) ? 0.0f : W[ok * O + n];
  } else {
    v = W[kk * O + n];
  }
  dst[e] = f2bf(v);
}

// Canonical CDNA wave64 f32 max via DPP (VALU pipe only).
__device__ __forceinline__ float wave_max_f32_nonneg(float x) {
#define DPP_MAXSTEP(CTRL)                                                     \
  {                                                                           \
    int o = __builtin_amdgcn_update_dpp(0, __float_as_int(x), (CTRL), 0xf, 0xf, true); \
    x = fmaxf(x, __int_as_float(o));                                          \
  }
  DPP_MAXSTEP(0x111)
  DPP_MAXSTEP(0x112)
  DPP_MAXSTEP(0x114)
  DPP_MAXSTEP(0x118)
  DPP_MAXSTEP(0x142)
  DPP_MAXSTEP(0x143)
#undef DPP_MAXSTEP
  return __int_as_float(__builtin_amdgcn_readlane(__float_as_int(x), 63));
}

__device__ __forceinline__ bool fps_pub_lane(float bestf, float wmax, int besti) {
  unsigned long long m = __ballot(bestf == wmax);
  if (__popcll(m) == 1) return bestf == wmax;
  unsigned long long mm = m;
  int bidx = 0x7fffffff;
  while (mm) {
    int l = __ffsll(mm) - 1;
    int bi = __shfl(besti, l, 64);
    bidx = min(bidx, bi);
    mm &= mm - 1;
  }
  return (bestf == wmax) && (besti == bidx);
}

// ---------------- farthest point sampling (R12 proven-best forms) ----------------
#define FPS_E(V, C, XV, YV, ZV, I)                                           \
  {                                                                          \
    float dx = __fsub_rn((XV), cx);                                          \
    float dy = __fsub_rn((YV), cy);                                          \
    float dz = __fsub_rn((ZV), cz);                                          \
    float d = fmaf(dz, dz, fmaf(dy, dy, __fmul_rn(dx, dx)));                 \
    float nd = fminf(dd##V.C, d);                                            \
    dd##V.C = nd;                                                            \
    if (nd > bestf) { bestf = nd; besti = (I); }                             \
  }

#define FPS_GRP(V, R)                                                        \
  {                                                                          \
    float4 xg = sx4[t + (R) * T];                                            \
    float4 yg = sy4[t + (R) * T];                                            \
    float4 zg = sz4[t + (R) * T];                                            \
    int ibase = 4 * (t + (R) * T);                                           \
    FPS_E(V, x, xg.x, yg.x, zg.x, ibase)                                     \
    FPS_E(V, y, xg.y, yg.y, zg.y, ibase + 1)                                 \
    FPS_E(V, z, xg.z, yg.z, zg.z, ibase + 2)                                 \
    FPS_E(V, w, xg.w, yg.w, zg.w, ibase + 3)                                 \
  }

template <int N, int NP, int T>
__global__ __launch_bounds__(T, 1) void fps16_kernel(const float* __restrict__ xyz,
                                                     float* __restrict__ nx) {
  static_assert(N == 16 * T, "fps16: need exactly 16 points per thread");
  constexpr int W = T / 64;
  __shared__ float4 sx4[N / 4], sy4[N / 4], sz4[N / 4];
  __shared__ unsigned long long skey[2][W];
  __shared__ int fid[NP];
  int b = blockIdx.x, t = threadIdx.x;
  int w = t >> 6;
  const float* base = xyz + (size_t)b * 3 * N;
  float* sxf = (float*)sx4;
  float* syf = (float*)sy4;
  float* szf = (float*)sz4;
  for (int i = t; i < N; i += T) sxf[i] = base[i];
  for (int i = t; i < N; i += T) syf[i] = base[N + i];
  for (int i = t; i < N; i += T) szf[i] = base[2 * N + i];
  float4 dd0, dd1, dd2, dd3;
  dd0 = dd1 = dd2 = dd3 = make_float4(1e10f, 1e10f, 1e10f, 1e10f);
  if (t < W) skey[0][t] = (t == 0) ? ~0ull : 0ull;
  if (t == 0) fid[0] = 0;
  int par = 0;
  __syncthreads();
  for (int it = 1; it < NP; ++it) {
    unsigned long long mk = skey[par][0];
#pragma unroll
    for (int w2 = 1; w2 < W; ++w2) {
      unsigned long long k2 = skey[par][w2];
      if (k2 > mk) mk = k2;
    }
    int wi = (int)(~(unsigned)mk);
    if (t == 0) fid[it - 1] = wi;
    float cx = sxf[wi], cy = syf[wi], cz = szf[wi];
    float bestf = -1.0f;
    int besti = 4 * t;
    FPS_GRP(0, 0)
    FPS_GRP(1, 1)
    FPS_GRP(2, 2)
    FPS_GRP(3, 3)
    float wmax = wave_max_f32_nonneg(bestf);
    if (fps_pub_lane(bestf, wmax, besti)) {
      skey[par ^ 1][w] =
          ((unsigned long long)__float_as_uint(wmax) << 32) | (unsigned)(~besti);
    }
    __syncthreads();
    par ^= 1;
  }
  {
    unsigned long long mk = skey[par][0];
#pragma unroll
    for (int w2 = 1; w2 < W; ++w2) {
      unsigned long long k2 = skey[par][w2];
      if (k2 > mk) mk = k2;
    }
    if (t == 0) fid[NP - 1] = (int)(~(unsigned)mk);
  }
  __syncthreads();
  for (int s = t; s < NP; s += T) {
    int f = fid[s];
    nx[(size_t)b * 3 * NP + s] = sxf[f];
    nx[(size_t)b * 3 * NP + NP + s] = syf[f];
    nx[(size_t)b * 3 * NP + 2 * NP + s] = szf[f];
  }
}

#define FPS_STEP(V, C, IDXOFF)                                               \
  {                                                                          \
    float dx = __fsub_rn(px##V.C, cx);                                       \
    float dy = __fsub_rn(py##V.C, cy);                                       \
    float dz = __fsub_rn(pz##V.C, cz);                                       \
    float d = fmaf(dz, dz, fmaf(dy, dy, __fmul_rn(dx, dx)));                 \
    float nd = fminf(dd##V.C, d);                                            \
    dd##V.C = nd;                                                            \
    if (nd > bestf) {                                                        \
      bestf = nd; besti = t + (IDXOFF); bx = px##V.C; by = py##V.C; bz = pz##V.C; \
    }                                                                        \
  }

#define FPS_LD4(arr, src, off) \
  arr = make_float4((src)[(off)], (src)[(off) + T], (src)[(off) + 2 * T], (src)[(off) + 3 * T])

template <int N, int NP, int T>
__global__ __launch_bounds__(T, 1) void fps4_kernel(const float* __restrict__ xyz,
                                                    float* __restrict__ nx) {
  static_assert(N == 4 * T, "fps4: need exactly 4 points per thread");
  constexpr int W = T / 64;
  __shared__ float4 sslot[2][W][2];
  __shared__ int fid[NP];
  int b = blockIdx.x, t = threadIdx.x;
  int w = t >> 6;
  const float* base = xyz + (size_t)b * 3 * N;
  float4 px0, py0, pz0, dd0;
  FPS_LD4(px0, base, t);
  FPS_LD4(py0, base + N, t);
  FPS_LD4(pz0, base + 2 * N, t);
  dd0 = make_float4(1e10f, 1e10f, 1e10f, 1e10f);
  if (t == 0) {
    fid[0] = 0;
    unsigned long long k0 = ~0ull;
    sslot[0][0][0] = make_float4(__uint_as_float((unsigned)k0),
                                 __uint_as_float((unsigned)(k0 >> 32)), px0.x, py0.x);
    sslot[0][0][1] = make_float4(pz0.x, 0.0f, 0.0f, 0.0f);
  }
  if (t >= 64 && (t & 63) == 0) {
    sslot[0][w][0] = make_float4(0.0f, 0.0f, 0.0f, 0.0f);
    sslot[0][w][1] = make_float4(0.0f, 0.0f, 0.0f, 0.0f);
  }
  int par = 0;
  __syncthreads();
  for (int it = 1; it < NP; ++it) {
    float4 q0 = sslot[par][0][0];
    float4 q1 = sslot[par][0][1];
    unsigned long long mk =
        ((unsigned long long)__float_as_uint(q0.y) << 32) | __float_as_uint(q0.x);
    float cx = q0.z, cy = q0.w, cz = q1.x;
#pragma unroll
    for (int w2 = 1; w2 < W; ++w2) {
      float4 p0 = sslot[par][w2][0];
      float4 p1 = sslot[par][w2][1];
      unsigned long long k2 =
          ((unsigned long long)__float_as_uint(p0.y) << 32) | __float_as_uint(p0.x);
      if (k2 > mk) { mk = k2; cx = p0.z; cy = p0.w; cz = p1.x; }
    }
    if (t == 0) fid[it - 1] = (int)(~(unsigned)mk);
    float bestf = -1.0f;
    int besti = t;
    float bx = px0.x, by = py0.x, bz = pz0.x;
    FPS_STEP(0, x, 0) FPS_STEP(0, y, T) FPS_STEP(0, z, 2 * T) FPS_STEP(0, w, 3 * T)
    float wmax = wave_max_f32_nonneg(bestf);
    if (fps_pub_lane(bestf, wmax, besti)) {
      unsigned long long key =
          ((unsigned long long)__float_as_uint(wmax) << 32) | (unsigned)(~besti);
      sslot[par ^ 1][w][0] = make_float4(__uint_as_float((unsigned)key),
                                         __uint_as_float((unsigned)(key >> 32)), bx, by);
      sslot[par ^ 1][w][1] = make_float4(bz, 0.0f, 0.0f, 0.0f);
    }
    __syncthreads();
    par ^= 1;
  }
  {
    float4 q0 = sslot[par][0][0];
    unsigned long long mk =
        ((unsigned long long)__float_as_uint(q0.y) << 32) | __float_as_uint(q0.x);
#pragma unroll
    for (int w2 = 1; w2 < W; ++w2) {
      float4 p0 = sslot[par][w2][0];
      unsigned long long k2 =
          ((unsigned long long)__float_as_uint(p0.y) << 32) | __float_as_uint(p0.x);
      if (k2 > mk) mk = k2;
    }
    if (t == 0) fid[NP - 1] = (int)(~(unsigned)mk);
  }
  __syncthreads();
  for (int s = t; s < NP; s += T) {
    int f = fid[s];
    nx[(size_t)b * 3 * NP + s] = base[f];
    nx[(size_t)b * 3 * NP + NP + s] = base[N + f];
    nx[(size_t)b * 3 * NP + 2 * NP + s] = base[2 * N + f];
  }
}

// ---------------- ball query ----------------
template <int NPTS, int NQ, int NS>
__global__ void bq_kernel(const float* __restrict__ pts, const float* __restrict__ qry,
                          float r2, int* __restrict__ gidx) {
  int gw = (blockIdx.x * blockDim.x + threadIdx.x) >> 6;
  int lane = threadIdx.x & 63;
  if (gw >= kB * NQ) return;
  int b = gw / NQ, s = gw - b * NQ;
  const float* pb = pts + (size_t)b * 3 * NPTS;
  float cx = qry[(size_t)b * 3 * NQ + s];
  float cy = qry[(size_t)b * 3 * NQ + NQ + s];
  float cz = qry[(size_t)b * 3 * NQ + 2 * NQ + s];
  float ss = fmaf(cz, cz, fmaf(cy, cy, __fmul_rn(cx, cx)));
  int* out = gidx + (size_t)gw * NS;
  int have = 0, first = 0;
  bool gotfirst = false;
  for (int n0 = 0; n0 < NPTS; n0 += 64) {
    int n = n0 + lane;
    float x = pb[n], y = pb[NPTS + n], z = pb[2 * NPTS + n];
    float dd = fmaf(z, z, fmaf(y, y, __fmul_rn(x, x)));
    float cross = fmaf(cz, z, fmaf(cy, y, __fmul_rn(cx, x)));
    float sqr = __fsub_rn(__fadd_rn(ss, dd), __fmul_rn(2.0f, cross));
    bool pred = !(sqr > r2);
    unsigned long long mask = __ballot(pred);
    if (!gotfirst && mask) { first = n0 + (__ffsll(mask) - 1); gotfirst = true; }
    if (pred) {
      int pos = have + __popcll(mask & ((1ull << lane) - 1ull));
      if (pos < NS) out[pos] = n;
    }
    have += __popcll(mask);
    if (have >= NS) break;
  }
  for (int slot = have + lane; slot < NS; slot += 64) out[slot] = first;
}

// ---------------- SA1 grouped MLP (3->64->64->128) + max over 32 samples ----------------
__global__ __launch_bounds__(256, 2) void sa1_mlp_kernel(
    const float* __restrict__ xyz, const float* __restrict__ nx1,
    const int* __restrict__ gidx,
    const float* __restrict__ W0f, const float* __restrict__ bf0,
    const float* __restrict__ WT1, const float* __restrict__ bf1,
    const float* __restrict__ WT2, const float* __restrict__ bf2,
    float* __restrict__ l1_pts) {
  __shared__ float XT[64 * 256];
  int t = threadIdx.x;
  int qi = t >> 5, sm = t & 31;
  int q = blockIdx.x * 8 + qi;
  int b = q >> 9, s = q & 511;
  int idx = gidx[(size_t)q * kNS1 + sm];
  float cx = nx1[b * 1536 + s];
  float cy = nx1[b * 1536 + 512 + s];
  float cz = nx1[b * 1536 + 1024 + s];
  const float* pb = xyz + (size_t)b * 3 * kN1;
  float f0 = pb[idx] - cx, f1 = pb[kN1 + idx] - cy, f2 = pb[2 * kN1 + idx] - cz;
  for (int j = 0; j < 64; ++j) {
    float4 w = *(const float4*)&W0f[j * 4];
    float v = fmaf(f2, w.z, fmaf(f1, w.y, fmaf(f0, w.x, bf0[j])));
    XT[j * 256 + t] = fmaxf(v, 0.0f);
  }
  __syncthreads();
  float acc[64];
#pragma unroll
  for (int j = 0; j < 64; ++j) acc[j] = bf1[j];
  for (int k = 0; k < 64; ++k) {
    float xk = XT[k * 256 + t];
    const float* wr = WT1 + k * 64;
#pragma unroll
    for (int j = 0; j < 64; ++j) acc[j] = fmaf(xk, wr[j], acc[j]);
  }
  __syncthreads();
#pragma unroll
  for (int j = 0; j < 64; ++j) XT[j * 256 + t] = fmaxf(acc[j], 0.0f);
  __syncthreads();
  float* outp = l1_pts + (size_t)q * 128;
  for (int jp = 0; jp < 2; ++jp) {
#pragma unroll
    for (int j = 0; j < 64; ++j) acc[j] = bf2[jp * 64 + j];
    for (int k = 0; k < 64; ++k) {
      float xk = XT[k * 256 + t];
      const float* wr = WT2 + k * 128 + jp * 64;
#pragma unroll
      for (int j = 0; j < 64; ++j) acc[j] = fmaf(xk, wr[j], acc[j]);
    }
#pragma unroll
    for (int j = 0; j < 64; ++j) {
      float m = fmaxf(acc[j], 0.0f);
      m = fmaxf(m, __shfl_xor(m, 1, 64));
      m = fmaxf(m, __shfl_xor(m, 2, 64));
      m = fmaxf(m, __shfl_xor(m, 4, 64));
      m = fmaxf(m, __shfl_xor(m, 8, 64));
      m = fmaxf(m, __shfl_xor(m, 16, 64));
      if (sm == 0) outp[jp * 64 + j] = m;
    }
  }
}

// ---------------- SA2 grouped MLP via bf16 MFMA ----------------
// Per block: one query q, M=64 samples. Activations bf16 in Abf[64][168] LDS
// (stride 168 avoids bank conflicts); layer1 K=160 (features 0..127, coords
// 128..130, zeros 131..159), layers 2/3 K=128. Weights pre-packed in fragment
// order (sa2pack_kernel). C-init carries fp32 bias; relu->bf16 between layers;
// layer3 max-pools in-register and writes fp32.
#define A_STR 168
__global__ __launch_bounds__(256) void sa2_mfma_kernel(
    const float* __restrict__ nx1, const float* __restrict__ l1_pts,
    const float* __restrict__ nx2, const int* __restrict__ gidx2,
    const short* __restrict__ P1, const float* __restrict__ bf1,
    const short* __restrict__ P2, const float* __restrict__ bf2,
    const short* __restrict__ P3, const float* __restrict__ bf3,
    float* __restrict__ l2_pts) {
  __shared__ short Abf[64 * A_STR];
  int t = threadIdx.x;
  int lane = t & 63;
  int wg = t >> 6;
  int q = blockIdx.x;
  int b = q >> 7, s = q & 127;
  int idx = gidx2[(size_t)q * kNS2 + lane];
  const float* pr = l1_pts + ((size_t)(b * kS1) + idx) * 128;
  // gather features -> bf16, cols 0..127 (row = sample = lane; wave covers 32 cols)
#pragma unroll
  for (int i = 0; i < 8; ++i) {
    float4 v = *(const float4*)&pr[wg * 32 + i * 4];
    unsigned lo = (unsigned)(unsigned short)f2bf(v.x) |
                  ((unsigned)(unsigned short)f2bf(v.y) << 16);
    unsigned hi = (unsigned)(unsigned short)f2bf(v.z) |
                  ((unsigned)(unsigned short)f2bf(v.w) << 16);
    *(uint2*)&Abf[lane * A_STR + wg * 32 + i * 4] = make_uint2(lo, hi);
  }
  if (wg == 0) {   // coords at cols 128..130, zero at 131
    float cx = nx2[b * 384 + s];
    float cy = nx2[b * 384 + 128 + s];
    float cz = nx2[b * 384 + 256 + s];
    float f0 = nx1[b * 1536 + idx] - cx;
    float f1 = nx1[b * 1536 + 512 + idx] - cy;
    float f2v = nx1[b * 1536 + 1024 + idx] - cz;
    unsigned lo = (unsigned)(unsigned short)f2bf(f0) |
                  ((unsigned)(unsigned short)f2bf(f1) << 16);
    unsigned hi = (unsigned)(unsigned short)f2bf(f2v);
    *(uint2*)&Abf[lane * A_STR + 128] = make_uint2(lo, hi);
  }
  if (wg == 1) {   // zeros at cols 132..159
#pragma unroll
    for (int j = 0; j < 7; ++j)
      *(uint2*)&Abf[lane * A_STR + 132 + j * 4] = make_uint2(0u, 0u);
  }
  __syncthreads();
  int lrow = lane & 15;          // row within 16 (A) / col within 16 (B,C)
  int lgrp = (lane >> 4) * 8;    // k-subgroup offset
  // ---------------- layer 1: K=160 (5 k-tiles), wave cols tn = 2wg,2wg+1
  bf16x8 B1[2][5];
#pragma unroll
  for (int c = 0; c < 2; ++c)
#pragma unroll
    for (int kt = 0; kt < 5; ++kt)
      B1[c][kt] = *(const bf16x8*)&P1[(((2 * wg + c) * 5 + kt) * 512 + lane * 8)];
  f32x4 acc1[4][2];
  {
    float b0 = bf1[(2 * wg + 0) * 16 + lrow];
    float b1v = bf1[(2 * wg + 1) * 16 + lrow];
#pragma unroll
    for (int r = 0; r < 4; ++r) {
      acc1[r][0] = (f32x4){b0, b0, b0, b0};
      acc1[r][1] = (f32x4){b1v, b1v, b1v, b1v};
    }
  }
#pragma unroll
  for (int r = 0; r < 4; ++r) {
    bf16x8 a[5];
#pragma unroll
    for (int kt = 0; kt < 5; ++kt)
      a[kt] = *(const bf16x8*)&Abf[(16 * r + lrow) * A_STR + kt * 32 + lgrp];
#pragma unroll
    for (int kt = 0; kt < 5; ++kt) {
      acc1[r][0] = __builtin_amdgcn_mfma_f32_16x16x32_bf16(a[kt], B1[0][kt], acc1[r][0], 0, 0, 0);
      acc1[r][1] = __builtin_amdgcn_mfma_f32_16x16x32_bf16(a[kt], B1[1][kt], acc1[r][1], 0, 0, 0);
    }
  }
  __syncthreads();   // all A reads complete
#pragma unroll
  for (int r = 0; r < 4; ++r)
#pragma unroll
    for (int c = 0; c < 2; ++c)
#pragma unroll
      for (int i = 0; i < 4; ++i) {
        int row = 16 * r + (lane >> 4) * 4 + i;
        int col = (2 * wg + c) * 16 + lrow;
        Abf[row * A_STR + col] = f2bf(fmaxf(acc1[r][c][i], 0.0f));
      }
  __syncthreads();
  // ---------------- layer 2: K=128 (4 k-tiles)
  bf16x8 B2[2][4];
#pragma unroll
  for (int c = 0; c < 2; ++c)
#pragma unroll
    for (int kt = 0; kt < 4; ++kt)
      B2[c][kt] = *(const bf16x8*)&P2[(((2 * wg + c) * 4 + kt) * 512 + lane * 8)];
  f32x4 acc2[4][2];
  {
    float b0 = bf2[(2 * wg + 0) * 16 + lrow];
    float b1v = bf2[(2 * wg + 1) * 16 + lrow];
#pragma unroll
    for (int r = 0; r < 4; ++r) {
      acc2[r][0] = (f32x4){b0, b0, b0, b0};
      acc2[r][1] = (f32x4){b1v, b1v, b1v, b1v};
    }
  }
#pragma unroll
  for (int r = 0; r < 4; ++r) {
    bf16x8 a[4];
#pragma unroll
    for (int kt = 0; kt < 4; ++kt)
      a[kt] = *(const bf16x8*)&Abf[(16 * r + lrow) * A_STR + kt * 32 + lgrp];
#pragma unroll
    for (int kt = 0; kt < 4; ++kt) {
      acc2[r][0] = __builtin_amdgcn_mfma_f32_16x16x32_bf16(a[kt], B2[0][kt], acc2[r][0], 0, 0, 0);
      acc2[r][1] = __builtin_amdgcn_mfma_f32_16x16x32_bf16(a[kt], B2[1][kt], acc2[r][1], 0, 0, 0);
    }
  }
  __syncthreads();
#pragma unroll
  for (int r = 0; r < 4; ++r)
#pragma unroll
    for (int c = 0; c < 2; ++c)
#pragma unroll
      for (int i = 0; i < 4; ++i) {
        int row = 16 * r + (lane >> 4) * 4 + i;
        int col = (2 * wg + c) * 16 + lrow;
        Abf[row * A_STR + col] = f2bf(fmaxf(acc2[r][c][i], 0.0f));
      }
  __syncthreads();
  // ---------------- layer 3: N=256 (wave cols tn = 4wg..4wg+3, two halves), K=128
  float* outp = l2_pts + (size_t)q * 256;
#pragma unroll
  for (int h = 0; h < 2; ++h) {
    int tn0 = 4 * wg + 2 * h;
    bf16x8 B3[2][4];
#pragma unroll
    for (int c = 0; c < 2; ++c)
#pragma unroll
      for (int kt = 0; kt < 4; ++kt)
        B3[c][kt] = *(const bf16x8*)&P3[(((tn0 + c) * 4 + kt) * 512 + lane * 8)];
    f32x4 acc3[4][2];
    {
      float b0 = bf3[(tn0 + 0) * 16 + lrow];
      float b1v = bf3[(tn0 + 1) * 16 + lrow];
#pragma unroll
      for (int r = 0; r < 4; ++r) {
        acc3[r][0] = (f32x4){b0, b0, b0, b0};
        acc3[r][1] = (f32x4){b1v, b1v, b1v, b1v};
      }
    }
#pragma unroll
    for (int r = 0; r < 4; ++r) {
      bf16x8 a[4];
#pragma unroll
      for (int kt = 0; kt < 4; ++kt)
        a[kt] = *(const bf16x8*)&Abf[(16 * r + lrow) * A_STR + kt * 32 + lgrp];
#pragma unroll
      for (int kt = 0; kt < 4; ++kt) {
        acc3[r][0] = __builtin_amdgcn_mfma_f32_16x16x32_bf16(a[kt], B3[0][kt], acc3[r][0], 0, 0, 0);
        acc3[r][1] = __builtin_amdgcn_mfma_f32_16x16x32_bf16(a[kt], B3[1][kt], acc3[r][1], 0, 0, 0);
      }
    }
    // relu + max over 64 rows, write cols (tn0..tn0+1)*16
#pragma unroll
    for (int c = 0; c < 2; ++c) {
      float m = 0.0f;   // relu floor
#pragma unroll
      for (int r = 0; r < 4; ++r)
#pragma unroll
        for (int i = 0; i < 4; ++i) m = fmaxf(m, acc3[r][c][i]);
      m = fmaxf(m, __shfl_xor(m, 16, 64));
      m = fmaxf(m, __shfl_xor(m, 32, 64));
      if (lane < 16) outp[(tn0 + c) * 16 + lane] = m;
    }
  }
}

// ---------------- SA3 (group-all): 259->256->512->1024 -> max over 128 ----------------
__global__ __launch_bounds__(256, 2) void sa3_passA_kernel(
    const float* __restrict__ nx2, const float* __restrict__ l2_pts,
    const float* __restrict__ WT, const float* __restrict__ bf,
    float* __restrict__ Y) {
  __shared__ float sF[16 * 260];
  int stile = blockIdx.x, t = threadIdx.x;
  int j = t;
  for (int i = t; i < 16 * 260; i += 256) {
    int row = stile * 16 + i / 260, k = i - (i / 260) * 260;
    int b = row >> 7, s = row & 127;
    float v;
    if (k < 3) v = nx2[b * 384 + k * 128 + s];
    else if (k < 259) v = l2_pts[(size_t)row * 256 + (k - 3)];
    else v = 0.0f;
    sF[i] = v;
  }
  __syncthreads();
  float acc[16];
  float bj = bf[j];
#pragma unroll
  for (int s = 0; s < 16; ++s) acc[s] = bj;
  for (int k = 0; k < 260; k += 4) {
    float w0 = WT[(size_t)k * 256 + j];
    float w1 = WT[(size_t)(k + 1) * 256 + j];
    float w2 = WT[(size_t)(k + 2) * 256 + j];
    float w3 = WT[(size_t)(k + 3) * 256 + j];
#pragma unroll
    for (int s = 0; s < 16; ++s) {
      const float4 fv = *(const float4*)&sF[s * 260 + k];
      acc[s] = fmaf(fv.x, w0, acc[s]);
      acc[s] = fmaf(fv.y, w1, acc[s]);
      acc[s] = fmaf(fv.z, w2, acc[s]);
      acc[s] = fmaf(fv.w, w3, acc[s]);
    }
  }
  float* yb = Y + (size_t)stile * 16 * 256 + j;
#pragma unroll
  for (int s = 0; s < 16; ++s) yb[(size_t)s * 256] = fmaxf(acc[s], 0.0f);
}

template <int KP>
__global__ __launch_bounds__(256, 2) void mlp_pass_kernel(
    const float* __restrict__ X, const float* __restrict__ WT, const float* __restrict__ bf,
    int O, float* __restrict__ Y) {
  __shared__ float sF[16 * KP];
  int stile = blockIdx.x, t = threadIdx.x;
  int j = blockIdx.y * 256 + t;
  const float* xb = X + (size_t)stile * 16 * KP;
  for (int i = t; i < 16 * KP; i += 256) sF[i] = xb[i];
  __syncthreads();
  float acc[16];
  float bj = bf[j];
#pragma unroll
  for (int s = 0; s < 16; ++s) acc[s] = bj;
  for (int k = 0; k < KP; k += 4) {
    float w0 = WT[(size_t)k * O + j];
    float w1 = WT[(size_t)(k + 1) * O + j];
    float w2 = WT[(size_t)(k + 2) * O + j];
    float w3 = WT[(size_t)(k + 3) * O + j];
#pragma unroll
    for (int s = 0; s < 16; ++s) {
      const float4 fv = *(const float4*)&sF[s * KP + k];
      acc[s] = fmaf(fv.x, w0, acc[s]);
      acc[s] = fmaf(fv.y, w1, acc[s]);
      acc[s] = fmaf(fv.z, w2, acc[s]);
      acc[s] = fmaf(fv.w, w3, acc[s]);
    }
  }
  float* yb = Y + (size_t)stile * 16 * O + j;
#pragma unroll
  for (int s = 0; s < 16; ++s) yb[(size_t)s * O] = fmaxf(acc[s], 0.0f);
}

__global__ __launch_bounds__(256, 2) void sa3_final_kernel(
    const float* __restrict__ X2g, const float* __restrict__ WTc, const float* __restrict__ bfc,
    float* __restrict__ out) {
  __shared__ float sF[16 * 512];
  int b = blockIdx.x, t = threadIdx.x;
  int j = blockIdx.y * 256 + t;
  float m = 0.0f;
  float bj = bfc[j];
  for (int st = 0; st < 8; ++st) {
    const float* xb = X2g + ((size_t)b * 128 + st * 16) * 512;
    for (int i = t; i < 16 * 512; i += 256) sF[i] = xb[i];
    __syncthreads();
    float acc[16];
#pragma unroll
    for (int s = 0; s < 16; ++s) acc[s] = bj;
    for (int k = 0; k < 512; k += 4) {
      float w0 = WTc[(size_t)k * 1024 + j];
      float w1 = WTc[(size_t)(k + 1) * 1024 + j];
      float w2 = WTc[(size_t)(k + 2) * 1024 + j];
      float w3 = WTc[(size_t)(k + 3) * 1024 + j];
#pragma unroll
      for (int s = 0; s < 16; ++s) {
        const float4 fv = *(const float4*)&sF[s * 512 + k];
        acc[s] = fmaf(fv.x, w0, acc[s]);
        acc[s] = fmaf(fv.y, w1, acc[s]);
        acc[s] = fmaf(fv.z, w2, acc[s]);
        acc[s] = fmaf(fv.w, w3, acc[s]);
      }
    }
#pragma unroll
    for (int s = 0; s < 16; ++s) m = fmaxf(m, fmaxf(acc[s], 0.0f));
    __syncthreads();
  }
  out[(size_t)b * 1024 + j] = m;
}

// ---------------- launch ----------------
extern "C" void kernel_launch(void* const* d_in, const int* in_sizes, int n_in,
                              void* d_out, int out_size, void* d_ws, size_t ws_size,
                              hipStream_t stream) {
  (void)in_sizes; (void)n_in; (void)out_size; (void)ws_size;
  const float* xyz = (const float*)d_in[0];
  auto WP = [&](int layer, int part) -> const float* {
    return (const float*)d_in[1 + layer * 4 + part];
  };
  float* wsf = (float*)d_ws;
  size_t cur = 0;
  auto alloc = [&](size_t n) { size_t o = cur; cur += (n + 63) & ~(size_t)63; return o; };
  size_t o_nx1 = alloc((size_t)kB * 3 * kS1);
  size_t o_nx2 = alloc((size_t)kB * 3 * kS2);
  size_t o_l1pts = alloc((size_t)kB * kS1 * 128);
  size_t o_l2pts = alloc((size_t)kB * kS2 * 256);
  size_t o_X1g = alloc((size_t)kB * kS2 * 256);
  size_t o_X2g = alloc((size_t)kB * kS2 * 512);
  size_t o_s1w0 = alloc(64 * 4), o_s1b0 = alloc(64);
  size_t o_s1w1 = alloc(64 * 64), o_s1b1 = alloc(64);
  size_t o_s1wt2 = alloc(64 * 128), o_s1b2 = alloc(128);
  size_t o_s2w1 = alloc(132 * 128), o_s2b1 = alloc(128);
  size_t o_s2wt2 = alloc(128 * 128), o_s2b2 = alloc(128);
  size_t o_s2w3 = alloc(128 * 256), o_s2b3 = alloc(256);
  size_t o_s3wtA = alloc(260 * 256), o_s3bA = alloc(256);
  size_t o_s3wtB = alloc(256 * 512), o_s3bB = alloc(512);
  size_t o_s3wtC = alloc(512 * 1024), o_s3bC = alloc(1024);
  size_t o_gidx1 = alloc((size_t)kB * kS1 * kNS1);
  size_t o_gidx2 = alloc((size_t)kB * kS2 * kNS2);
  size_t o_p1 = alloc(10240);   // 20480 bf16 shorts
  size_t o_p2 = alloc(8192);    // 16384 shorts
  size_t o_p3 = alloc(16384);   // 32768 shorts
  int* gidx1 = (int*)(wsf + o_gidx1);
  int* gidx2 = (int*)(wsf + o_gidx2);
  short* P1 = (short*)(wsf + o_p1);
  short* P2 = (short*)(wsf + o_p2);
  short* P3 = (short*)(wsf + o_p3);

  // fused fold of all 9 layers
  FoldPack fp;
  const int OKKp[9][3] = {{64, 3, 4},     {64, 64, 64},   {128, 64, 64},
                          {128, 131, 132}, {128, 128, 128}, {256, 128, 128},
                          {256, 259, 260}, {512, 256, 256}, {1024, 512, 512}};
  float* wouts[9] = {wsf + o_s1w0, wsf + o_s1w1, wsf + o_s1wt2,
                     wsf + o_s2w1, wsf + o_s2wt2, wsf + o_s2w3,
                     wsf + o_s3wtA, wsf + o_s3wtB, wsf + o_s3wtC};
  float* bouts[9] = {wsf + o_s1b0, wsf + o_s1b1, wsf + o_s1b2,
                     wsf + o_s2b1, wsf + o_s2b2, wsf + o_s2b3,
                     wsf + o_s3bA, wsf + o_s3bB, wsf + o_s3bC};
  const int nblk[9] = {1, 4, 8, 17, 16, 32, 65, 128, 512};
  fp.cum[0] = 0;
  for (int L = 0; L < 9; ++L) {
    fp.d[L].W = WP(L, 0);
    fp.d[L].b = WP(L, 1);
    fp.d[L].g = WP(L, 2);
    fp.d[L].bt = WP(L, 3);
    fp.d[L].Wout = wouts[L];
    fp.d[L].bout = bouts[L];
    fp.d[L].O = OKKp[L][0];
    fp.d[L].K = OKKp[L][1];
    fp.d[L].Kp = OKKp[L][2];
    fp.d[L].transposed = (L == 0) ? 0 : 1;
    fp.cum[L + 1] = fp.cum[L] + nblk[L];
  }
  foldall_kernel<<<fp.cum[9], 256, 0, stream>>>(fp);

  // pack sa2 weights into bf16 MFMA fragment order
  sa2pack_kernel<<<80, 256, 0, stream>>>(wsf + o_s2w1, P1, 128, 160, 1);
  sa2pack_kernel<<<64, 256, 0, stream>>>(wsf + o_s2wt2, P2, 128, 128, 0);
  sa2pack_kernel<<<128, 256, 0, stream>>>(wsf + o_s2w3, P3, 256, 128, 0);

  // SA1
  fps16_kernel<kN1, kS1, 256><<<kB, 256, 0, stream>>>(xyz, wsf + o_nx1);
  bq_kernel<kN1, kS1, kNS1><<<(kB * kS1) / 4, 256, 0, stream>>>(xyz, wsf + o_nx1, 0.04f, gidx1);
  sa1_mlp_kernel<<<(kB * kS1) / 8, 256, 0, stream>>>(
      xyz, wsf + o_nx1, gidx1,
      wsf + o_s1w0, wsf + o_s1b0, wsf + o_s1w1, wsf + o_s1b1, wsf + o_s1wt2, wsf + o_s1b2,
      wsf + o_l1pts);

  // SA2
  fps4_kernel<kS1, kS2, 128><<<kB, 128, 0, stream>>>(wsf + o_nx1, wsf + o_nx2);
  bq_kernel<kS1, kS2, kNS2><<<(kB * kS2) / 4, 256, 0, stream>>>(wsf + o_nx1, wsf + o_nx2, 0.16f, gidx2);
  sa2_mfma_kernel<<<kB * kS2, 256, 0, stream>>>(
      wsf + o_nx1, wsf + o_l1pts, wsf + o_nx2, gidx2,
      P1, wsf + o_s2b1, P2, wsf + o_s2b2, P3, wsf + o_s2b3,
      wsf + o_l2pts);

  // SA3 (group all)
  sa3_passA_kernel<<<256, 256, 0, stream>>>(wsf + o_nx2, wsf + o_l2pts,
                                            wsf + o_s3wtA, wsf + o_s3bA, wsf + o_X1g);
  mlp_pass_kernel<256><<<dim3(256, 2), 256, 0, stream>>>(wsf + o_X1g, wsf + o_s3wtB, wsf + o_s3bB, 512, wsf + o_X2g);
  sa3_final_kernel<<<dim3(kB, 4), 256, 0, stream>>>(wsf + o_X2g, wsf + o_s3wtC, wsf + o_s3bC, (float*)d_out);
}

// Round 19
// 921.071 us; speedup vs baseline: 1.6655x; 1.2296x over previous
//
#include <hip/hip_runtime.h>
#include <hip/hip_bf16.h>
#include <cstddef>
#include <math.h>

#define kB 32
#define kN1 4096
#define kS1 512
#define kNS1 32
#define kS2 128
#define kNS2 64

typedef short bf16x8 __attribute__((ext_vector_type(8)));
typedef float f32x4 __attribute__((ext_vector_type(4)));

__device__ __forceinline__ short f2bf(float f) {   // RTN-even fp32 -> bf16 bits
  unsigned u = __float_as_uint(f);
  unsigned r = (u + 0x7fffu + ((u >> 16) & 1u)) >> 16;
  return (short)r;
}

// ---------------- fused weight folding for all 9 layers ----------------
struct FoldDesc {
  const float *W, *b, *g, *bt;
  float *Wout, *bout;
  int O, K, Kp, transposed;
};
struct FoldPack {
  FoldDesc d[9];
  int cum[10];
};

__global__ __launch_bounds__(256) void foldall_kernel(FoldPack p) {
  int blk = blockIdx.x;
  int L = 0;
#pragma unroll
  for (int i = 0; i < 9; ++i)
    if (blk >= p.cum[i + 1]) L = i + 1;
  FoldDesc d = p.d[L];
  int nb = p.cum[L + 1] - p.cum[L];
  int tid = (blk - p.cum[L]) * 256 + threadIdx.x;
  int stride = nb * 256;
  float inv = 1.0f / sqrtf(1.0f + 1e-5f);
  for (int i = tid; i < d.O * d.Kp; i += stride) {
    int o = i / d.Kp, k = i - o * d.Kp;
    float s = d.g[o] * inv;
    float w = (k < d.K) ? d.W[o * d.K + k] * s : 0.0f;
    if (d.transposed) d.Wout[k * d.O + o] = w;
    else d.Wout[o * d.Kp + k] = w;
  }
  for (int o = tid; o < d.O; o += stride) {
    d.bout[o] = d.b[o] * (d.g[o] * inv) + d.bt[o];
  }
}

// Pack folded fp32 k-major weights [K][O] into bf16 MFMA B-fragment order.
// mode 1 = sa2 layer1 K-permutation (features->rows 3..130, coords->0..2, pad 0).
__global__ void sa2pack_kernel(const float* __restrict__ W, short* __restrict__ dst,
                               int O, int Kpad, int mode) {
  int e = blockIdx.x * 256 + threadIdx.x;
  int total = O * Kpad;
  if (e >= total) return;
  int i = e & 7, lane = (e >> 3) & 63, tile = e >> 9;
  int KT = Kpad / 32;
  int tn = tile / KT, tk = tile - tn * KT;
  int kk = tk * 32 + ((lane >> 4) & 3) * 8 + i;
  int n = tn * 16 + (lane & 15);
  float v;
  if (mode == 1) {
    int ok = (kk < 128) ? kk + 3 : ((kk < 131) ? kk - 128 : -1);
    v = (ok < 0) ? 0.0f : W[ok * O + n];
  } else {
    v = W[kk * O + n];
  }
  dst[e] = f2bf(v);
}

// Canonical CDNA wave64 f32 max via DPP (VALU pipe only).
__device__ __forceinline__ float wave_max_f32_nonneg(float x) {
#define DPP_MAXSTEP(CTRL)                                                     \
  {                                                                           \
    int o = __builtin_amdgcn_update_dpp(0, __float_as_int(x), (CTRL), 0xf, 0xf, true); \
    x = fmaxf(x, __int_as_float(o));                                          \
  }
  DPP_MAXSTEP(0x111)
  DPP_MAXSTEP(0x112)
  DPP_MAXSTEP(0x114)
  DPP_MAXSTEP(0x118)
  DPP_MAXSTEP(0x142)
  DPP_MAXSTEP(0x143)
#undef DPP_MAXSTEP
  return __int_as_float(__builtin_amdgcn_readlane(__float_as_int(x), 63));
}

__device__ __forceinline__ bool fps_pub_lane(float bestf, float wmax, int besti) {
  unsigned long long m = __ballot(bestf == wmax);
  if (__popcll(m) == 1) return bestf == wmax;
  unsigned long long mm = m;
  int bidx = 0x7fffffff;
  while (mm) {
    int l = __ffsll(mm) - 1;
    int bi = __shfl(besti, l, 64);
    bidx = min(bidx, bi);
    mm &= mm - 1;
  }
  return (bestf == wmax) && (besti == bidx);
}

// ---------------- farthest point sampling (R12 proven-best forms) ----------------
#define FPS_E(V, C, XV, YV, ZV, I)                                           \
  {                                                                          \
    float dx = __fsub_rn((XV), cx);                                          \
    float dy = __fsub_rn((YV), cy);                                          \
    float dz = __fsub_rn((ZV), cz);                                          \
    float d = fmaf(dz, dz, fmaf(dy, dy, __fmul_rn(dx, dx)));                 \
    float nd = fminf(dd##V.C, d);                                            \
    dd##V.C = nd;                                                            \
    if (nd > bestf) { bestf = nd; besti = (I); }                             \
  }

#define FPS_GRP(V, R)                                                        \
  {                                                                          \
    float4 xg = sx4[t + (R) * T];                                            \
    float4 yg = sy4[t + (R) * T];                                            \
    float4 zg = sz4[t + (R) * T];                                            \
    int ibase = 4 * (t + (R) * T);                                           \
    FPS_E(V, x, xg.x, yg.x, zg.x, ibase)                                     \
    FPS_E(V, y, xg.y, yg.y, zg.y, ibase + 1)                                 \
    FPS_E(V, z, xg.z, yg.z, zg.z, ibase + 2)                                 \
    FPS_E(V, w, xg.w, yg.w, zg.w, ibase + 3)                                 \
  }

template <int N, int NP, int T>
__global__ __launch_bounds__(T, 1) void fps16_kernel(const float* __restrict__ xyz,
                                                     float* __restrict__ nx) {
  static_assert(N == 16 * T, "fps16: need exactly 16 points per thread");
  constexpr int W = T / 64;
  __shared__ float4 sx4[N / 4], sy4[N / 4], sz4[N / 4];
  __shared__ unsigned long long skey[2][W];
  __shared__ int fid[NP];
  int b = blockIdx.x, t = threadIdx.x;
  int w = t >> 6;
  const float* base = xyz + (size_t)b * 3 * N;
  float* sxf = (float*)sx4;
  float* syf = (float*)sy4;
  float* szf = (float*)sz4;
  for (int i = t; i < N; i += T) sxf[i] = base[i];
  for (int i = t; i < N; i += T) syf[i] = base[N + i];
  for (int i = t; i < N; i += T) szf[i] = base[2 * N + i];
  float4 dd0, dd1, dd2, dd3;
  dd0 = dd1 = dd2 = dd3 = make_float4(1e10f, 1e10f, 1e10f, 1e10f);
  if (t < W) skey[0][t] = (t == 0) ? ~0ull : 0ull;
  if (t == 0) fid[0] = 0;
  int par = 0;
  __syncthreads();
  for (int it = 1; it < NP; ++it) {
    unsigned long long mk = skey[par][0];
#pragma unroll
    for (int w2 = 1; w2 < W; ++w2) {
      unsigned long long k2 = skey[par][w2];
      if (k2 > mk) mk = k2;
    }
    int wi = (int)(~(unsigned)mk);
    if (t == 0) fid[it - 1] = wi;
    float cx = sxf[wi], cy = syf[wi], cz = szf[wi];
    float bestf = -1.0f;
    int besti = 4 * t;
    FPS_GRP(0, 0)
    FPS_GRP(1, 1)
    FPS_GRP(2, 2)
    FPS_GRP(3, 3)
    float wmax = wave_max_f32_nonneg(bestf);
    if (fps_pub_lane(bestf, wmax, besti)) {
      skey[par ^ 1][w] =
          ((unsigned long long)__float_as_uint(wmax) << 32) | (unsigned)(~besti);
    }
    __syncthreads();
    par ^= 1;
  }
  {
    unsigned long long mk = skey[par][0];
#pragma unroll
    for (int w2 = 1; w2 < W; ++w2) {
      unsigned long long k2 = skey[par][w2];
      if (k2 > mk) mk = k2;
    }
    if (t == 0) fid[NP - 1] = (int)(~(unsigned)mk);
  }
  __syncthreads();
  for (int s = t; s < NP; s += T) {
    int f = fid[s];
    nx[(size_t)b * 3 * NP + s] = sxf[f];
    nx[(size_t)b * 3 * NP + NP + s] = syf[f];
    nx[(size_t)b * 3 * NP + 2 * NP + s] = szf[f];
  }
}

#define FPS_STEP(V, C, IDXOFF)                                               \
  {                                                                          \
    float dx = __fsub_rn(px##V.C, cx);                                       \
    float dy = __fsub_rn(py##V.C, cy);                                       \
    float dz = __fsub_rn(pz##V.C, cz);                                       \
    float d = fmaf(dz, dz, fmaf(dy, dy, __fmul_rn(dx, dx)));                 \
    float nd = fminf(dd##V.C, d);                                            \
    dd##V.C = nd;                                                            \
    if (nd > bestf) {                                                        \
      bestf = nd; besti = t + (IDXOFF); bx = px##V.C; by = py##V.C; bz = pz##V.C; \
    }                                                                        \
  }

#define FPS_LD4(arr, src, off) \
  arr = make_float4((src)[(off)], (src)[(off) + T], (src)[(off) + 2 * T], (src)[(off) + 3 * T])

template <int N, int NP, int T>
__global__ __launch_bounds__(T, 1) void fps4_kernel(const float* __restrict__ xyz,
                                                    float* __restrict__ nx) {
  static_assert(N == 4 * T, "fps4: need exactly 4 points per thread");
  constexpr int W = T / 64;
  __shared__ float4 sslot[2][W][2];
  __shared__ int fid[NP];
  int b = blockIdx.x, t = threadIdx.x;
  int w = t >> 6;
  const float* base = xyz + (size_t)b * 3 * N;
  float4 px0, py0, pz0, dd0;
  FPS_LD4(px0, base, t);
  FPS_LD4(py0, base + N, t);
  FPS_LD4(pz0, base + 2 * N, t);
  dd0 = make_float4(1e10f, 1e10f, 1e10f, 1e10f);
  if (t == 0) {
    fid[0] = 0;
    unsigned long long k0 = ~0ull;
    sslot[0][0][0] = make_float4(__uint_as_float((unsigned)k0),
                                 __uint_as_float((unsigned)(k0 >> 32)), px0.x, py0.x);
    sslot[0][0][1] = make_float4(pz0.x, 0.0f, 0.0f, 0.0f);
  }
  if (t >= 64 && (t & 63) == 0) {
    sslot[0][w][0] = make_float4(0.0f, 0.0f, 0.0f, 0.0f);
    sslot[0][w][1] = make_float4(0.0f, 0.0f, 0.0f, 0.0f);
  }
  int par = 0;
  __syncthreads();
  for (int it = 1; it < NP; ++it) {
    float4 q0 = sslot[par][0][0];
    float4 q1 = sslot[par][0][1];
    unsigned long long mk =
        ((unsigned long long)__float_as_uint(q0.y) << 32) | __float_as_uint(q0.x);
    float cx = q0.z, cy = q0.w, cz = q1.x;
#pragma unroll
    for (int w2 = 1; w2 < W; ++w2) {
      float4 p0 = sslot[par][w2][0];
      float4 p1 = sslot[par][w2][1];
      unsigned long long k2 =
          ((unsigned long long)__float_as_uint(p0.y) << 32) | __float_as_uint(p0.x);
      if (k2 > mk) { mk = k2; cx = p0.z; cy = p0.w; cz = p1.x; }
    }
    if (t == 0) fid[it - 1] = (int)(~(unsigned)mk);
    float bestf = -1.0f;
    int besti = t;
    float bx = px0.x, by = py0.x, bz = pz0.x;
    FPS_STEP(0, x, 0) FPS_STEP(0, y, T) FPS_STEP(0, z, 2 * T) FPS_STEP(0, w, 3 * T)
    float wmax = wave_max_f32_nonneg(bestf);
    if (fps_pub_lane(bestf, wmax, besti)) {
      unsigned long long key =
          ((unsigned long long)__float_as_uint(wmax) << 32) | (unsigned)(~besti);
      sslot[par ^ 1][w][0] = make_float4(__uint_as_float((unsigned)key),
                                         __uint_as_float((unsigned)(key >> 32)), bx, by);
      sslot[par ^ 1][w][1] = make_float4(bz, 0.0f, 0.0f, 0.0f);
    }
    __syncthreads();
    par ^= 1;
  }
  {
    float4 q0 = sslot[par][0][0];
    unsigned long long mk =
        ((unsigned long long)__float_as_uint(q0.y) << 32) | __float_as_uint(q0.x);
#pragma unroll
    for (int w2 = 1; w2 < W; ++w2) {
      float4 p0 = sslot[par][w2][0];
      unsigned long long k2 =
          ((unsigned long long)__float_as_uint(p0.y) << 32) | __float_as_uint(p0.x);
      if (k2 > mk) mk = k2;
    }
    if (t == 0) fid[NP - 1] = (int)(~(unsigned)mk);
  }
  __syncthreads();
  for (int s = t; s < NP; s += T) {
    int f = fid[s];
    nx[(size_t)b * 3 * NP + s] = base[f];
    nx[(size_t)b * 3 * NP + NP + s] = base[N + f];
    nx[(size_t)b * 3 * NP + 2 * NP + s] = base[2 * N + f];
  }
}

// ---------------- ball query ----------------
template <int NPTS, int NQ, int NS>
__global__ void bq_kernel(const float* __restrict__ pts, const float* __restrict__ qry,
                          float r2, int* __restrict__ gidx) {
  int gw = (blockIdx.x * blockDim.x + threadIdx.x) >> 6;
  int lane = threadIdx.x & 63;
  if (gw >= kB * NQ) return;
  int b = gw / NQ, s = gw - b * NQ;
  const float* pb = pts + (size_t)b * 3 * NPTS;
  float cx = qry[(size_t)b * 3 * NQ + s];
  float cy = qry[(size_t)b * 3 * NQ + NQ + s];
  float cz = qry[(size_t)b * 3 * NQ + 2 * NQ + s];
  float ss = fmaf(cz, cz, fmaf(cy, cy, __fmul_rn(cx, cx)));
  int* out = gidx + (size_t)gw * NS;
  int have = 0, first = 0;
  bool gotfirst = false;
  for (int n0 = 0; n0 < NPTS; n0 += 64) {
    int n = n0 + lane;
    float x = pb[n], y = pb[NPTS + n], z = pb[2 * NPTS + n];
    float dd = fmaf(z, z, fmaf(y, y, __fmul_rn(x, x)));
    float cross = fmaf(cz, z, fmaf(cy, y, __fmul_rn(cx, x)));
    float sqr = __fsub_rn(__fadd_rn(ss, dd), __fmul_rn(2.0f, cross));
    bool pred = !(sqr > r2);
    unsigned long long mask = __ballot(pred);
    if (!gotfirst && mask) { first = n0 + (__ffsll(mask) - 1); gotfirst = true; }
    if (pred) {
      int pos = have + __popcll(mask & ((1ull << lane) - 1ull));
      if (pos < NS) out[pos] = n;
    }
    have += __popcll(mask);
    if (have >= NS) break;
  }
  for (int slot = have + lane; slot < NS; slot += 64) out[slot] = first;
}

// ---------------- SA1 grouped MLP via bf16 MFMA ----------------
// Block = 2 queries, M=64 rows (row = qi*32 + sample). Layer1 (3->64) fp32 VALU
// -> relu -> bf16 into Abf[64][72]. Layers 2 (K=64,N=64) and 3 (K=64,N=128) as
// 16x16x32 bf16 MFMA with pre-packed weights; fp32 bias via C-init; per-query
// max-pool in-register (r-tiles {0,1} / {2,3}); relu via 0-init floor.
#define A1_STR 72
__global__ __launch_bounds__(256) void sa1_mfma_kernel(
    const float* __restrict__ xyz, const float* __restrict__ nx1,
    const int* __restrict__ gidx,
    const float* __restrict__ W0f, const float* __restrict__ bf0,   // [64][4], [64]
    const short* __restrict__ Q1, const float* __restrict__ bf1,    // packed [4][2][512]
    const short* __restrict__ Q2, const float* __restrict__ bf2,    // packed [8][2][512]
    float* __restrict__ l1_pts) {
  __shared__ short Abf[64 * A1_STR];
  int t = threadIdx.x;
  int lane = t & 63;
  int wg = t >> 6;
  int q0 = blockIdx.x * 2;
  // layer 1: thread handles row = t&63, cols wg*16..+15
  {
    int row = t & 63;
    int q = q0 + (row >> 5);
    int b = q >> 9, s = q & 511;
    int sm = row & 31;
    int idx = gidx[(size_t)q * kNS1 + sm];
    float cx = nx1[b * 1536 + s];
    float cy = nx1[b * 1536 + 512 + s];
    float cz = nx1[b * 1536 + 1024 + s];
    const float* pb = xyz + (size_t)b * 3 * kN1;
    float f0 = pb[idx] - cx, f1 = pb[kN1 + idx] - cy, f2v = pb[2 * kN1 + idx] - cz;
#pragma unroll
    for (int j = 0; j < 16; ++j) {
      int col = wg * 16 + j;
      float4 w = *(const float4*)&W0f[col * 4];
      float v = fmaf(f2v, w.z, fmaf(f1, w.y, fmaf(f0, w.x, bf0[col])));
      Abf[row * A1_STR + col] = f2bf(fmaxf(v, 0.0f));
    }
  }
  __syncthreads();
  int lrow = lane & 15;
  int lgrp = (lane >> 4) * 8;
  // layer 2: N=64, tile tn = wg; K=64 (2 k-tiles)
  {
    bf16x8 B0 = *(const bf16x8*)&Q1[(wg * 2 + 0) * 512 + lane * 8];
    bf16x8 B1 = *(const bf16x8*)&Q1[(wg * 2 + 1) * 512 + lane * 8];
    f32x4 acc[4];
    float bb = bf1[wg * 16 + lrow];
#pragma unroll
    for (int r = 0; r < 4; ++r) acc[r] = (f32x4){bb, bb, bb, bb};
#pragma unroll
    for (int r = 0; r < 4; ++r) {
      bf16x8 a0 = *(const bf16x8*)&Abf[(16 * r + lrow) * A1_STR + lgrp];
      bf16x8 a1 = *(const bf16x8*)&Abf[(16 * r + lrow) * A1_STR + 32 + lgrp];
      acc[r] = __builtin_amdgcn_mfma_f32_16x16x32_bf16(a0, B0, acc[r], 0, 0, 0);
      acc[r] = __builtin_amdgcn_mfma_f32_16x16x32_bf16(a1, B1, acc[r], 0, 0, 0);
    }
    __syncthreads();
#pragma unroll
    for (int r = 0; r < 4; ++r)
#pragma unroll
      for (int i = 0; i < 4; ++i) {
        int row = 16 * r + (lane >> 4) * 4 + i;
        Abf[row * A1_STR + wg * 16 + lrow] = f2bf(fmaxf(acc[r][i], 0.0f));
      }
    __syncthreads();
  }
  // layer 3: N=128, tiles tn = 2wg, 2wg+1; K=64; then max-pool per query
  {
    bf16x8 B3[2][2];
#pragma unroll
    for (int c = 0; c < 2; ++c)
#pragma unroll
      for (int kt = 0; kt < 2; ++kt)
        B3[c][kt] = *(const bf16x8*)&Q2[((2 * wg + c) * 2 + kt) * 512 + lane * 8];
    f32x4 acc[4][2];
#pragma unroll
    for (int c = 0; c < 2; ++c) {
      float bb = bf2[(2 * wg + c) * 16 + lrow];
#pragma unroll
      for (int r = 0; r < 4; ++r) acc[r][c] = (f32x4){bb, bb, bb, bb};
    }
#pragma unroll
    for (int r = 0; r < 4; ++r) {
      bf16x8 a0 = *(const bf16x8*)&Abf[(16 * r + lrow) * A1_STR + lgrp];
      bf16x8 a1 = *(const bf16x8*)&Abf[(16 * r + lrow) * A1_STR + 32 + lgrp];
#pragma unroll
      for (int c = 0; c < 2; ++c) {
        acc[r][c] = __builtin_amdgcn_mfma_f32_16x16x32_bf16(a0, B3[c][0], acc[r][c], 0, 0, 0);
        acc[r][c] = __builtin_amdgcn_mfma_f32_16x16x32_bf16(a1, B3[c][1], acc[r][c], 0, 0, 0);
      }
    }
#pragma unroll
    for (int c = 0; c < 2; ++c) {
      float m0 = 0.0f, m1 = 0.0f;   // relu floor
#pragma unroll
      for (int i = 0; i < 4; ++i) {
        m0 = fmaxf(m0, fmaxf(acc[0][c][i], acc[1][c][i]));   // query 0: rows 0..31
        m1 = fmaxf(m1, fmaxf(acc[2][c][i], acc[3][c][i]));   // query 1: rows 32..63
      }
      m0 = fmaxf(m0, __shfl_xor(m0, 16, 64));
      m0 = fmaxf(m0, __shfl_xor(m0, 32, 64));
      m1 = fmaxf(m1, __shfl_xor(m1, 16, 64));
      m1 = fmaxf(m1, __shfl_xor(m1, 32, 64));
      int col = (2 * wg + c) * 16 + lrow;
      if (lane < 16) {
        l1_pts[(size_t)q0 * 128 + col] = m0;
        l1_pts[(size_t)(q0 + 1) * 128 + col] = m1;
      }
    }
  }
}

// ---------------- SA2 grouped MLP via bf16 MFMA ----------------
#define A_STR 168
__global__ __launch_bounds__(256) void sa2_mfma_kernel(
    const float* __restrict__ nx1, const float* __restrict__ l1_pts,
    const float* __restrict__ nx2, const int* __restrict__ gidx2,
    const short* __restrict__ P1, const float* __restrict__ bf1,
    const short* __restrict__ P2, const float* __restrict__ bf2,
    const short* __restrict__ P3, const float* __restrict__ bf3,
    float* __restrict__ l2_pts) {
  __shared__ short Abf[64 * A_STR];
  int t = threadIdx.x;
  int lane = t & 63;
  int wg = t >> 6;
  int q = blockIdx.x;
  int b = q >> 7, s = q & 127;
  int idx = gidx2[(size_t)q * kNS2 + lane];
  const float* pr = l1_pts + ((size_t)(b * kS1) + idx) * 128;
#pragma unroll
  for (int i = 0; i < 8; ++i) {
    float4 v = *(const float4*)&pr[wg * 32 + i * 4];
    unsigned lo = (unsigned)(unsigned short)f2bf(v.x) |
                  ((unsigned)(unsigned short)f2bf(v.y) << 16);
    unsigned hi = (unsigned)(unsigned short)f2bf(v.z) |
                  ((unsigned)(unsigned short)f2bf(v.w) << 16);
    *(uint2*)&Abf[lane * A_STR + wg * 32 + i * 4] = make_uint2(lo, hi);
  }
  if (wg == 0) {
    float cx = nx2[b * 384 + s];
    float cy = nx2[b * 384 + 128 + s];
    float cz = nx2[b * 384 + 256 + s];
    float f0 = nx1[b * 1536 + idx] - cx;
    float f1 = nx1[b * 1536 + 512 + idx] - cy;
    float f2v = nx1[b * 1536 + 1024 + idx] - cz;
    unsigned lo = (unsigned)(unsigned short)f2bf(f0) |
                  ((unsigned)(unsigned short)f2bf(f1) << 16);
    unsigned hi = (unsigned)(unsigned short)f2bf(f2v);
    *(uint2*)&Abf[lane * A_STR + 128] = make_uint2(lo, hi);
  }
  if (wg == 1) {
#pragma unroll
    for (int j = 0; j < 7; ++j)
      *(uint2*)&Abf[lane * A_STR + 132 + j * 4] = make_uint2(0u, 0u);
  }
  __syncthreads();
  int lrow = lane & 15;
  int lgrp = (lane >> 4) * 8;
  // layer 1: K=160 (5 k-tiles)
  bf16x8 B1[2][5];
#pragma unroll
  for (int c = 0; c < 2; ++c)
#pragma unroll
    for (int kt = 0; kt < 5; ++kt)
      B1[c][kt] = *(const bf16x8*)&P1[(((2 * wg + c) * 5 + kt) * 512 + lane * 8)];
  f32x4 acc1[4][2];
  {
    float b0 = bf1[(2 * wg + 0) * 16 + lrow];
    float b1v = bf1[(2 * wg + 1) * 16 + lrow];
#pragma unroll
    for (int r = 0; r < 4; ++r) {
      acc1[r][0] = (f32x4){b0, b0, b0, b0};
      acc1[r][1] = (f32x4){b1v, b1v, b1v, b1v};
    }
  }
#pragma unroll
  for (int r = 0; r < 4; ++r) {
    bf16x8 a[5];
#pragma unroll
    for (int kt = 0; kt < 5; ++kt)
      a[kt] = *(const bf16x8*)&Abf[(16 * r + lrow) * A_STR + kt * 32 + lgrp];
#pragma unroll
    for (int kt = 0; kt < 5; ++kt) {
      acc1[r][0] = __builtin_amdgcn_mfma_f32_16x16x32_bf16(a[kt], B1[0][kt], acc1[r][0], 0, 0, 0);
      acc1[r][1] = __builtin_amdgcn_mfma_f32_16x16x32_bf16(a[kt], B1[1][kt], acc1[r][1], 0, 0, 0);
    }
  }
  __syncthreads();
#pragma unroll
  for (int r = 0; r < 4; ++r)
#pragma unroll
    for (int c = 0; c < 2; ++c)
#pragma unroll
      for (int i = 0; i < 4; ++i) {
        int row = 16 * r + (lane >> 4) * 4 + i;
        int col = (2 * wg + c) * 16 + lrow;
        Abf[row * A_STR + col] = f2bf(fmaxf(acc1[r][c][i], 0.0f));
      }
  __syncthreads();
  // layer 2: K=128 (4 k-tiles)
  bf16x8 B2[2][4];
#pragma unroll
  for (int c = 0; c < 2; ++c)
#pragma unroll
    for (int kt = 0; kt < 4; ++kt)
      B2[c][kt] = *(const bf16x8*)&P2[(((2 * wg + c) * 4 + kt) * 512 + lane * 8)];
  f32x4 acc2[4][2];
  {
    float b0 = bf2[(2 * wg + 0) * 16 + lrow];
    float b1v = bf2[(2 * wg + 1) * 16 + lrow];
#pragma unroll
    for (int r = 0; r < 4; ++r) {
      acc2[r][0] = (f32x4){b0, b0, b0, b0};
      acc2[r][1] = (f32x4){b1v, b1v, b1v, b1v};
    }
  }
#pragma unroll
  for (int r = 0; r < 4; ++r) {
    bf16x8 a[4];
#pragma unroll
    for (int kt = 0; kt < 4; ++kt)
      a[kt] = *(const bf16x8*)&Abf[(16 * r + lrow) * A_STR + kt * 32 + lgrp];
#pragma unroll
    for (int kt = 0; kt < 4; ++kt) {
      acc2[r][0] = __builtin_amdgcn_mfma_f32_16x16x32_bf16(a[kt], B2[0][kt], acc2[r][0], 0, 0, 0);
      acc2[r][1] = __builtin_amdgcn_mfma_f32_16x16x32_bf16(a[kt], B2[1][kt], acc2[r][1], 0, 0, 0);
    }
  }
  __syncthreads();
#pragma unroll
  for (int r = 0; r < 4; ++r)
#pragma unroll
    for (int c = 0; c < 2; ++c)
#pragma unroll
      for (int i = 0; i < 4; ++i) {
        int row = 16 * r + (lane >> 4) * 4 + i;
        int col = (2 * wg + c) * 16 + lrow;
        Abf[row * A_STR + col] = f2bf(fmaxf(acc2[r][c][i], 0.0f));
      }
  __syncthreads();
  // layer 3: N=256, K=128; max over 64 rows
  float* outp = l2_pts + (size_t)q * 256;
#pragma unroll
  for (int h = 0; h < 2; ++h) {
    int tn0 = 4 * wg + 2 * h;
    bf16x8 B3[2][4];
#pragma unroll
    for (int c = 0; c < 2; ++c)
#pragma unroll
      for (int kt = 0; kt < 4; ++kt)
        B3[c][kt] = *(const bf16x8*)&P3[(((tn0 + c) * 4 + kt) * 512 + lane * 8)];
    f32x4 acc3[4][2];
    {
      float b0 = bf3[(tn0 + 0) * 16 + lrow];
      float b1v = bf3[(tn0 + 1) * 16 + lrow];
#pragma unroll
      for (int r = 0; r < 4; ++r) {
        acc3[r][0] = (f32x4){b0, b0, b0, b0};
        acc3[r][1] = (f32x4){b1v, b1v, b1v, b1v};
      }
    }
#pragma unroll
    for (int r = 0; r < 4; ++r) {
      bf16x8 a[4];
#pragma unroll
      for (int kt = 0; kt < 4; ++kt)
        a[kt] = *(const bf16x8*)&Abf[(16 * r + lrow) * A_STR + kt * 32 + lgrp];
#pragma unroll
      for (int kt = 0; kt < 4; ++kt) {
        acc3[r][0] = __builtin_amdgcn_mfma_f32_16x16x32_bf16(a[kt], B3[0][kt], acc3[r][0], 0, 0, 0);
        acc3[r][1] = __builtin_amdgcn_mfma_f32_16x16x32_bf16(a[kt], B3[1][kt], acc3[r][1], 0, 0, 0);
      }
    }
#pragma unroll
    for (int c = 0; c < 2; ++c) {
      float m = 0.0f;
#pragma unroll
      for (int r = 0; r < 4; ++r)
#pragma unroll
        for (int i = 0; i < 4; ++i) m = fmaxf(m, acc3[r][c][i]);
      m = fmaxf(m, __shfl_xor(m, 16, 64));
      m = fmaxf(m, __shfl_xor(m, 32, 64));
      if (lane < 16) outp[(tn0 + c) * 16 + lane] = m;
    }
  }
}

// ---------------- SA3 (group-all): 259->256->512->1024 -> max over 128 ----------------
__global__ __launch_bounds__(256, 2) void sa3_passA_kernel(
    const float* __restrict__ nx2, const float* __restrict__ l2_pts,
    const float* __restrict__ WT, const float* __restrict__ bf,
    float* __restrict__ Y) {
  __shared__ float sF[16 * 260];
  int stile = blockIdx.x, t = threadIdx.x;
  int j = t;
  for (int i = t; i < 16 * 260; i += 256) {
    int row = stile * 16 + i / 260, k = i - (i / 260) * 260;
    int b = row >> 7, s = row & 127;
    float v;
    if (k < 3) v = nx2[b * 384 + k * 128 + s];
    else if (k < 259) v = l2_pts[(size_t)row * 256 + (k - 3)];
    else v = 0.0f;
    sF[i] = v;
  }
  __syncthreads();
  float acc[16];
  float bj = bf[j];
#pragma unroll
  for (int s = 0; s < 16; ++s) acc[s] = bj;
  for (int k = 0; k < 260; k += 4) {
    float w0 = WT[(size_t)k * 256 + j];
    float w1 = WT[(size_t)(k + 1) * 256 + j];
    float w2 = WT[(size_t)(k + 2) * 256 + j];
    float w3 = WT[(size_t)(k + 3) * 256 + j];
#pragma unroll
    for (int s = 0; s < 16; ++s) {
      const float4 fv = *(const float4*)&sF[s * 260 + k];
      acc[s] = fmaf(fv.x, w0, acc[s]);
      acc[s] = fmaf(fv.y, w1, acc[s]);
      acc[s] = fmaf(fv.z, w2, acc[s]);
      acc[s] = fmaf(fv.w, w3, acc[s]);
    }
  }
  float* yb = Y + (size_t)stile * 16 * 256 + j;
#pragma unroll
  for (int s = 0; s < 16; ++s) yb[(size_t)s * 256] = fmaxf(acc[s], 0.0f);
}

template <int KP>
__global__ __launch_bounds__(256, 2) void mlp_pass_kernel(
    const float* __restrict__ X, const float* __restrict__ WT, const float* __restrict__ bf,
    int O, float* __restrict__ Y) {
  __shared__ float sF[16 * KP];
  int stile = blockIdx.x, t = threadIdx.x;
  int j = blockIdx.y * 256 + t;
  const float* xb = X + (size_t)stile * 16 * KP;
  for (int i = t; i < 16 * KP; i += 256) sF[i] = xb[i];
  __syncthreads();
  float acc[16];
  float bj = bf[j];
#pragma unroll
  for (int s = 0; s < 16; ++s) acc[s] = bj;
  for (int k = 0; k < KP; k += 4) {
    float w0 = WT[(size_t)k * O + j];
    float w1 = WT[(size_t)(k + 1) * O + j];
    float w2 = WT[(size_t)(k + 2) * O + j];
    float w3 = WT[(size_t)(k + 3) * O + j];
#pragma unroll
    for (int s = 0; s < 16; ++s) {
      const float4 fv = *(const float4*)&sF[s * KP + k];
      acc[s] = fmaf(fv.x, w0, acc[s]);
      acc[s] = fmaf(fv.y, w1, acc[s]);
      acc[s] = fmaf(fv.z, w2, acc[s]);
      acc[s] = fmaf(fv.w, w3, acc[s]);
    }
  }
  float* yb = Y + (size_t)stile * 16 * O + j;
#pragma unroll
  for (int s = 0; s < 16; ++s) yb[(size_t)s * O] = fmaxf(acc[s], 0.0f);
}

__global__ __launch_bounds__(256, 2) void sa3_final_kernel(
    const float* __restrict__ X2g, const float* __restrict__ WTc, const float* __restrict__ bfc,
    float* __restrict__ out) {
  __shared__ float sF[16 * 512];
  int b = blockIdx.x, t = threadIdx.x;
  int j = blockIdx.y * 256 + t;
  float m = 0.0f;
  float bj = bfc[j];
  for (int st = 0; st < 8; ++st) {
    const float* xb = X2g + ((size_t)b * 128 + st * 16) * 512;
    for (int i = t; i < 16 * 512; i += 256) sF[i] = xb[i];
    __syncthreads();
    float acc[16];
#pragma unroll
    for (int s = 0; s < 16; ++s) acc[s] = bj;
    for (int k = 0; k < 512; k += 4) {
      float w0 = WTc[(size_t)k * 1024 + j];
      float w1 = WTc[(size_t)(k + 1) * 1024 + j];
      float w2 = WTc[(size_t)(k + 2) * 1024 + j];
      float w3 = WTc[(size_t)(k + 3) * 1024 + j];
#pragma unroll
      for (int s = 0; s < 16; ++s) {
        const float4 fv = *(const float4*)&sF[s * 512 + k];
        acc[s] = fmaf(fv.x, w0, acc[s]);
        acc[s] = fmaf(fv.y, w1, acc[s]);
        acc[s] = fmaf(fv.z, w2, acc[s]);
        acc[s] = fmaf(fv.w, w3, acc[s]);
      }
    }
#pragma unroll
    for (int s = 0; s < 16; ++s) m = fmaxf(m, fmaxf(acc[s], 0.0f));
    __syncthreads();
  }
  out[(size_t)b * 1024 + j] = m;
}

// ---------------- launch ----------------
extern "C" void kernel_launch(void* const* d_in, const int* in_sizes, int n_in,
                              void* d_out, int out_size, void* d_ws, size_t ws_size,
                              hipStream_t stream) {
  (void)in_sizes; (void)n_in; (void)out_size; (void)ws_size;
  const float* xyz = (const float*)d_in[0];
  auto WP = [&](int layer, int part) -> const float* {
    return (const float*)d_in[1 + layer * 4 + part];
  };
  float* wsf = (float*)d_ws;
  size_t cur = 0;
  auto alloc = [&](size_t n) { size_t o = cur; cur += (n + 63) & ~(size_t)63; return o; };
  size_t o_nx1 = alloc((size_t)kB * 3 * kS1);
  size_t o_nx2 = alloc((size_t)kB * 3 * kS2);
  size_t o_l1pts = alloc((size_t)kB * kS1 * 128);
  size_t o_l2pts = alloc((size_t)kB * kS2 * 256);
  size_t o_X1g = alloc((size_t)kB * kS2 * 256);
  size_t o_X2g = alloc((size_t)kB * kS2 * 512);
  size_t o_s1w0 = alloc(64 * 4), o_s1b0 = alloc(64);
  size_t o_s1w1 = alloc(64 * 64), o_s1b1 = alloc(64);
  size_t o_s1wt2 = alloc(64 * 128), o_s1b2 = alloc(128);
  size_t o_s2w1 = alloc(132 * 128), o_s2b1 = alloc(128);
  size_t o_s2wt2 = alloc(128 * 128), o_s2b2 = alloc(128);
  size_t o_s2w3 = alloc(128 * 256), o_s2b3 = alloc(256);
  size_t o_s3wtA = alloc(260 * 256), o_s3bA = alloc(256);
  size_t o_s3wtB = alloc(256 * 512), o_s3bB = alloc(512);
  size_t o_s3wtC = alloc(512 * 1024), o_s3bC = alloc(1024);
  size_t o_gidx1 = alloc((size_t)kB * kS1 * kNS1);
  size_t o_gidx2 = alloc((size_t)kB * kS2 * kNS2);
  size_t o_p1 = alloc(10240);   // 20480 bf16 shorts
  size_t o_p2 = alloc(8192);    // 16384 shorts
  size_t o_p3 = alloc(16384);   // 32768 shorts
  size_t o_q1 = alloc(2048);    // 4096 shorts  (sa1 layer2)
  size_t o_q2 = alloc(4096);    // 8192 shorts  (sa1 layer3)
  int* gidx1 = (int*)(wsf + o_gidx1);
  int* gidx2 = (int*)(wsf + o_gidx2);
  short* P1 = (short*)(wsf + o_p1);
  short* P2 = (short*)(wsf + o_p2);
  short* P3 = (short*)(wsf + o_p3);
  short* Q1 = (short*)(wsf + o_q1);
  short* Q2 = (short*)(wsf + o_q2);

  // fused fold of all 9 layers
  FoldPack fp;
  const int OKKp[9][3] = {{64, 3, 4},     {64, 64, 64},   {128, 64, 64},
                          {128, 131, 132}, {128, 128, 128}, {256, 128, 128},
                          {256, 259, 260}, {512, 256, 256}, {1024, 512, 512}};
  float* wouts[9] = {wsf + o_s1w0, wsf + o_s1w1, wsf + o_s1wt2,
                     wsf + o_s2w1, wsf + o_s2wt2, wsf + o_s2w3,
                     wsf + o_s3wtA, wsf + o_s3wtB, wsf + o_s3wtC};
  float* bouts[9] = {wsf + o_s1b0, wsf + o_s1b1, wsf + o_s1b2,
                     wsf + o_s2b1, wsf + o_s2b2, wsf + o_s2b3,
                     wsf + o_s3bA, wsf + o_s3bB, wsf + o_s3bC};
  const int nblk[9] = {1, 4, 8, 17, 16, 32, 65, 128, 512};
  fp.cum[0] = 0;
  for (int L = 0; L < 9; ++L) {
    fp.d[L].W = WP(L, 0);
    fp.d[L].b = WP(L, 1);
    fp.d[L].g = WP(L, 2);
    fp.d[L].bt = WP(L, 3);
    fp.d[L].Wout = wouts[L];
    fp.d[L].bout = bouts[L];
    fp.d[L].O = OKKp[L][0];
    fp.d[L].K = OKKp[L][1];
    fp.d[L].Kp = OKKp[L][2];
    fp.d[L].transposed = (L == 0) ? 0 : 1;
    fp.cum[L + 1] = fp.cum[L] + nblk[L];
  }
  foldall_kernel<<<fp.cum[9], 256, 0, stream>>>(fp);

  // pack sa1/sa2 weights into bf16 MFMA fragment order
  sa2pack_kernel<<<16, 256, 0, stream>>>(wsf + o_s1w1, Q1, 64, 64, 0);
  sa2pack_kernel<<<32, 256, 0, stream>>>(wsf + o_s1wt2, Q2, 128, 64, 0);
  sa2pack_kernel<<<80, 256, 0, stream>>>(wsf + o_s2w1, P1, 128, 160, 1);
  sa2pack_kernel<<<64, 256, 0, stream>>>(wsf + o_s2wt2, P2, 128, 128, 0);
  sa2pack_kernel<<<128, 256, 0, stream>>>(wsf + o_s2w3, P3, 256, 128, 0);

  // SA1
  fps16_kernel<kN1, kS1, 256><<<kB, 256, 0, stream>>>(xyz, wsf + o_nx1);
  bq_kernel<kN1, kS1, kNS1><<<(kB * kS1) / 4, 256, 0, stream>>>(xyz, wsf + o_nx1, 0.04f, gidx1);
  sa1_mfma_kernel<<<(kB * kS1) / 2, 256, 0, stream>>>(
      xyz, wsf + o_nx1, gidx1,
      wsf + o_s1w0, wsf + o_s1b0, Q1, wsf + o_s1b1, Q2, wsf + o_s1b2,
      wsf + o_l1pts);

  // SA2
  fps4_kernel<kS1, kS2, 128><<<kB, 128, 0, stream>>>(wsf + o_nx1, wsf + o_nx2);
  bq_kernel<kS1, kS2, kNS2><<<(kB * kS2) / 4, 256, 0, stream>>>(wsf + o_nx1, wsf + o_nx2, 0.16f, gidx2);
  sa2_mfma_kernel<<<kB * kS2, 256, 0, stream>>>(
      wsf + o_nx1, wsf + o_l1pts, wsf + o_nx2, gidx2,
      P1, wsf + o_s2b1, P2, wsf + o_s2b2, P3, wsf + o_s2b3,
      wsf + o_l2pts);

  // SA3 (group all)
  sa3_passA_kernel<<<256, 256, 0, stream>>>(wsf + o_nx2, wsf + o_l2pts,
                                            wsf + o_s3wtA, wsf + o_s3bA, wsf + o_X1g);
  mlp_pass_kernel<256><<<dim3(256, 2), 256, 0, stream>>>(wsf + o_X1g, wsf + o_s3wtB, wsf + o_s3bB, 512, wsf + o_X2g);
  sa3_final_kernel<<<dim3(kB, 4), 256, 0, stream>>>(wsf + o_X2g, wsf + o_s3wtC, wsf + o_s3bC, (float*)d_out);
}

// Round 20
// 639.015 us; speedup vs baseline: 2.4007x; 1.4414x over previous
//
#include <hip/hip_runtime.h>
#include <hip/hip_bf16.h>
#include <cstddef>
#include <math.h>

#define kB 32
#define kN1 4096
#define kS1 512
#define kNS1 32
#define kS2 128
#define kNS2 64

typedef short bf16x8 __attribute__((ext_vector_type(8)));
typedef float f32x4 __attribute__((ext_vector_type(4)));

__device__ __forceinline__ short f2bf(float f) {   // RTN-even fp32 -> bf16 bits
  unsigned u = __float_as_uint(f);
  unsigned r = (u + 0x7fffu + ((u >> 16) & 1u)) >> 16;
  return (short)r;
}

// ---------------- fused weight folding for all 9 layers ----------------
struct FoldDesc {
  const float *W, *b, *g, *bt;
  float *Wout, *bout;
  int O, K, Kp, transposed;
};
struct FoldPack {
  FoldDesc d[9];
  int cum[10];
};

__global__ __launch_bounds__(256) void foldall_kernel(FoldPack p) {
  int blk = blockIdx.x;
  int L = 0;
#pragma unroll
  for (int i = 0; i < 9; ++i)
    if (blk >= p.cum[i + 1]) L = i + 1;
  FoldDesc d = p.d[L];
  int nb = p.cum[L + 1] - p.cum[L];
  int tid = (blk - p.cum[L]) * 256 + threadIdx.x;
  int stride = nb * 256;
  float inv = 1.0f / sqrtf(1.0f + 1e-5f);
  for (int i = tid; i < d.O * d.Kp; i += stride) {
    int o = i / d.Kp, k = i - o * d.Kp;
    float s = d.g[o] * inv;
    float w = (k < d.K) ? d.W[o * d.K + k] * s : 0.0f;
    if (d.transposed) d.Wout[k * d.O + o] = w;
    else d.Wout[o * d.Kp + k] = w;
  }
  for (int o = tid; o < d.O; o += stride) {
    d.bout[o] = d.b[o] * (d.g[o] * inv) + d.bt[o];
  }
}

// Pack folded fp32 k-major weights [K][O] into bf16 MFMA B-fragment order.
// mode 1 = sa2 layer1 K-permutation (features->rows 3..130, coords->0..2, pad 0).
// mode 0: rows kk >= Kreal are zero (K padding).
__global__ void sa2pack_kernel(const float* __restrict__ W, short* __restrict__ dst,
                               int O, int Kpad, int mode, int Kreal) {
  int e = blockIdx.x * 256 + threadIdx.x;
  int total = O * Kpad;
  if (e >= total) return;
  int i = e & 7, lane = (e >> 3) & 63, tile = e >> 9;
  int KT = Kpad / 32;
  int tn = tile / KT, tk = tile - tn * KT;
  int kk = tk * 32 + ((lane >> 4) & 3) * 8 + i;
  int n = tn * 16 + (lane & 15);
  float v;
  if (mode == 1) {
    int ok = (kk < 128) ? kk + 3 : ((kk < 131) ? kk - 128 : -1);
    v = (ok < 0) ? 0.0f : W[ok * O + n];
  } else {
    v = (kk < Kreal) ? W[kk * O + n] : 0.0f;
  }
  dst[e] = f2bf(v);
}

// Canonical CDNA wave64 f32 max via DPP (VALU pipe only).
__device__ __forceinline__ float wave_max_f32_nonneg(float x) {
#define DPP_MAXSTEP(CTRL)                                                     \
  {                                                                           \
    int o = __builtin_amdgcn_update_dpp(0, __float_as_int(x), (CTRL), 0xf, 0xf, true); \
    x = fmaxf(x, __int_as_float(o));                                          \
  }
  DPP_MAXSTEP(0x111)
  DPP_MAXSTEP(0x112)
  DPP_MAXSTEP(0x114)
  DPP_MAXSTEP(0x118)
  DPP_MAXSTEP(0x142)
  DPP_MAXSTEP(0x143)
#undef DPP_MAXSTEP
  return __int_as_float(__builtin_amdgcn_readlane(__float_as_int(x), 63));
}

__device__ __forceinline__ bool fps_pub_lane(float bestf, float wmax, int besti) {
  unsigned long long m = __ballot(bestf == wmax);
  if (__popcll(m) == 1) return bestf == wmax;
  unsigned long long mm = m;
  int bidx = 0x7fffffff;
  while (mm) {
    int l = __ffsll(mm) - 1;
    int bi = __shfl(besti, l, 64);
    bidx = min(bidx, bi);
    mm &= mm - 1;
  }
  return (bestf == wmax) && (besti == bidx);
}

// ---------------- farthest point sampling (R12 proven-best forms) ----------------
#define FPS_E(V, C, XV, YV, ZV, I)                                           \
  {                                                                          \
    float dx = __fsub_rn((XV), cx);                                          \
    float dy = __fsub_rn((YV), cy);                                          \
    float dz = __fsub_rn((ZV), cz);                                          \
    float d = fmaf(dz, dz, fmaf(dy, dy, __fmul_rn(dx, dx)));                 \
    float nd = fminf(dd##V.C, d);                                            \
    dd##V.C = nd;                                                            \
    if (nd > bestf) { bestf = nd; besti = (I); }                             \
  }

#define FPS_GRP(V, R)                                                        \
  {                                                                          \
    float4 xg = sx4[t + (R) * T];                                            \
    float4 yg = sy4[t + (R) * T];                                            \
    float4 zg = sz4[t + (R) * T];                                            \
    int ibase = 4 * (t + (R) * T);                                           \
    FPS_E(V, x, xg.x, yg.x, zg.x, ibase)                                     \
    FPS_E(V, y, xg.y, yg.y, zg.y, ibase + 1)                                 \
    FPS_E(V, z, xg.z, yg.z, zg.z, ibase + 2)                                 \
    FPS_E(V, w, xg.w, yg.w, zg.w, ibase + 3)                                 \
  }

template <int N, int NP, int T>
__global__ __launch_bounds__(T, 1) void fps16_kernel(const float* __restrict__ xyz,
                                                     float* __restrict__ nx) {
  static_assert(N == 16 * T, "fps16: need exactly 16 points per thread");
  constexpr int W = T / 64;
  __shared__ float4 sx4[N / 4], sy4[N / 4], sz4[N / 4];
  __shared__ unsigned long long skey[2][W];
  __shared__ int fid[NP];
  int b = blockIdx.x, t = threadIdx.x;
  int w = t >> 6;
  const float* base = xyz + (size_t)b * 3 * N;
  float* sxf = (float*)sx4;
  float* syf = (float*)sy4;
  float* szf = (float*)sz4;
  for (int i = t; i < N; i += T) sxf[i] = base[i];
  for (int i = t; i < N; i += T) syf[i] = base[N + i];
  for (int i = t; i < N; i += T) szf[i] = base[2 * N + i];
  float4 dd0, dd1, dd2, dd3;
  dd0 = dd1 = dd2 = dd3 = make_float4(1e10f, 1e10f, 1e10f, 1e10f);
  if (t < W) skey[0][t] = (t == 0) ? ~0ull : 0ull;
  if (t == 0) fid[0] = 0;
  int par = 0;
  __syncthreads();
  for (int it = 1; it < NP; ++it) {
    unsigned long long mk = skey[par][0];
#pragma unroll
    for (int w2 = 1; w2 < W; ++w2) {
      unsigned long long k2 = skey[par][w2];
      if (k2 > mk) mk = k2;
    }
    int wi = (int)(~(unsigned)mk);
    if (t == 0) fid[it - 1] = wi;
    float cx = sxf[wi], cy = syf[wi], cz = szf[wi];
    float bestf = -1.0f;
    int besti = 4 * t;
    FPS_GRP(0, 0)
    FPS_GRP(1, 1)
    FPS_GRP(2, 2)
    FPS_GRP(3, 3)
    float wmax = wave_max_f32_nonneg(bestf);
    if (fps_pub_lane(bestf, wmax, besti)) {
      skey[par ^ 1][w] =
          ((unsigned long long)__float_as_uint(wmax) << 32) | (unsigned)(~besti);
    }
    __syncthreads();
    par ^= 1;
  }
  {
    unsigned long long mk = skey[par][0];
#pragma unroll
    for (int w2 = 1; w2 < W; ++w2) {
      unsigned long long k2 = skey[par][w2];
      if (k2 > mk) mk = k2;
    }
    if (t == 0) fid[NP - 1] = (int)(~(unsigned)mk);
  }
  __syncthreads();
  for (int s = t; s < NP; s += T) {
    int f = fid[s];
    nx[(size_t)b * 3 * NP + s] = sxf[f];
    nx[(size_t)b * 3 * NP + NP + s] = syf[f];
    nx[(size_t)b * 3 * NP + 2 * NP + s] = szf[f];
  }
}

#define FPS_STEP(V, C, IDXOFF)                                               \
  {                                                                          \
    float dx = __fsub_rn(px##V.C, cx);                                       \
    float dy = __fsub_rn(py##V.C, cy);                                       \
    float dz = __fsub_rn(pz##V.C, cz);                                       \
    float d = fmaf(dz, dz, fmaf(dy, dy, __fmul_rn(dx, dx)));                 \
    float nd = fminf(dd##V.C, d);                                            \
    dd##V.C = nd;                                                            \
    if (nd > bestf) {                                                        \
      bestf = nd; besti = t + (IDXOFF); bx = px##V.C; by = py##V.C; bz = pz##V.C; \
    }                                                                        \
  }

#define FPS_LD4(arr, src, off) \
  arr = make_float4((src)[(off)], (src)[(off) + T], (src)[(off) + 2 * T], (src)[(off) + 3 * T])

template <int N, int NP, int T>
__global__ __launch_bounds__(T, 1) void fps4_kernel(const float* __restrict__ xyz,
                                                    float* __restrict__ nx) {
  static_assert(N == 4 * T, "fps4: need exactly 4 points per thread");
  constexpr int W = T / 64;
  __shared__ float4 sslot[2][W][2];
  __shared__ int fid[NP];
  int b = blockIdx.x, t = threadIdx.x;
  int w = t >> 6;
  const float* base = xyz + (size_t)b * 3 * N;
  float4 px0, py0, pz0, dd0;
  FPS_LD4(px0, base, t);
  FPS_LD4(py0, base + N, t);
  FPS_LD4(pz0, base + 2 * N, t);
  dd0 = make_float4(1e10f, 1e10f, 1e10f, 1e10f);
  if (t == 0) {
    fid[0] = 0;
    unsigned long long k0 = ~0ull;
    sslot[0][0][0] = make_float4(__uint_as_float((unsigned)k0),
                                 __uint_as_float((unsigned)(k0 >> 32)), px0.x, py0.x);
    sslot[0][0][1] = make_float4(pz0.x, 0.0f, 0.0f, 0.0f);
  }
  if (t >= 64 && (t & 63) == 0) {
    sslot[0][w][0] = make_float4(0.0f, 0.0f, 0.0f, 0.0f);
    sslot[0][w][1] = make_float4(0.0f, 0.0f, 0.0f, 0.0f);
  }
  int par = 0;
  __syncthreads();
  for (int it = 1; it < NP; ++it) {
    float4 q0 = sslot[par][0][0];
    float4 q1 = sslot[par][0][1];
    unsigned long long mk =
        ((unsigned long long)__float_as_uint(q0.y) << 32) | __float_as_uint(q0.x);
    float cx = q0.z, cy = q0.w, cz = q1.x;
#pragma unroll
    for (int w2 = 1; w2 < W; ++w2) {
      float4 p0 = sslot[par][w2][0];
      float4 p1 = sslot[par][w2][1];
      unsigned long long k2 =
          ((unsigned long long)__float_as_uint(p0.y) << 32) | __float_as_uint(p0.x);
      if (k2 > mk) { mk = k2; cx = p0.z; cy = p0.w; cz = p1.x; }
    }
    if (t == 0) fid[it - 1] = (int)(~(unsigned)mk);
    float bestf = -1.0f;
    int besti = t;
    float bx = px0.x, by = py0.x, bz = pz0.x;
    FPS_STEP(0, x, 0) FPS_STEP(0, y, T) FPS_STEP(0, z, 2 * T) FPS_STEP(0, w, 3 * T)
    float wmax = wave_max_f32_nonneg(bestf);
    if (fps_pub_lane(bestf, wmax, besti)) {
      unsigned long long key =
          ((unsigned long long)__float_as_uint(wmax) << 32) | (unsigned)(~besti);
      sslot[par ^ 1][w][0] = make_float4(__uint_as_float((unsigned)key),
                                         __uint_as_float((unsigned)(key >> 32)), bx, by);
      sslot[par ^ 1][w][1] = make_float4(bz, 0.0f, 0.0f, 0.0f);
    }
    __syncthreads();
    par ^= 1;
  }
  {
    float4 q0 = sslot[par][0][0];
    unsigned long long mk =
        ((unsigned long long)__float_as_uint(q0.y) << 32) | __float_as_uint(q0.x);
#pragma unroll
    for (int w2 = 1; w2 < W; ++w2) {
      float4 p0 = sslot[par][w2][0];
      unsigned long long k2 =
          ((unsigned long long)__float_as_uint(p0.y) << 32) | __float_as_uint(p0.x);
      if (k2 > mk) mk = k2;
    }
    if (t == 0) fid[NP - 1] = (int)(~(unsigned)mk);
  }
  __syncthreads();
  for (int s = t; s < NP; s += T) {
    int f = fid[s];
    nx[(size_t)b * 3 * NP + s] = base[f];
    nx[(size_t)b * 3 * NP + NP + s] = base[N + f];
    nx[(size_t)b * 3 * NP + 2 * NP + s] = base[2 * N + f];
  }
}

// ---------------- ball query ----------------
template <int NPTS, int NQ, int NS>
__global__ void bq_kernel(const float* __restrict__ pts, const float* __restrict__ qry,
                          float r2, int* __restrict__ gidx) {
  int gw = (blockIdx.x * blockDim.x + threadIdx.x) >> 6;
  int lane = threadIdx.x & 63;
  if (gw >= kB * NQ) return;
  int b = gw / NQ, s = gw - b * NQ;
  const float* pb = pts + (size_t)b * 3 * NPTS;
  float cx = qry[(size_t)b * 3 * NQ + s];
  float cy = qry[(size_t)b * 3 * NQ + NQ + s];
  float cz = qry[(size_t)b * 3 * NQ + 2 * NQ + s];
  float ss = fmaf(cz, cz, fmaf(cy, cy, __fmul_rn(cx, cx)));
  int* out = gidx + (size_t)gw * NS;
  int have = 0, first = 0;
  bool gotfirst = false;
  for (int n0 = 0; n0 < NPTS; n0 += 64) {
    int n = n0 + lane;
    float x = pb[n], y = pb[NPTS + n], z = pb[2 * NPTS + n];
    float dd = fmaf(z, z, fmaf(y, y, __fmul_rn(x, x)));
    float cross = fmaf(cz, z, fmaf(cy, y, __fmul_rn(cx, x)));
    float sqr = __fsub_rn(__fadd_rn(ss, dd), __fmul_rn(2.0f, cross));
    bool pred = !(sqr > r2);
    unsigned long long mask = __ballot(pred);
    if (!gotfirst && mask) { first = n0 + (__ffsll(mask) - 1); gotfirst = true; }
    if (pred) {
      int pos = have + __popcll(mask & ((1ull << lane) - 1ull));
      if (pos < NS) out[pos] = n;
    }
    have += __popcll(mask);
    if (have >= NS) break;
  }
  for (int slot = have + lane; slot < NS; slot += 64) out[slot] = first;
}

// ---------------- SA1 grouped MLP via bf16 MFMA ----------------
#define A1_STR 72
__global__ __launch_bounds__(256) void sa1_mfma_kernel(
    const float* __restrict__ xyz, const float* __restrict__ nx1,
    const int* __restrict__ gidx,
    const float* __restrict__ W0f, const float* __restrict__ bf0,
    const short* __restrict__ Q1, const float* __restrict__ bf1,
    const short* __restrict__ Q2, const float* __restrict__ bf2,
    float* __restrict__ l1_pts) {
  __shared__ short Abf[64 * A1_STR];
  int t = threadIdx.x;
  int lane = t & 63;
  int wg = t >> 6;
  int q0 = blockIdx.x * 2;
  {
    int row = t & 63;
    int q = q0 + (row >> 5);
    int b = q >> 9, s = q & 511;
    int sm = row & 31;
    int idx = gidx[(size_t)q * kNS1 + sm];
    float cx = nx1[b * 1536 + s];
    float cy = nx1[b * 1536 + 512 + s];
    float cz = nx1[b * 1536 + 1024 + s];
    const float* pb = xyz + (size_t)b * 3 * kN1;
    float f0 = pb[idx] - cx, f1 = pb[kN1 + idx] - cy, f2v = pb[2 * kN1 + idx] - cz;
#pragma unroll
    for (int j = 0; j < 16; ++j) {
      int col = wg * 16 + j;
      float4 w = *(const float4*)&W0f[col * 4];
      float v = fmaf(f2v, w.z, fmaf(f1, w.y, fmaf(f0, w.x, bf0[col])));
      Abf[row * A1_STR + col] = f2bf(fmaxf(v, 0.0f));
    }
  }
  __syncthreads();
  int lrow = lane & 15;
  int lgrp = (lane >> 4) * 8;
  {
    bf16x8 B0 = *(const bf16x8*)&Q1[(wg * 2 + 0) * 512 + lane * 8];
    bf16x8 B1 = *(const bf16x8*)&Q1[(wg * 2 + 1) * 512 + lane * 8];
    f32x4 acc[4];
    float bb = bf1[wg * 16 + lrow];
#pragma unroll
    for (int r = 0; r < 4; ++r) acc[r] = (f32x4){bb, bb, bb, bb};
#pragma unroll
    for (int r = 0; r < 4; ++r) {
      bf16x8 a0 = *(const bf16x8*)&Abf[(16 * r + lrow) * A1_STR + lgrp];
      bf16x8 a1 = *(const bf16x8*)&Abf[(16 * r + lrow) * A1_STR + 32 + lgrp];
      acc[r] = __builtin_amdgcn_mfma_f32_16x16x32_bf16(a0, B0, acc[r], 0, 0, 0);
      acc[r] = __builtin_amdgcn_mfma_f32_16x16x32_bf16(a1, B1, acc[r], 0, 0, 0);
    }
    __syncthreads();
#pragma unroll
    for (int r = 0; r < 4; ++r)
#pragma unroll
      for (int i = 0; i < 4; ++i) {
        int row = 16 * r + (lane >> 4) * 4 + i;
        Abf[row * A1_STR + wg * 16 + lrow] = f2bf(fmaxf(acc[r][i], 0.0f));
      }
    __syncthreads();
  }
  {
    bf16x8 B3[2][2];
#pragma unroll
    for (int c = 0; c < 2; ++c)
#pragma unroll
      for (int kt = 0; kt < 2; ++kt)
        B3[c][kt] = *(const bf16x8*)&Q2[((2 * wg + c) * 2 + kt) * 512 + lane * 8];
    f32x4 acc[4][2];
#pragma unroll
    for (int c = 0; c < 2; ++c) {
      float bb = bf2[(2 * wg + c) * 16 + lrow];
#pragma unroll
      for (int r = 0; r < 4; ++r) acc[r][c] = (f32x4){bb, bb, bb, bb};
    }
#pragma unroll
    for (int r = 0; r < 4; ++r) {
      bf16x8 a0 = *(const bf16x8*)&Abf[(16 * r + lrow) * A1_STR + lgrp];
      bf16x8 a1 = *(const bf16x8*)&Abf[(16 * r + lrow) * A1_STR + 32 + lgrp];
#pragma unroll
      for (int c = 0; c < 2; ++c) {
        acc[r][c] = __builtin_amdgcn_mfma_f32_16x16x32_bf16(a0, B3[c][0], acc[r][c], 0, 0, 0);
        acc[r][c] = __builtin_amdgcn_mfma_f32_16x16x32_bf16(a1, B3[c][1], acc[r][c], 0, 0, 0);
      }
    }
#pragma unroll
    for (int c = 0; c < 2; ++c) {
      float m0 = 0.0f, m1 = 0.0f;
#pragma unroll
      for (int i = 0; i < 4; ++i) {
        m0 = fmaxf(m0, fmaxf(acc[0][c][i], acc[1][c][i]));
        m1 = fmaxf(m1, fmaxf(acc[2][c][i], acc[3][c][i]));
      }
      m0 = fmaxf(m0, __shfl_xor(m0, 16, 64));
      m0 = fmaxf(m0, __shfl_xor(m0, 32, 64));
      m1 = fmaxf(m1, __shfl_xor(m1, 16, 64));
      m1 = fmaxf(m1, __shfl_xor(m1, 32, 64));
      int col = (2 * wg + c) * 16 + lrow;
      if (lane < 16) {
        l1_pts[(size_t)q0 * 128 + col] = m0;
        l1_pts[(size_t)(q0 + 1) * 128 + col] = m1;
      }
    }
  }
}

// ---------------- SA2 grouped MLP via bf16 MFMA ----------------
#define A_STR 168
__global__ __launch_bounds__(256) void sa2_mfma_kernel(
    const float* __restrict__ nx1, const float* __restrict__ l1_pts,
    const float* __restrict__ nx2, const int* __restrict__ gidx2,
    const short* __restrict__ P1, const float* __restrict__ bf1,
    const short* __restrict__ P2, const float* __restrict__ bf2,
    const short* __restrict__ P3, const float* __restrict__ bf3,
    float* __restrict__ l2_pts) {
  __shared__ short Abf[64 * A_STR];
  int t = threadIdx.x;
  int lane = t & 63;
  int wg = t >> 6;
  int q = blockIdx.x;
  int b = q >> 7, s = q & 127;
  int idx = gidx2[(size_t)q * kNS2 + lane];
  const float* pr = l1_pts + ((size_t)(b * kS1) + idx) * 128;
#pragma unroll
  for (int i = 0; i < 8; ++i) {
    float4 v = *(const float4*)&pr[wg * 32 + i * 4];
    unsigned lo = (unsigned)(unsigned short)f2bf(v.x) |
                  ((unsigned)(unsigned short)f2bf(v.y) << 16);
    unsigned hi = (unsigned)(unsigned short)f2bf(v.z) |
                  ((unsigned)(unsigned short)f2bf(v.w) << 16);
    *(uint2*)&Abf[lane * A_STR + wg * 32 + i * 4] = make_uint2(lo, hi);
  }
  if (wg == 0) {
    float cx = nx2[b * 384 + s];
    float cy = nx2[b * 384 + 128 + s];
    float cz = nx2[b * 384 + 256 + s];
    float f0 = nx1[b * 1536 + idx] - cx;
    float f1 = nx1[b * 1536 + 512 + idx] - cy;
    float f2v = nx1[b * 1536 + 1024 + idx] - cz;
    unsigned lo = (unsigned)(unsigned short)f2bf(f0) |
                  ((unsigned)(unsigned short)f2bf(f1) << 16);
    unsigned hi = (unsigned)(unsigned short)f2bf(f2v);
    *(uint2*)&Abf[lane * A_STR + 128] = make_uint2(lo, hi);
  }
  if (wg == 1) {
#pragma unroll
    for (int j = 0; j < 7; ++j)
      *(uint2*)&Abf[lane * A_STR + 132 + j * 4] = make_uint2(0u, 0u);
  }
  __syncthreads();
  int lrow = lane & 15;
  int lgrp = (lane >> 4) * 8;
  bf16x8 B1[2][5];
#pragma unroll
  for (int c = 0; c < 2; ++c)
#pragma unroll
    for (int kt = 0; kt < 5; ++kt)
      B1[c][kt] = *(const bf16x8*)&P1[(((2 * wg + c) * 5 + kt) * 512 + lane * 8)];
  f32x4 acc1[4][2];
  {
    float b0 = bf1[(2 * wg + 0) * 16 + lrow];
    float b1v = bf1[(2 * wg + 1) * 16 + lrow];
#pragma unroll
    for (int r = 0; r < 4; ++r) {
      acc1[r][0] = (f32x4){b0, b0, b0, b0};
      acc1[r][1] = (f32x4){b1v, b1v, b1v, b1v};
    }
  }
#pragma unroll
  for (int r = 0; r < 4; ++r) {
    bf16x8 a[5];
#pragma unroll
    for (int kt = 0; kt < 5; ++kt)
      a[kt] = *(const bf16x8*)&Abf[(16 * r + lrow) * A_STR + kt * 32 + lgrp];
#pragma unroll
    for (int kt = 0; kt < 5; ++kt) {
      acc1[r][0] = __builtin_amdgcn_mfma_f32_16x16x32_bf16(a[kt], B1[0][kt], acc1[r][0], 0, 0, 0);
      acc1[r][1] = __builtin_amdgcn_mfma_f32_16x16x32_bf16(a[kt], B1[1][kt], acc1[r][1], 0, 0, 0);
    }
  }
  __syncthreads();
#pragma unroll
  for (int r = 0; r < 4; ++r)
#pragma unroll
    for (int c = 0; c < 2; ++c)
#pragma unroll
      for (int i = 0; i < 4; ++i) {
        int row = 16 * r + (lane >> 4) * 4 + i;
        int col = (2 * wg + c) * 16 + lrow;
        Abf[row * A_STR + col] = f2bf(fmaxf(acc1[r][c][i], 0.0f));
      }
  __syncthreads();
  bf16x8 B2[2][4];
#pragma unroll
  for (int c = 0; c < 2; ++c)
#pragma unroll
    for (int kt = 0; kt < 4; ++kt)
      B2[c][kt] = *(const bf16x8*)&P2[(((2 * wg + c) * 4 + kt) * 512 + lane * 8)];
  f32x4 acc2[4][2];
  {
    float b0 = bf2[(2 * wg + 0) * 16 + lrow];
    float b1v = bf2[(2 * wg + 1) * 16 + lrow];
#pragma unroll
    for (int r = 0; r < 4; ++r) {
      acc2[r][0] = (f32x4){b0, b0, b0, b0};
      acc2[r][1] = (f32x4){b1v, b1v, b1v, b1v};
    }
  }
#pragma unroll
  for (int r = 0; r < 4; ++r) {
    bf16x8 a[4];
#pragma unroll
    for (int kt = 0; kt < 4; ++kt)
      a[kt] = *(const bf16x8*)&Abf[(16 * r + lrow) * A_STR + kt * 32 + lgrp];
#pragma unroll
    for (int kt = 0; kt < 4; ++kt) {
      acc2[r][0] = __builtin_amdgcn_mfma_f32_16x16x32_bf16(a[kt], B2[0][kt], acc2[r][0], 0, 0, 0);
      acc2[r][1] = __builtin_amdgcn_mfma_f32_16x16x32_bf16(a[kt], B2[1][kt], acc2[r][1], 0, 0, 0);
    }
  }
  __syncthreads();
#pragma unroll
  for (int r = 0; r < 4; ++r)
#pragma unroll
    for (int c = 0; c < 2; ++c)
#pragma unroll
      for (int i = 0; i < 4; ++i) {
        int row = 16 * r + (lane >> 4) * 4 + i;
        int col = (2 * wg + c) * 16 + lrow;
        Abf[row * A_STR + col] = f2bf(fmaxf(acc2[r][c][i], 0.0f));
      }
  __syncthreads();
  float* outp = l2_pts + (size_t)q * 256;
#pragma unroll
  for (int h = 0; h < 2; ++h) {
    int tn0 = 4 * wg + 2 * h;
    bf16x8 B3[2][4];
#pragma unroll
    for (int c = 0; c < 2; ++c)
#pragma unroll
      for (int kt = 0; kt < 4; ++kt)
        B3[c][kt] = *(const bf16x8*)&P3[(((tn0 + c) * 4 + kt) * 512 + lane * 8)];
    f32x4 acc3[4][2];
    {
      float b0 = bf3[(tn0 + 0) * 16 + lrow];
      float b1v = bf3[(tn0 + 1) * 16 + lrow];
#pragma unroll
      for (int r = 0; r < 4; ++r) {
        acc3[r][0] = (f32x4){b0, b0, b0, b0};
        acc3[r][1] = (f32x4){b1v, b1v, b1v, b1v};
      }
    }
#pragma unroll
    for (int r = 0; r < 4; ++r) {
      bf16x8 a[4];
#pragma unroll
      for (int kt = 0; kt < 4; ++kt)
        a[kt] = *(const bf16x8*)&Abf[(16 * r + lrow) * A_STR + kt * 32 + lgrp];
#pragma unroll
      for (int kt = 0; kt < 4; ++kt) {
        acc3[r][0] = __builtin_amdgcn_mfma_f32_16x16x32_bf16(a[kt], B3[0][kt], acc3[r][0], 0, 0, 0);
        acc3[r][1] = __builtin_amdgcn_mfma_f32_16x16x32_bf16(a[kt], B3[1][kt], acc3[r][1], 0, 0, 0);
      }
    }
#pragma unroll
    for (int c = 0; c < 2; ++c) {
      float m = 0.0f;
#pragma unroll
      for (int r = 0; r < 4; ++r)
#pragma unroll
        for (int i = 0; i < 4; ++i) m = fmaxf(m, acc3[r][c][i]);
      m = fmaxf(m, __shfl_xor(m, 16, 64));
      m = fmaxf(m, __shfl_xor(m, 32, 64));
      if (lane < 16) outp[(tn0 + c) * 16 + lane] = m;
    }
  }
}

// ---------------- SA3 via bf16 MFMA ----------------
// concat -> bf16 F0 [4096][288] (cols 0..2 coords, 3..258 l2_pts, 259.. zero)
__global__ void concat3bf_kernel(const float* __restrict__ nx2,
                                 const float* __restrict__ l2_pts,
                                 short* __restrict__ F0bf) {
  int i = blockIdx.x * 256 + threadIdx.x;
  if (i >= 4096 * 288) return;
  int row = i / 288, k = i - row * 288;
  int b = row >> 7, s = row & 127;
  float v;
  if (k < 3) v = nx2[b * 384 + k * 128 + s];
  else if (k < 259) v = l2_pts[(size_t)row * 256 + (k - 3)];
  else v = 0.0f;
  F0bf[i] = f2bf(v);
}

// Generic MFMA pass: M-tile = RT*16 rows (A preloaded to regs), N = 4*NTW*16.
// DOMAX: per-tile max over rows + atomicMax(float-bits) into zeroed out.
template <int KT, int RT, int NTW, bool DOMAX>
__global__ __launch_bounds__(256) void g3_mfma_kernel(
    const short* __restrict__ Xbf, const short* __restrict__ BP,
    const float* __restrict__ bias, short* __restrict__ Ybf,
    float* __restrict__ outp) {
  constexpr int K = KT * 32;
  constexpr int ROWS = RT * 16;
  constexpr int AS = K + 8;
  constexpr int N = 4 * NTW * 16;
  __shared__ short Abf[ROWS * AS];
  int t = threadIdx.x, lane = t & 63, wg = t >> 6;
  int row0 = blockIdx.x * ROWS;
  {
    constexpr int TPR = 256 / ROWS;
    constexpr int CPT = K / TPR;
    int row = t & (ROWS - 1);
    int chunk = t / ROWS;
    const short* src = Xbf + (size_t)(row0 + row) * K + chunk * CPT;
    short* dstp = Abf + row * AS + chunk * CPT;
#pragma unroll
    for (int i = 0; i < CPT / 4; ++i)
      *(uint2*)&dstp[i * 4] = *(const uint2*)&src[i * 4];
  }
  __syncthreads();
  int lrow = lane & 15, lgrp = (lane >> 4) * 8;
  bf16x8 a[RT][KT];
#pragma unroll
  for (int r = 0; r < RT; ++r)
#pragma unroll
    for (int kt = 0; kt < KT; ++kt)
      a[r][kt] = *(const bf16x8*)&Abf[(16 * r + lrow) * AS + kt * 32 + lgrp];
  for (int h = 0; h < NTW; ++h) {
    int nt = wg * NTW + h;
    f32x4 acc[RT];
    float bb = bias[nt * 16 + lrow];
#pragma unroll
    for (int r = 0; r < RT; ++r) acc[r] = (f32x4){bb, bb, bb, bb};
#pragma unroll
    for (int kt = 0; kt < KT; ++kt) {
      bf16x8 Bf = *(const bf16x8*)&BP[((size_t)nt * KT + kt) * 512 + lane * 8];
#pragma unroll
      for (int r = 0; r < RT; ++r)
        acc[r] = __builtin_amdgcn_mfma_f32_16x16x32_bf16(a[r][kt], Bf, acc[r], 0, 0, 0);
    }
    if (!DOMAX) {
#pragma unroll
      for (int r = 0; r < RT; ++r)
#pragma unroll
        for (int i = 0; i < 4; ++i) {
          int row = 16 * r + (lane >> 4) * 4 + i;
          Ybf[(size_t)(row0 + row) * N + nt * 16 + lrow] = f2bf(fmaxf(acc[r][i], 0.0f));
        }
    } else {
      float m = 0.0f;   // relu floor
#pragma unroll
      for (int r = 0; r < RT; ++r)
#pragma unroll
        for (int i = 0; i < 4; ++i) m = fmaxf(m, acc[r][i]);
      m = fmaxf(m, __shfl_xor(m, 16, 64));
      m = fmaxf(m, __shfl_xor(m, 32, 64));
      if (lane < 16) {
        int b = row0 >> 7;
        atomicMax((unsigned*)&outp[(size_t)b * 1024 + nt * 16 + lrow],
                  __float_as_uint(m));
      }
    }
  }
}

// ---------------- launch ----------------
extern "C" void kernel_launch(void* const* d_in, const int* in_sizes, int n_in,
                              void* d_out, int out_size, void* d_ws, size_t ws_size,
                              hipStream_t stream) {
  (void)in_sizes; (void)n_in; (void)out_size; (void)ws_size;
  const float* xyz = (const float*)d_in[0];
  auto WP = [&](int layer, int part) -> const float* {
    return (const float*)d_in[1 + layer * 4 + part];
  };
  float* wsf = (float*)d_ws;
  size_t cur = 0;
  auto alloc = [&](size_t n) { size_t o = cur; cur += (n + 63) & ~(size_t)63; return o; };
  size_t o_nx1 = alloc((size_t)kB * 3 * kS1);
  size_t o_nx2 = alloc((size_t)kB * 3 * kS2);
  size_t o_l1pts = alloc((size_t)kB * kS1 * 128);
  size_t o_l2pts = alloc((size_t)kB * kS2 * 256);
  size_t o_s1w0 = alloc(64 * 4), o_s1b0 = alloc(64);
  size_t o_s1w1 = alloc(64 * 64), o_s1b1 = alloc(64);
  size_t o_s1wt2 = alloc(64 * 128), o_s1b2 = alloc(128);
  size_t o_s2w1 = alloc(132 * 128), o_s2b1 = alloc(128);
  size_t o_s2wt2 = alloc(128 * 128), o_s2b2 = alloc(128);
  size_t o_s2w3 = alloc(128 * 256), o_s2b3 = alloc(256);
  size_t o_s3wtA = alloc(260 * 256), o_s3bA = alloc(256);
  size_t o_s3wtB = alloc(256 * 512), o_s3bB = alloc(512);
  size_t o_s3wtC = alloc(512 * 1024), o_s3bC = alloc(1024);
  size_t o_gidx1 = alloc((size_t)kB * kS1 * kNS1);
  size_t o_gidx2 = alloc((size_t)kB * kS2 * kNS2);
  size_t o_p1 = alloc(10240);
  size_t o_p2 = alloc(8192);
  size_t o_p3 = alloc(16384);
  size_t o_q1 = alloc(2048);
  size_t o_q2 = alloc(4096);
  size_t o_ra = alloc(36864);     // 256*288 shorts
  size_t o_rb = alloc(65536);     // 512*256 shorts
  size_t o_rc = alloc(262144);    // 1024*512 shorts
  size_t o_f0bf = alloc(589824);  // 4096*288 shorts
  size_t o_y1bf = alloc(524288);  // 4096*256 shorts
  int* gidx1 = (int*)(wsf + o_gidx1);
  int* gidx2 = (int*)(wsf + o_gidx2);
  short* P1 = (short*)(wsf + o_p1);
  short* P2 = (short*)(wsf + o_p2);
  short* P3 = (short*)(wsf + o_p3);
  short* Q1 = (short*)(wsf + o_q1);
  short* Q2 = (short*)(wsf + o_q2);
  short* RA = (short*)(wsf + o_ra);
  short* RB = (short*)(wsf + o_rb);
  short* RC = (short*)(wsf + o_rc);
  short* F0bf = (short*)(wsf + o_f0bf);
  short* Y1bf = (short*)(wsf + o_y1bf);
  size_t o_y2bf = alloc(1048576); // 4096*512 shorts
  short* Y2bf = (short*)(wsf + o_y2bf);

  // fused fold of all 9 layers
  FoldPack fp;
  const int OKKp[9][3] = {{64, 3, 4},     {64, 64, 64},   {128, 64, 64},
                          {128, 131, 132}, {128, 128, 128}, {256, 128, 128},
                          {256, 259, 260}, {512, 256, 256}, {1024, 512, 512}};
  float* wouts[9] = {wsf + o_s1w0, wsf + o_s1w1, wsf + o_s1wt2,
                     wsf + o_s2w1, wsf + o_s2wt2, wsf + o_s2w3,
                     wsf + o_s3wtA, wsf + o_s3wtB, wsf + o_s3wtC};
  float* bouts[9] = {wsf + o_s1b0, wsf + o_s1b1, wsf + o_s1b2,
                     wsf + o_s2b1, wsf + o_s2b2, wsf + o_s2b3,
                     wsf + o_s3bA, wsf + o_s3bB, wsf + o_s3bC};
  const int nblk[9] = {1, 4, 8, 17, 16, 32, 65, 128, 512};
  fp.cum[0] = 0;
  for (int L = 0; L < 9; ++L) {
    fp.d[L].W = WP(L, 0);
    fp.d[L].b = WP(L, 1);
    fp.d[L].g = WP(L, 2);
    fp.d[L].bt = WP(L, 3);
    fp.d[L].Wout = wouts[L];
    fp.d[L].bout = bouts[L];
    fp.d[L].O = OKKp[L][0];
    fp.d[L].K = OKKp[L][1];
    fp.d[L].Kp = OKKp[L][2];
    fp.d[L].transposed = (L == 0) ? 0 : 1;
    fp.cum[L + 1] = fp.cum[L] + nblk[L];
  }
  foldall_kernel<<<fp.cum[9], 256, 0, stream>>>(fp);

  // pack weights into bf16 MFMA fragment order
  sa2pack_kernel<<<16, 256, 0, stream>>>(wsf + o_s1w1, Q1, 64, 64, 0, 64);
  sa2pack_kernel<<<32, 256, 0, stream>>>(wsf + o_s1wt2, Q2, 128, 64, 0, 64);
  sa2pack_kernel<<<80, 256, 0, stream>>>(wsf + o_s2w1, P1, 128, 160, 1, 0);
  sa2pack_kernel<<<64, 256, 0, stream>>>(wsf + o_s2wt2, P2, 128, 128, 0, 128);
  sa2pack_kernel<<<128, 256, 0, stream>>>(wsf + o_s2w3, P3, 256, 128, 0, 128);
  sa2pack_kernel<<<288, 256, 0, stream>>>(wsf + o_s3wtA, RA, 256, 288, 0, 260);
  sa2pack_kernel<<<512, 256, 0, stream>>>(wsf + o_s3wtB, RB, 512, 256, 0, 256);
  sa2pack_kernel<<<2048, 256, 0, stream>>>(wsf + o_s3wtC, RC, 1024, 512, 0, 512);

  // SA1
  fps16_kernel<kN1, kS1, 256><<<kB, 256, 0, stream>>>(xyz, wsf + o_nx1);
  bq_kernel<kN1, kS1, kNS1><<<(kB * kS1) / 4, 256, 0, stream>>>(xyz, wsf + o_nx1, 0.04f, gidx1);
  sa1_mfma_kernel<<<(kB * kS1) / 2, 256, 0, stream>>>(
      xyz, wsf + o_nx1, gidx1,
      wsf + o_s1w0, wsf + o_s1b0, Q1, wsf + o_s1b1, Q2, wsf + o_s1b2,
      wsf + o_l1pts);

  // SA2
  fps4_kernel<kS1, kS2, 128><<<kB, 128, 0, stream>>>(wsf + o_nx1, wsf + o_nx2);
  bq_kernel<kS1, kS2, kNS2><<<(kB * kS2) / 4, 256, 0, stream>>>(wsf + o_nx1, wsf + o_nx2, 0.16f, gidx2);
  sa2_mfma_kernel<<<kB * kS2, 256, 0, stream>>>(
      wsf + o_nx1, wsf + o_l1pts, wsf + o_nx2, gidx2,
      P1, wsf + o_s2b1, P2, wsf + o_s2b2, P3, wsf + o_s2b3,
      wsf + o_l2pts);

  // SA3 (group all) via MFMA
  concat3bf_kernel<<<4608, 256, 0, stream>>>(wsf + o_nx2, wsf + o_l2pts, F0bf);
  g3_mfma_kernel<9, 4, 4, false><<<64, 256, 0, stream>>>(
      F0bf, RA, wsf + o_s3bA, Y1bf, (float*)nullptr);
  g3_mfma_kernel<8, 4, 8, false><<<64, 256, 0, stream>>>(
      Y1bf, RB, wsf + o_s3bB, Y2bf, (float*)nullptr);
  hipMemsetAsync(d_out, 0, (size_t)kB * 1024 * sizeof(float), stream);
  g3_mfma_kernel<16, 2, 16, true><<<128, 256, 0, stream>>>(
      Y2bf, RC, wsf + o_s3bC, (short*)nullptr, (float*)d_out);
}

// Round 21
// 603.227 us; speedup vs baseline: 2.5431x; 1.0593x over previous
//
#include <hip/hip_runtime.h>
#include <hip/hip_bf16.h>
#include <cstddef>
#include <math.h>

#define kB 32
#define kN1 4096
#define kS1 512
#define kNS1 32
#define kS2 128
#define kNS2 64

typedef short bf16x8 __attribute__((ext_vector_type(8)));
typedef float f32x4 __attribute__((ext_vector_type(4)));
typedef float f32x2 __attribute__((ext_vector_type(2)));

__device__ __forceinline__ short f2bf(float f) {   // RTN-even fp32 -> bf16 bits
  unsigned u = __float_as_uint(f);
  unsigned r = (u + 0x7fffu + ((u >> 16) & 1u)) >> 16;
  return (short)r;
}

// ---------------- fused weight folding for all 9 layers ----------------
struct FoldDesc {
  const float *W, *b, *g, *bt;
  float *Wout, *bout;
  int O, K, Kp, transposed;
};
struct FoldPack {
  FoldDesc d[9];
  int cum[10];
};

__global__ __launch_bounds__(256) void foldall_kernel(FoldPack p) {
  int blk = blockIdx.x;
  int L = 0;
#pragma unroll
  for (int i = 0; i < 9; ++i)
    if (blk >= p.cum[i + 1]) L = i + 1;
  FoldDesc d = p.d[L];
  int nb = p.cum[L + 1] - p.cum[L];
  int tid = (blk - p.cum[L]) * 256 + threadIdx.x;
  int stride = nb * 256;
  float inv = 1.0f / sqrtf(1.0f + 1e-5f);
  for (int i = tid; i < d.O * d.Kp; i += stride) {
    int o = i / d.Kp, k = i - o * d.Kp;
    float s = d.g[o] * inv;
    float w = (k < d.K) ? d.W[o * d.K + k] * s : 0.0f;
    if (d.transposed) d.Wout[k * d.O + o] = w;
    else d.Wout[o * d.Kp + k] = w;
  }
  for (int o = tid; o < d.O; o += stride) {
    d.bout[o] = d.b[o] * (d.g[o] * inv) + d.bt[o];
  }
}

// ---------------- fused packing of all MFMA weight buffers ----------------
// dst[(tn*KT + tk)*512 + lane*8 + i] = W[kmap(tk*32 + (lane>>4)*8 + i)][tn*16 + (lane&15)]
// mode 1 = sa2 layer1 K-permutation; mode 0: rows kk >= Kreal are zero.
struct PackJob { const float* W; short* dst; int O, Kpad, mode, Kreal; };
struct PackPack { PackJob j[8]; int cum[9]; };

__global__ __launch_bounds__(256) void packall_kernel(PackPack p) {
  int blk = blockIdx.x;
  int L = 0;
#pragma unroll
  for (int i = 0; i < 8; ++i)
    if (blk >= p.cum[i + 1]) L = i + 1;
  PackJob d = p.j[L];
  int e = (blk - p.cum[L]) * 256 + threadIdx.x;
  if (e >= d.O * d.Kpad) return;
  int i = e & 7, lane = (e >> 3) & 63, tile = e >> 9;
  int KT = d.Kpad / 32;
  int tn = tile / KT, tk = tile - tn * KT;
  int kk = tk * 32 + ((lane >> 4) & 3) * 8 + i;
  int n = tn * 16 + (lane & 15);
  float v;
  if (d.mode == 1) {
    int ok = (kk < 128) ? kk + 3 : ((kk < 131) ? kk - 128 : -1);
    v = (ok < 0) ? 0.0f : d.W[ok * d.O + n];
  } else {
    v = (kk < d.Kreal) ? d.W[kk * d.O + n] : 0.0f;
  }
  d.dst[e] = f2bf(v);
}

// Canonical CDNA wave64 f32 max via DPP (VALU pipe only).
__device__ __forceinline__ float wave_max_f32_nonneg(float x) {
#define DPP_MAXSTEP(CTRL)                                                     \
  {                                                                           \
    int o = __builtin_amdgcn_update_dpp(0, __float_as_int(x), (CTRL), 0xf, 0xf, true); \
    x = fmaxf(x, __int_as_float(o));                                          \
  }
  DPP_MAXSTEP(0x111)
  DPP_MAXSTEP(0x112)
  DPP_MAXSTEP(0x114)
  DPP_MAXSTEP(0x118)
  DPP_MAXSTEP(0x142)
  DPP_MAXSTEP(0x143)
#undef DPP_MAXSTEP
  return __int_as_float(__builtin_amdgcn_readlane(__float_as_int(x), 63));
}

__device__ __forceinline__ bool fps_pub_lane(float bestf, float wmax, int besti) {
  unsigned long long m = __ballot(bestf == wmax);
  if (__popcll(m) == 1) return bestf == wmax;
  unsigned long long mm = m;
  int bidx = 0x7fffffff;
  while (mm) {
    int l = __ffsll(mm) - 1;
    int bi = __shfl(besti, l, 64);
    bidx = min(bidx, bi);
    mm &= mm - 1;
  }
  return (bestf == wmax) && (besti == bidx);
}

// ---------------- farthest point sampling ----------------
// fps16 (R12 structure): coords in LDS as float4 groups, dd register-resident,
// key-only u64 winner slots, DPP wave-max. Dist update vectorized over float2
// (packed dual-fp32 VALU ops) -- per-element IEEE ops identical to scalar, so
// the selected point set is bit-identical; index tracking stays ascending.
#define FPS_E2(DDV, CA, CB, XA, XB, YA, YB, ZA, ZB, I0)                      \
  {                                                                          \
    f32x2 dx = (f32x2){(XA), (XB)} - cx2;                                    \
    f32x2 dy = (f32x2){(YA), (YB)} - cy2;                                    \
    f32x2 dz = (f32x2){(ZA), (ZB)} - cz2;                                    \
    f32x2 d = __builtin_elementwise_fma(                                     \
        dz, dz, __builtin_elementwise_fma(dy, dy, dx * dx));                 \
    float nda = fminf(DDV.CA, d.x);                                          \
    DDV.CA = nda;                                                            \
    if (nda > bestf) { bestf = nda; besti = (I0); }                          \
    float ndb = fminf(DDV.CB, d.y);                                          \
    DDV.CB = ndb;                                                            \
    if (ndb > bestf) { bestf = ndb; besti = (I0) + 1; }                      \
  }

#define FPS_GRP(V, R)                                                        \
  {                                                                          \
    float4 xg = sx4[t + (R) * T];                                            \
    float4 yg = sy4[t + (R) * T];                                            \
    float4 zg = sz4[t + (R) * T];                                            \
    int ibase = 4 * (t + (R) * T);                                           \
    FPS_E2(dd##V, x, y, xg.x, xg.y, yg.x, yg.y, zg.x, zg.y, ibase)           \
    FPS_E2(dd##V, z, w, xg.z, xg.w, yg.z, yg.w, zg.z, zg.w, ibase + 2)       \
  }

template <int N, int NP, int T>
__global__ __launch_bounds__(T, 1) void fps16_kernel(const float* __restrict__ xyz,
                                                     float* __restrict__ nx) {
  static_assert(N == 16 * T, "fps16: need exactly 16 points per thread");
  constexpr int W = T / 64;
  __shared__ float4 sx4[N / 4], sy4[N / 4], sz4[N / 4];
  __shared__ unsigned long long skey[2][W];
  __shared__ int fid[NP];
  int b = blockIdx.x, t = threadIdx.x;
  int w = t >> 6;
  const float* base = xyz + (size_t)b * 3 * N;
  float* sxf = (float*)sx4;
  float* syf = (float*)sy4;
  float* szf = (float*)sz4;
  for (int i = t; i < N; i += T) sxf[i] = base[i];
  for (int i = t; i < N; i += T) syf[i] = base[N + i];
  for (int i = t; i < N; i += T) szf[i] = base[2 * N + i];
  float4 dd0, dd1, dd2, dd3;
  dd0 = dd1 = dd2 = dd3 = make_float4(1e10f, 1e10f, 1e10f, 1e10f);
  if (t < W) skey[0][t] = (t == 0) ? ~0ull : 0ull;
  if (t == 0) fid[0] = 0;
  int par = 0;
  __syncthreads();
  for (int it = 1; it < NP; ++it) {
    unsigned long long mk = skey[par][0];
#pragma unroll
    for (int w2 = 1; w2 < W; ++w2) {
      unsigned long long k2 = skey[par][w2];
      if (k2 > mk) mk = k2;
    }
    int wi = (int)(~(unsigned)mk);
    if (t == 0) fid[it - 1] = wi;
    float cx = sxf[wi], cy = syf[wi], cz = szf[wi];
    f32x2 cx2 = (f32x2){cx, cx};
    f32x2 cy2 = (f32x2){cy, cy};
    f32x2 cz2 = (f32x2){cz, cz};
    float bestf = -1.0f;
    int besti = 4 * t;
    FPS_GRP(0, 0)
    FPS_GRP(1, 1)
    FPS_GRP(2, 2)
    FPS_GRP(3, 3)
    float wmax = wave_max_f32_nonneg(bestf);
    if (fps_pub_lane(bestf, wmax, besti)) {
      skey[par ^ 1][w] =
          ((unsigned long long)__float_as_uint(wmax) << 32) | (unsigned)(~besti);
    }
    __syncthreads();
    par ^= 1;
  }
  {
    unsigned long long mk = skey[par][0];
#pragma unroll
    for (int w2 = 1; w2 < W; ++w2) {
      unsigned long long k2 = skey[par][w2];
      if (k2 > mk) mk = k2;
    }
    if (t == 0) fid[NP - 1] = (int)(~(unsigned)mk);
  }
  __syncthreads();
  for (int s = t; s < NP; s += T) {
    int f = fid[s];
    nx[(size_t)b * 3 * NP + s] = sxf[f];
    nx[(size_t)b * 3 * NP + NP + s] = syf[f];
    nx[(size_t)b * 3 * NP + 2 * NP + s] = szf[f];
  }
}

#define FPS_STEP(V, C, IDXOFF)                                               \
  {                                                                          \
    float dx = __fsub_rn(px##V.C, cx);                                       \
    float dy = __fsub_rn(py##V.C, cy);                                       \
    float dz = __fsub_rn(pz##V.C, cz);                                       \
    float d = fmaf(dz, dz, fmaf(dy, dy, __fmul_rn(dx, dx)));                 \
    float nd = fminf(dd##V.C, d);                                            \
    dd##V.C = nd;                                                            \
    if (nd > bestf) {                                                        \
      bestf = nd; besti = t + (IDXOFF); bx = px##V.C; by = py##V.C; bz = pz##V.C; \
    }                                                                        \
  }

#define FPS_LD4(arr, src, off) \
  arr = make_float4((src)[(off)], (src)[(off) + T], (src)[(off) + 2 * T], (src)[(off) + 3 * T])

template <int N, int NP, int T>
__global__ __launch_bounds__(T, 1) void fps4_kernel(const float* __restrict__ xyz,
                                                    float* __restrict__ nx) {
  static_assert(N == 4 * T, "fps4: need exactly 4 points per thread");
  constexpr int W = T / 64;
  __shared__ float4 sslot[2][W][2];
  __shared__ int fid[NP];
  int b = blockIdx.x, t = threadIdx.x;
  int w = t >> 6;
  const float* base = xyz + (size_t)b * 3 * N;
  float4 px0, py0, pz0, dd0;
  FPS_LD4(px0, base, t);
  FPS_LD4(py0, base + N, t);
  FPS_LD4(pz0, base + 2 * N, t);
  dd0 = make_float4(1e10f, 1e10f, 1e10f, 1e10f);
  if (t == 0) {
    fid[0] = 0;
    unsigned long long k0 = ~0ull;
    sslot[0][0][0] = make_float4(__uint_as_float((unsigned)k0),
                                 __uint_as_float((unsigned)(k0 >> 32)), px0.x, py0.x);
    sslot[0][0][1] = make_float4(pz0.x, 0.0f, 0.0f, 0.0f);
  }
  if (t >= 64 && (t & 63) == 0) {
    sslot[0][w][0] = make_float4(0.0f, 0.0f, 0.0f, 0.0f);
    sslot[0][w][1] = make_float4(0.0f, 0.0f, 0.0f, 0.0f);
  }
  int par = 0;
  __syncthreads();
  for (int it = 1; it < NP; ++it) {
    float4 q0 = sslot[par][0][0];
    float4 q1 = sslot[par][0][1];
    unsigned long long mk =
        ((unsigned long long)__float_as_uint(q0.y) << 32) | __float_as_uint(q0.x);
    float cx = q0.z, cy = q0.w, cz = q1.x;
#pragma unroll
    for (int w2 = 1; w2 < W; ++w2) {
      float4 p0 = sslot[par][w2][0];
      float4 p1 = sslot[par][w2][1];
      unsigned long long k2 =
          ((unsigned long long)__float_as_uint(p0.y) << 32) | __float_as_uint(p0.x);
      if (k2 > mk) { mk = k2; cx = p0.z; cy = p0.w; cz = p1.x; }
    }
    if (t == 0) fid[it - 1] = (int)(~(unsigned)mk);
    float bestf = -1.0f;
    int besti = t;
    float bx = px0.x, by = py0.x, bz = pz0.x;
    FPS_STEP(0, x, 0) FPS_STEP(0, y, T) FPS_STEP(0, z, 2 * T) FPS_STEP(0, w, 3 * T)
    float wmax = wave_max_f32_nonneg(bestf);
    if (fps_pub_lane(bestf, wmax, besti)) {
      unsigned long long key =
          ((unsigned long long)__float_as_uint(wmax) << 32) | (unsigned)(~besti);
      sslot[par ^ 1][w][0] = make_float4(__uint_as_float((unsigned)key),
                                         __uint_as_float((unsigned)(key >> 32)), bx, by);
      sslot[par ^ 1][w][1] = make_float4(bz, 0.0f, 0.0f, 0.0f);
    }
    __syncthreads();
    par ^= 1;
  }
  {
    float4 q0 = sslot[par][0][0];
    unsigned long long mk =
        ((unsigned long long)__float_as_uint(q0.y) << 32) | __float_as_uint(q0.x);
#pragma unroll
    for (int w2 = 1; w2 < W; ++w2) {
      float4 p0 = sslot[par][w2][0];
      unsigned long long k2 =
          ((unsigned long long)__float_as_uint(p0.y) << 32) | __float_as_uint(p0.x);
      if (k2 > mk) mk = k2;
    }
    if (t == 0) fid[NP - 1] = (int)(~(unsigned)mk);
  }
  __syncthreads();
  for (int s = t; s < NP; s += T) {
    int f = fid[s];
    nx[(size_t)b * 3 * NP + s] = base[f];
    nx[(size_t)b * 3 * NP + NP + s] = base[N + f];
    nx[(size_t)b * 3 * NP + 2 * NP + s] = base[2 * N + f];
  }
}

// ---------------- ball query ----------------
template <int NPTS, int NQ, int NS>
__global__ void bq_kernel(const float* __restrict__ pts, const float* __restrict__ qry,
                          float r2, int* __restrict__ gidx) {
  int gw = (blockIdx.x * blockDim.x + threadIdx.x) >> 6;
  int lane = threadIdx.x & 63;
  if (gw >= kB * NQ) return;
  int b = gw / NQ, s = gw - b * NQ;
  const float* pb = pts + (size_t)b * 3 * NPTS;
  float cx = qry[(size_t)b * 3 * NQ + s];
  float cy = qry[(size_t)b * 3 * NQ + NQ + s];
  float cz = qry[(size_t)b * 3 * NQ + 2 * NQ + s];
  float ss = fmaf(cz, cz, fmaf(cy, cy, __fmul_rn(cx, cx)));
  int* out = gidx + (size_t)gw * NS;
  int have = 0, first = 0;
  bool gotfirst = false;
  for (int n0 = 0; n0 < NPTS; n0 += 64) {
    int n = n0 + lane;
    float x = pb[n], y = pb[NPTS + n], z = pb[2 * NPTS + n];
    float dd = fmaf(z, z, fmaf(y, y, __fmul_rn(x, x)));
    float cross = fmaf(cz, z, fmaf(cy, y, __fmul_rn(cx, x)));
    float sqr = __fsub_rn(__fadd_rn(ss, dd), __fmul_rn(2.0f, cross));
    bool pred = !(sqr > r2);
    unsigned long long mask = __ballot(pred);
    if (!gotfirst && mask) { first = n0 + (__ffsll(mask) - 1); gotfirst = true; }
    if (pred) {
      int pos = have + __popcll(mask & ((1ull << lane) - 1ull));
      if (pos < NS) out[pos] = n;
    }
    have += __popcll(mask);
    if (have >= NS) break;
  }
  for (int slot = have + lane; slot < NS; slot += 64) out[slot] = first;
}

// ---------------- SA1 grouped MLP via bf16 MFMA ----------------
#define A1_STR 72
__global__ __launch_bounds__(256) void sa1_mfma_kernel(
    const float* __restrict__ xyz, const float* __restrict__ nx1,
    const int* __restrict__ gidx,
    const float* __restrict__ W0f, const float* __restrict__ bf0,
    const short* __restrict__ Q1, const float* __restrict__ bf1,
    const short* __restrict__ Q2, const float* __restrict__ bf2,
    float* __restrict__ l1_pts) {
  __shared__ short Abf[64 * A1_STR];
  int t = threadIdx.x;
  int lane = t & 63;
  int wg = t >> 6;
  int q0 = blockIdx.x * 2;
  {
    int row = t & 63;
    int q = q0 + (row >> 5);
    int b = q >> 9, s = q & 511;
    int sm = row & 31;
    int idx = gidx[(size_t)q * kNS1 + sm];
    float cx = nx1[b * 1536 + s];
    float cy = nx1[b * 1536 + 512 + s];
    float cz = nx1[b * 1536 + 1024 + s];
    const float* pb = xyz + (size_t)b * 3 * kN1;
    float f0 = pb[idx] - cx, f1 = pb[kN1 + idx] - cy, f2v = pb[2 * kN1 + idx] - cz;
#pragma unroll
    for (int j = 0; j < 16; ++j) {
      int col = wg * 16 + j;
      float4 w = *(const float4*)&W0f[col * 4];
      float v = fmaf(f2v, w.z, fmaf(f1, w.y, fmaf(f0, w.x, bf0[col])));
      Abf[row * A1_STR + col] = f2bf(fmaxf(v, 0.0f));
    }
  }
  __syncthreads();
  int lrow = lane & 15;
  int lgrp = (lane >> 4) * 8;
  {
    bf16x8 B0 = *(const bf16x8*)&Q1[(wg * 2 + 0) * 512 + lane * 8];
    bf16x8 B1 = *(const bf16x8*)&Q1[(wg * 2 + 1) * 512 + lane * 8];
    f32x4 acc[4];
    float bb = bf1[wg * 16 + lrow];
#pragma unroll
    for (int r = 0; r < 4; ++r) acc[r] = (f32x4){bb, bb, bb, bb};
#pragma unroll
    for (int r = 0; r < 4; ++r) {
      bf16x8 a0 = *(const bf16x8*)&Abf[(16 * r + lrow) * A1_STR + lgrp];
      bf16x8 a1 = *(const bf16x8*)&Abf[(16 * r + lrow) * A1_STR + 32 + lgrp];
      acc[r] = __builtin_amdgcn_mfma_f32_16x16x32_bf16(a0, B0, acc[r], 0, 0, 0);
      acc[r] = __builtin_amdgcn_mfma_f32_16x16x32_bf16(a1, B1, acc[r], 0, 0, 0);
    }
    __syncthreads();
#pragma unroll
    for (int r = 0; r < 4; ++r)
#pragma unroll
      for (int i = 0; i < 4; ++i) {
        int row = 16 * r + (lane >> 4) * 4 + i;
        Abf[row * A1_STR + wg * 16 + lrow] = f2bf(fmaxf(acc[r][i], 0.0f));
      }
    __syncthreads();
  }
  {
    bf16x8 B3[2][2];
#pragma unroll
    for (int c = 0; c < 2; ++c)
#pragma unroll
      for (int kt = 0; kt < 2; ++kt)
        B3[c][kt] = *(const bf16x8*)&Q2[((2 * wg + c) * 2 + kt) * 512 + lane * 8];
    f32x4 acc[4][2];
#pragma unroll
    for (int c = 0; c < 2; ++c) {
      float bb = bf2[(2 * wg + c) * 16 + lrow];
#pragma unroll
      for (int r = 0; r < 4; ++r) acc[r][c] = (f32x4){bb, bb, bb, bb};
    }
#pragma unroll
    for (int r = 0; r < 4; ++r) {
      bf16x8 a0 = *(const bf16x8*)&Abf[(16 * r + lrow) * A1_STR + lgrp];
      bf16x8 a1 = *(const bf16x8*)&Abf[(16 * r + lrow) * A1_STR + 32 + lgrp];
#pragma unroll
      for (int c = 0; c < 2; ++c) {
        acc[r][c] = __builtin_amdgcn_mfma_f32_16x16x32_bf16(a0, B3[c][0], acc[r][c], 0, 0, 0);
        acc[r][c] = __builtin_amdgcn_mfma_f32_16x16x32_bf16(a1, B3[c][1], acc[r][c], 0, 0, 0);
      }
    }
#pragma unroll
    for (int c = 0; c < 2; ++c) {
      float m0 = 0.0f, m1 = 0.0f;
#pragma unroll
      for (int i = 0; i < 4; ++i) {
        m0 = fmaxf(m0, fmaxf(acc[0][c][i], acc[1][c][i]));
        m1 = fmaxf(m1, fmaxf(acc[2][c][i], acc[3][c][i]));
      }
      m0 = fmaxf(m0, __shfl_xor(m0, 16, 64));
      m0 = fmaxf(m0, __shfl_xor(m0, 32, 64));
      m1 = fmaxf(m1, __shfl_xor(m1, 16, 64));
      m1 = fmaxf(m1, __shfl_xor(m1, 32, 64));
      int col = (2 * wg + c) * 16 + lrow;
      if (lane < 16) {
        l1_pts[(size_t)q0 * 128 + col] = m0;
        l1_pts[(size_t)(q0 + 1) * 128 + col] = m1;
      }
    }
  }
}

// ---------------- SA2 grouped MLP via bf16 MFMA ----------------
#define A_STR 168
__global__ __launch_bounds__(256) void sa2_mfma_kernel(
    const float* __restrict__ nx1, const float* __restrict__ l1_pts,
    const float* __restrict__ nx2, const int* __restrict__ gidx2,
    const short* __restrict__ P1, const float* __restrict__ bf1,
    const short* __restrict__ P2, const float* __restrict__ bf2,
    const short* __restrict__ P3, const float* __restrict__ bf3,
    float* __restrict__ l2_pts) {
  __shared__ short Abf[64 * A_STR];
  int t = threadIdx.x;
  int lane = t & 63;
  int wg = t >> 6;
  int q = blockIdx.x;
  int b = q >> 7, s = q & 127;
  int idx = gidx2[(size_t)q * kNS2 + lane];
  const float* pr = l1_pts + ((size_t)(b * kS1) + idx) * 128;
#pragma unroll
  for (int i = 0; i < 8; ++i) {
    float4 v = *(const float4*)&pr[wg * 32 + i * 4];
    unsigned lo = (unsigned)(unsigned short)f2bf(v.x) |
                  ((unsigned)(unsigned short)f2bf(v.y) << 16);
    unsigned hi = (unsigned)(unsigned short)f2bf(v.z) |
                  ((unsigned)(unsigned short)f2bf(v.w) << 16);
    *(uint2*)&Abf[lane * A_STR + wg * 32 + i * 4] = make_uint2(lo, hi);
  }
  if (wg == 0) {
    float cx = nx2[b * 384 + s];
    float cy = nx2[b * 384 + 128 + s];
    float cz = nx2[b * 384 + 256 + s];
    float f0 = nx1[b * 1536 + idx] - cx;
    float f1 = nx1[b * 1536 + 512 + idx] - cy;
    float f2v = nx1[b * 1536 + 1024 + idx] - cz;
    unsigned lo = (unsigned)(unsigned short)f2bf(f0) |
                  ((unsigned)(unsigned short)f2bf(f1) << 16);
    unsigned hi = (unsigned)(unsigned short)f2bf(f2v);
    *(uint2*)&Abf[lane * A_STR + 128] = make_uint2(lo, hi);
  }
  if (wg == 1) {
#pragma unroll
    for (int j = 0; j < 7; ++j)
      *(uint2*)&Abf[lane * A_STR + 132 + j * 4] = make_uint2(0u, 0u);
  }
  __syncthreads();
  int lrow = lane & 15;
  int lgrp = (lane >> 4) * 8;
  bf16x8 B1[2][5];
#pragma unroll
  for (int c = 0; c < 2; ++c)
#pragma unroll
    for (int kt = 0; kt < 5; ++kt)
      B1[c][kt] = *(const bf16x8*)&P1[(((2 * wg + c) * 5 + kt) * 512 + lane * 8)];
  f32x4 acc1[4][2];
  {
    float b0 = bf1[(2 * wg + 0) * 16 + lrow];
    float b1v = bf1[(2 * wg + 1) * 16 + lrow];
#pragma unroll
    for (int r = 0; r < 4; ++r) {
      acc1[r][0] = (f32x4){b0, b0, b0, b0};
      acc1[r][1] = (f32x4){b1v, b1v, b1v, b1v};
    }
  }
#pragma unroll
  for (int r = 0; r < 4; ++r) {
    bf16x8 a[5];
#pragma unroll
    for (int kt = 0; kt < 5; ++kt)
      a[kt] = *(const bf16x8*)&Abf[(16 * r + lrow) * A_STR + kt * 32 + lgrp];
#pragma unroll
    for (int kt = 0; kt < 5; ++kt) {
      acc1[r][0] = __builtin_amdgcn_mfma_f32_16x16x32_bf16(a[kt], B1[0][kt], acc1[r][0], 0, 0, 0);
      acc1[r][1] = __builtin_amdgcn_mfma_f32_16x16x32_bf16(a[kt], B1[1][kt], acc1[r][1], 0, 0, 0);
    }
  }
  __syncthreads();
#pragma unroll
  for (int r = 0; r < 4; ++r)
#pragma unroll
    for (int c = 0; c < 2; ++c)
#pragma unroll
      for (int i = 0; i < 4; ++i) {
        int row = 16 * r + (lane >> 4) * 4 + i;
        int col = (2 * wg + c) * 16 + lrow;
        Abf[row * A_STR + col] = f2bf(fmaxf(acc1[r][c][i], 0.0f));
      }
  __syncthreads();
  bf16x8 B2[2][4];
#pragma unroll
  for (int c = 0; c < 2; ++c)
#pragma unroll
    for (int kt = 0; kt < 4; ++kt)
      B2[c][kt] = *(const bf16x8*)&P2[(((2 * wg + c) * 4 + kt) * 512 + lane * 8)];
  f32x4 acc2[4][2];
  {
    float b0 = bf2[(2 * wg + 0) * 16 + lrow];
    float b1v = bf2[(2 * wg + 1) * 16 + lrow];
#pragma unroll
    for (int r = 0; r < 4; ++r) {
      acc2[r][0] = (f32x4){b0, b0, b0, b0};
      acc2[r][1] = (f32x4){b1v, b1v, b1v, b1v};
    }
  }
#pragma unroll
  for (int r = 0; r < 4; ++r) {
    bf16x8 a[4];
#pragma unroll
    for (int kt = 0; kt < 4; ++kt)
      a[kt] = *(const bf16x8*)&Abf[(16 * r + lrow) * A_STR + kt * 32 + lgrp];
#pragma unroll
    for (int kt = 0; kt < 4; ++kt) {
      acc2[r][0] = __builtin_amdgcn_mfma_f32_16x16x32_bf16(a[kt], B2[0][kt], acc2[r][0], 0, 0, 0);
      acc2[r][1] = __builtin_amdgcn_mfma_f32_16x16x32_bf16(a[kt], B2[1][kt], acc2[r][1], 0, 0, 0);
    }
  }
  __syncthreads();
#pragma unroll
  for (int r = 0; r < 4; ++r)
#pragma unroll
    for (int c = 0; c < 2; ++c)
#pragma unroll
      for (int i = 0; i < 4; ++i) {
        int row = 16 * r + (lane >> 4) * 4 + i;
        int col = (2 * wg + c) * 16 + lrow;
        Abf[row * A_STR + col] = f2bf(fmaxf(acc2[r][c][i], 0.0f));
      }
  __syncthreads();
  float* outp = l2_pts + (size_t)q * 256;
#pragma unroll
  for (int h = 0; h < 2; ++h) {
    int tn0 = 4 * wg + 2 * h;
    bf16x8 B3[2][4];
#pragma unroll
    for (int c = 0; c < 2; ++c)
#pragma unroll
      for (int kt = 0; kt < 4; ++kt)
        B3[c][kt] = *(const bf16x8*)&P3[(((tn0 + c) * 4 + kt) * 512 + lane * 8)];
    f32x4 acc3[4][2];
    {
      float b0 = bf3[(tn0 + 0) * 16 + lrow];
      float b1v = bf3[(tn0 + 1) * 16 + lrow];
#pragma unroll
      for (int r = 0; r < 4; ++r) {
        acc3[r][0] = (f32x4){b0, b0, b0, b0};
        acc3[r][1] = (f32x4){b1v, b1v, b1v, b1v};
      }
    }
#pragma unroll
    for (int r = 0; r < 4; ++r) {
      bf16x8 a[4];
#pragma unroll
      for (int kt = 0; kt < 4; ++kt)
        a[kt] = *(const bf16x8*)&Abf[(16 * r + lrow) * A_STR + kt * 32 + lgrp];
#pragma unroll
      for (int kt = 0; kt < 4; ++kt) {
        acc3[r][0] = __builtin_amdgcn_mfma_f32_16x16x32_bf16(a[kt], B3[0][kt], acc3[r][0], 0, 0, 0);
        acc3[r][1] = __builtin_amdgcn_mfma_f32_16x16x32_bf16(a[kt], B3[1][kt], acc3[r][1], 0, 0, 0);
      }
    }
#pragma unroll
    for (int c = 0; c < 2; ++c) {
      float m = 0.0f;
#pragma unroll
      for (int r = 0; r < 4; ++r)
#pragma unroll
        for (int i = 0; i < 4; ++i) m = fmaxf(m, acc3[r][c][i]);
      m = fmaxf(m, __shfl_xor(m, 16, 64));
      m = fmaxf(m, __shfl_xor(m, 32, 64));
      if (lane < 16) outp[(tn0 + c) * 16 + lane] = m;
    }
  }
}

// ---------------- SA3 via bf16 MFMA ----------------
__global__ void concat3bf_kernel(const float* __restrict__ nx2,
                                 const float* __restrict__ l2_pts,
                                 short* __restrict__ F0bf) {
  int i = blockIdx.x * 256 + threadIdx.x;
  if (i >= 4096 * 288) return;
  int row = i / 288, k = i - row * 288;
  int b = row >> 7, s = row & 127;
  float v;
  if (k < 3) v = nx2[b * 384 + k * 128 + s];
  else if (k < 259) v = l2_pts[(size_t)row * 256 + (k - 3)];
  else v = 0.0f;
  F0bf[i] = f2bf(v);
}

// Generic MFMA pass: M-tile = RT*16 rows (A preloaded to regs), N = 4*NTW*16.
template <int KT, int RT, int NTW, bool DOMAX>
__global__ __launch_bounds__(256) void g3_mfma_kernel(
    const short* __restrict__ Xbf, const short* __restrict__ BP,
    const float* __restrict__ bias, short* __restrict__ Ybf,
    float* __restrict__ outp) {
  constexpr int K = KT * 32;
  constexpr int ROWS = RT * 16;
  constexpr int AS = K + 8;
  constexpr int N = 4 * NTW * 16;
  __shared__ short Abf[ROWS * AS];
  int t = threadIdx.x, lane = t & 63, wg = t >> 6;
  int row0 = blockIdx.x * ROWS;
  {
    constexpr int TPR = 256 / ROWS;
    constexpr int CPT = K / TPR;
    int row = t & (ROWS - 1);
    int chunk = t / ROWS;
    const short* src = Xbf + (size_t)(row0 + row) * K + chunk * CPT;
    short* dstp = Abf + row * AS + chunk * CPT;
#pragma unroll
    for (int i = 0; i < CPT / 4; ++i)
      *(uint2*)&dstp[i * 4] = *(const uint2*)&src[i * 4];
  }
  __syncthreads();
  int lrow = lane & 15, lgrp = (lane >> 4) * 8;
  bf16x8 a[RT][KT];
#pragma unroll
  for (int r = 0; r < RT; ++r)
#pragma unroll
    for (int kt = 0; kt < KT; ++kt)
      a[r][kt] = *(const bf16x8*)&Abf[(16 * r + lrow) * AS + kt * 32 + lgrp];
  for (int h = 0; h < NTW; ++h) {
    int nt = wg * NTW + h;
    f32x4 acc[RT];
    float bb = bias[nt * 16 + lrow];
#pragma unroll
    for (int r = 0; r < RT; ++r) acc[r] = (f32x4){bb, bb, bb, bb};
#pragma unroll
    for (int kt = 0; kt < KT; ++kt) {
      bf16x8 Bf = *(const bf16x8*)&BP[((size_t)nt * KT + kt) * 512 + lane * 8];
#pragma unroll
      for (int r = 0; r < RT; ++r)
        acc[r] = __builtin_amdgcn_mfma_f32_16x16x32_bf16(a[r][kt], Bf, acc[r], 0, 0, 0);
    }
    if (!DOMAX) {
#pragma unroll
      for (int r = 0; r < RT; ++r)
#pragma unroll
        for (int i = 0; i < 4; ++i) {
          int row = 16 * r + (lane >> 4) * 4 + i;
          Ybf[(size_t)(row0 + row) * N + nt * 16 + lrow] = f2bf(fmaxf(acc[r][i], 0.0f));
        }
    } else {
      float m = 0.0f;
#pragma unroll
      for (int r = 0; r < RT; ++r)
#pragma unroll
        for (int i = 0; i < 4; ++i) m = fmaxf(m, acc[r][i]);
      m = fmaxf(m, __shfl_xor(m, 16, 64));
      m = fmaxf(m, __shfl_xor(m, 32, 64));
      if (lane < 16) {
        int b = row0 >> 7;
        atomicMax((unsigned*)&outp[(size_t)b * 1024 + nt * 16 + lrow],
                  __float_as_uint(m));
      }
    }
  }
}

// ---------------- launch ----------------
extern "C" void kernel_launch(void* const* d_in, const int* in_sizes, int n_in,
                              void* d_out, int out_size, void* d_ws, size_t ws_size,
                              hipStream_t stream) {
  (void)in_sizes; (void)n_in; (void)out_size; (void)ws_size;
  const float* xyz = (const float*)d_in[0];
  auto WP = [&](int layer, int part) -> const float* {
    return (const float*)d_in[1 + layer * 4 + part];
  };
  float* wsf = (float*)d_ws;
  size_t cur = 0;
  auto alloc = [&](size_t n) { size_t o = cur; cur += (n + 63) & ~(size_t)63; return o; };
  size_t o_nx1 = alloc((size_t)kB * 3 * kS1);
  size_t o_nx2 = alloc((size_t)kB * 3 * kS2);
  size_t o_l1pts = alloc((size_t)kB * kS1 * 128);
  size_t o_l2pts = alloc((size_t)kB * kS2 * 256);
  size_t o_s1w0 = alloc(64 * 4), o_s1b0 = alloc(64);
  size_t o_s1w1 = alloc(64 * 64), o_s1b1 = alloc(64);
  size_t o_s1wt2 = alloc(64 * 128), o_s1b2 = alloc(128);
  size_t o_s2w1 = alloc(132 * 128), o_s2b1 = alloc(128);
  size_t o_s2wt2 = alloc(128 * 128), o_s2b2 = alloc(128);
  size_t o_s2w3 = alloc(128 * 256), o_s2b3 = alloc(256);
  size_t o_s3wtA = alloc(260 * 256), o_s3bA = alloc(256);
  size_t o_s3wtB = alloc(256 * 512), o_s3bB = alloc(512);
  size_t o_s3wtC = alloc(512 * 1024), o_s3bC = alloc(1024);
  size_t o_gidx1 = alloc((size_t)kB * kS1 * kNS1);
  size_t o_gidx2 = alloc((size_t)kB * kS2 * kNS2);
  size_t o_p1 = alloc(10240);
  size_t o_p2 = alloc(8192);
  size_t o_p3 = alloc(16384);
  size_t o_q1 = alloc(2048);
  size_t o_q2 = alloc(4096);
  size_t o_ra = alloc(36864);     // 256*288 shorts
  size_t o_rb = alloc(65536);     // 512*256 shorts
  size_t o_rc = alloc(262144);    // 1024*512 shorts
  size_t o_f0bf = alloc(589824);  // 4096*288 shorts
  size_t o_y1bf = alloc(524288);  // 4096*256 shorts
  size_t o_y2bf = alloc(1048576); // 4096*512 shorts
  int* gidx1 = (int*)(wsf + o_gidx1);
  int* gidx2 = (int*)(wsf + o_gidx2);
  short* P1 = (short*)(wsf + o_p1);
  short* P2 = (short*)(wsf + o_p2);
  short* P3 = (short*)(wsf + o_p3);
  short* Q1 = (short*)(wsf + o_q1);
  short* Q2 = (short*)(wsf + o_q2);
  short* RA = (short*)(wsf + o_ra);
  short* RB = (short*)(wsf + o_rb);
  short* RC = (short*)(wsf + o_rc);
  short* F0bf = (short*)(wsf + o_f0bf);
  short* Y1bf = (short*)(wsf + o_y1bf);
  short* Y2bf = (short*)(wsf + o_y2bf);

  // fused fold of all 9 layers
  FoldPack fp;
  const int OKKp[9][3] = {{64, 3, 4},     {64, 64, 64},   {128, 64, 64},
                          {128, 131, 132}, {128, 128, 128}, {256, 128, 128},
                          {256, 259, 260}, {512, 256, 256}, {1024, 512, 512}};
  float* wouts[9] = {wsf + o_s1w0, wsf + o_s1w1, wsf + o_s1wt2,
                     wsf + o_s2w1, wsf + o_s2wt2, wsf + o_s2w3,
                     wsf + o_s3wtA, wsf + o_s3wtB, wsf + o_s3wtC};
  float* bouts[9] = {wsf + o_s1b0, wsf + o_s1b1, wsf + o_s1b2,
                     wsf + o_s2b1, wsf + o_s2b2, wsf + o_s2b3,
                     wsf + o_s3bA, wsf + o_s3bB, wsf + o_s3bC};
  const int nblk[9] = {1, 4, 8, 17, 16, 32, 65, 128, 512};
  fp.cum[0] = 0;
  for (int L = 0; L < 9; ++L) {
    fp.d[L].W = WP(L, 0);
    fp.d[L].b = WP(L, 1);
    fp.d[L].g = WP(L, 2);
    fp.d[L].bt = WP(L, 3);
    fp.d[L].Wout = wouts[L];
    fp.d[L].bout = bouts[L];
    fp.d[L].O = OKKp[L][0];
    fp.d[L].K = OKKp[L][1];
    fp.d[L].Kp = OKKp[L][2];
    fp.d[L].transposed = (L == 0) ? 0 : 1;
    fp.cum[L + 1] = fp.cum[L] + nblk[L];
  }
  foldall_kernel<<<fp.cum[9], 256, 0, stream>>>(fp);

  // fused pack of all MFMA weight buffers
  PackPack pp;
  const float* psrc[8] = {wsf + o_s1w1, wsf + o_s1wt2, wsf + o_s2w1, wsf + o_s2wt2,
                          wsf + o_s2w3, wsf + o_s3wtA, wsf + o_s3wtB, wsf + o_s3wtC};
  short* pdst[8] = {Q1, Q2, P1, P2, P3, RA, RB, RC};
  const int pO[8] = {64, 128, 128, 128, 256, 256, 512, 1024};
  const int pKp[8] = {64, 64, 160, 128, 128, 288, 256, 512};
  const int pMode[8] = {0, 0, 1, 0, 0, 0, 0, 0};
  const int pKr[8] = {64, 64, 0, 128, 128, 260, 256, 512};
  pp.cum[0] = 0;
  for (int L = 0; L < 8; ++L) {
    pp.j[L].W = psrc[L];
    pp.j[L].dst = pdst[L];
    pp.j[L].O = pO[L];
    pp.j[L].Kpad = pKp[L];
    pp.j[L].mode = pMode[L];
    pp.j[L].Kreal = pKr[L];
    pp.cum[L + 1] = pp.cum[L] + (pO[L] * pKp[L] + 255) / 256;
  }
  packall_kernel<<<pp.cum[8], 256, 0, stream>>>(pp);

  // SA1
  fps16_kernel<kN1, kS1, 256><<<kB, 256, 0, stream>>>(xyz, wsf + o_nx1);
  bq_kernel<kN1, kS1, kNS1><<<(kB * kS1) / 4, 256, 0, stream>>>(xyz, wsf + o_nx1, 0.04f, gidx1);
  sa1_mfma_kernel<<<(kB * kS1) / 2, 256, 0, stream>>>(
      xyz, wsf + o_nx1, gidx1,
      wsf + o_s1w0, wsf + o_s1b0, Q1, wsf + o_s1b1, Q2, wsf + o_s1b2,
      wsf + o_l1pts);

  // SA2
  fps4_kernel<kS1, kS2, 128><<<kB, 128, 0, stream>>>(wsf + o_nx1, wsf + o_nx2);
  bq_kernel<kS1, kS2, kNS2><<<(kB * kS2) / 4, 256, 0, stream>>>(wsf + o_nx1, wsf + o_nx2, 0.16f, gidx2);
  sa2_mfma_kernel<<<kB * kS2, 256, 0, stream>>>(
      wsf + o_nx1, wsf + o_l1pts, wsf + o_nx2, gidx2,
      P1, wsf + o_s2b1, P2, wsf + o_s2b2, P3, wsf + o_s2b3,
      wsf + o_l2pts);

  // SA3 (group all) via MFMA
  concat3bf_kernel<<<4608, 256, 0, stream>>>(wsf + o_nx2, wsf + o_l2pts, F0bf);
  g3_mfma_kernel<9, 4, 4, false><<<64, 256, 0, stream>>>(
      F0bf, RA, wsf + o_s3bA, Y1bf, (float*)nullptr);
  g3_mfma_kernel<8, 4, 8, false><<<64, 256, 0, stream>>>(
      Y1bf, RB, wsf + o_s3bB, Y2bf, (float*)nullptr);
  hipMemsetAsync(d_out, 0, (size_t)kB * 1024 * sizeof(float), stream);
  g3_mfma_kernel<16, 2, 16, true><<<128, 256, 0, stream>>>(
      Y2bf, RC, wsf + o_s3bC, (short*)nullptr, (float*)d_out);
}

// Round 22
// 585.449 us; speedup vs baseline: 2.6203x; 1.0304x over previous
//
#include <hip/hip_runtime.h>
#include <hip/hip_bf16.h>
#include <cstddef>
#include <math.h>

#define kB 32
#define kN1 4096
#define kS1 512
#define kNS1 32
#define kS2 128
#define kNS2 64

typedef short bf16x8 __attribute__((ext_vector_type(8)));
typedef float f32x4 __attribute__((ext_vector_type(4)));
typedef float f32x2 __attribute__((ext_vector_type(2)));

__device__ __forceinline__ short f2bf(float f) {   // RTN-even fp32 -> bf16 bits
  unsigned u = __float_as_uint(f);
  unsigned r = (u + 0x7fffu + ((u >> 16) & 1u)) >> 16;
  return (short)r;
}

// ---------------- fused weight folding for all 9 layers ----------------
struct FoldDesc {
  const float *W, *b, *g, *bt;
  float *Wout, *bout;
  int O, K, Kp, transposed;
};
struct FoldPack {
  FoldDesc d[9];
  int cum[10];
};

__global__ __launch_bounds__(256) void foldall_kernel(FoldPack p) {
  int blk = blockIdx.x;
  int L = 0;
#pragma unroll
  for (int i = 0; i < 9; ++i)
    if (blk >= p.cum[i + 1]) L = i + 1;
  FoldDesc d = p.d[L];
  int nb = p.cum[L + 1] - p.cum[L];
  int tid = (blk - p.cum[L]) * 256 + threadIdx.x;
  int stride = nb * 256;
  float inv = 1.0f / sqrtf(1.0f + 1e-5f);
  for (int i = tid; i < d.O * d.Kp; i += stride) {
    int o = i / d.Kp, k = i - o * d.Kp;
    float s = d.g[o] * inv;
    float w = (k < d.K) ? d.W[o * d.K + k] * s : 0.0f;
    if (d.transposed) d.Wout[k * d.O + o] = w;
    else d.Wout[o * d.Kp + k] = w;
  }
  for (int o = tid; o < d.O; o += stride) {
    d.bout[o] = d.b[o] * (d.g[o] * inv) + d.bt[o];
  }
}

// ---------------- fused packing of all MFMA weight buffers ----------------
struct PackJob { const float* W; short* dst; int O, Kpad, mode, Kreal; };
struct PackPack { PackJob j[8]; int cum[9]; };

__global__ __launch_bounds__(256) void packall_kernel(PackPack p) {
  int blk = blockIdx.x;
  int L = 0;
#pragma unroll
  for (int i = 0; i < 8; ++i)
    if (blk >= p.cum[i + 1]) L = i + 1;
  PackJob d = p.j[L];
  int e = (blk - p.cum[L]) * 256 + threadIdx.x;
  if (e >= d.O * d.Kpad) return;
  int i = e & 7, lane = (e >> 3) & 63, tile = e >> 9;
  int KT = d.Kpad / 32;
  int tn = tile / KT, tk = tile - tn * KT;
  int kk = tk * 32 + ((lane >> 4) & 3) * 8 + i;
  int n = tn * 16 + (lane & 15);
  float v;
  if (d.mode == 1) {
    int ok = (kk < 128) ? kk + 3 : ((kk < 131) ? kk - 128 : -1);
    v = (ok < 0) ? 0.0f : d.W[ok * d.O + n];
  } else {
    v = (kk < d.Kreal) ? d.W[kk * d.O + n] : 0.0f;
  }
  d.dst[e] = f2bf(v);
}

// Canonical CDNA wave64 f32 max via DPP (VALU pipe only).
__device__ __forceinline__ float wave_max_f32_nonneg(float x) {
#define DPP_MAXSTEP(CTRL)                                                     \
  {                                                                           \
    int o = __builtin_amdgcn_update_dpp(0, __float_as_int(x), (CTRL), 0xf, 0xf, true); \
    x = fmaxf(x, __int_as_float(o));                                          \
  }
  DPP_MAXSTEP(0x111)
  DPP_MAXSTEP(0x112)
  DPP_MAXSTEP(0x114)
  DPP_MAXSTEP(0x118)
  DPP_MAXSTEP(0x142)
  DPP_MAXSTEP(0x143)
#undef DPP_MAXSTEP
  return __int_as_float(__builtin_amdgcn_readlane(__float_as_int(x), 63));
}

__device__ __forceinline__ bool fps_pub_lane(float bestf, float wmax, int besti) {
  unsigned long long m = __ballot(bestf == wmax);
  if (__popcll(m) == 1) return bestf == wmax;
  unsigned long long mm = m;
  int bidx = 0x7fffffff;
  while (mm) {
    int l = __ffsll(mm) - 1;
    int bi = __shfl(besti, l, 64);
    bidx = min(bidx, bi);
    mm &= mm - 1;
  }
  return (bestf == wmax) && (besti == bidx);
}

// ---------------- farthest point sampling ----------------
// fps16: coords in LDS as float4 groups, dd register-resident, key-only u64
// winner slots, DPP wave-max, packed-f32 dist. Iteration restructured so the
// 12 loop-invariant coord b128 loads are ISSUED right after the 4 skey reads
// (before the compare chain): their ~576-cyc LDS drain overlaps the scan +
// centroid dependent chain instead of serializing after it.
#define FPS_E2L(DDV, CA, CB, XA, XB, YA, YB, ZA, ZB, I0)                     \
  {                                                                          \
    f32x2 dx = (f32x2){(XA), (XB)} - cx2;                                    \
    f32x2 dy = (f32x2){(YA), (YB)} - cy2;                                    \
    f32x2 dz = (f32x2){(ZA), (ZB)} - cz2;                                    \
    f32x2 d = __builtin_elementwise_fma(                                     \
        dz, dz, __builtin_elementwise_fma(dy, dy, dx * dx));                 \
    float nda = fminf(DDV.CA, d.x);                                          \
    DDV.CA = nda;                                                            \
    if (nda > bestf) { bestf = nda; besti = (I0); }                          \
    float ndb = fminf(DDV.CB, d.y);                                          \
    DDV.CB = ndb;                                                            \
    if (ndb > bestf) { bestf = ndb; besti = (I0) + 1; }                      \
  }

#define FPS_GRPL(V, XG, YG, ZG, IB)                                          \
  {                                                                          \
    FPS_E2L(dd##V, x, y, XG.x, XG.y, YG.x, YG.y, ZG.x, ZG.y, (IB))           \
    FPS_E2L(dd##V, z, w, XG.z, XG.w, YG.z, YG.w, ZG.z, ZG.w, (IB) + 2)       \
  }

template <int N, int NP, int T>
__global__ __launch_bounds__(T, 1) void fps16_kernel(const float* __restrict__ xyz,
                                                     float* __restrict__ nx) {
  static_assert(N == 16 * T, "fps16: need exactly 16 points per thread");
  constexpr int W = T / 64;
  static_assert(W == 4, "fps16 loop specialized for 4 waves");
  __shared__ float4 sx4[N / 4], sy4[N / 4], sz4[N / 4];
  __shared__ unsigned long long skey[2][W];
  __shared__ int fid[NP];
  int b = blockIdx.x, t = threadIdx.x;
  int w = t >> 6;
  const float* base = xyz + (size_t)b * 3 * N;
  float* sxf = (float*)sx4;
  float* syf = (float*)sy4;
  float* szf = (float*)sz4;
  for (int i = t; i < N; i += T) sxf[i] = base[i];
  for (int i = t; i < N; i += T) syf[i] = base[N + i];
  for (int i = t; i < N; i += T) szf[i] = base[2 * N + i];
  float4 dd0, dd1, dd2, dd3;
  dd0 = dd1 = dd2 = dd3 = make_float4(1e10f, 1e10f, 1e10f, 1e10f);
  if (t < W) skey[0][t] = (t == 0) ? ~0ull : 0ull;
  if (t == 0) fid[0] = 0;
  int par = 0;
  __syncthreads();
  for (int it = 1; it < NP; ++it) {
    // (1) skey reads issued first (waited via lgkmcnt(12) while coords drain)
    unsigned long long k0 = skey[par][0];
    unsigned long long k1 = skey[par][1];
    unsigned long long k2v = skey[par][2];
    unsigned long long k3 = skey[par][3];
    // (2) all coord loads issued now -- loop-invariant addresses, no deps
    float4 xg0 = sx4[t];         float4 xg1 = sx4[t + T];
    float4 xg2 = sx4[t + 2 * T]; float4 xg3 = sx4[t + 3 * T];
    float4 yg0 = sy4[t];         float4 yg1 = sy4[t + T];
    float4 yg2 = sy4[t + 2 * T]; float4 yg3 = sy4[t + 3 * T];
    float4 zg0 = sz4[t];         float4 zg1 = sz4[t + T];
    float4 zg2 = sz4[t + 2 * T]; float4 zg3 = sz4[t + 3 * T];
    // (3) scan compare chain (only needs k0..k3)
    unsigned long long mk = k0;
    if (k1 > mk) mk = k1;
    if (k2v > mk) mk = k2v;
    if (k3 > mk) mk = k3;
    int wi = (int)(~(unsigned)mk);
    if (t == 0) fid[it - 1] = wi;
    // (4) centroid fetch by index
    float cx = sxf[wi], cy = syf[wi], cz = szf[wi];
    f32x2 cx2 = (f32x2){cx, cx};
    f32x2 cy2 = (f32x2){cy, cy};
    f32x2 cz2 = (f32x2){cz, cz};
    // (5) packed dist update from preloaded locals
    float bestf = -1.0f;
    int besti = 4 * t;
    FPS_GRPL(0, xg0, yg0, zg0, 4 * t)
    FPS_GRPL(1, xg1, yg1, zg1, 4 * (t + T))
    FPS_GRPL(2, xg2, yg2, zg2, 4 * (t + 2 * T))
    FPS_GRPL(3, xg3, yg3, zg3, 4 * (t + 3 * T))
    float wmax = wave_max_f32_nonneg(bestf);
    if (fps_pub_lane(bestf, wmax, besti)) {
      skey[par ^ 1][w] =
          ((unsigned long long)__float_as_uint(wmax) << 32) | (unsigned)(~besti);
    }
    __syncthreads();
    par ^= 1;
  }
  {
    unsigned long long mk = skey[par][0];
#pragma unroll
    for (int w2 = 1; w2 < W; ++w2) {
      unsigned long long k2 = skey[par][w2];
      if (k2 > mk) mk = k2;
    }
    if (t == 0) fid[NP - 1] = (int)(~(unsigned)mk);
  }
  __syncthreads();
  for (int s = t; s < NP; s += T) {
    int f = fid[s];
    nx[(size_t)b * 3 * NP + s] = sxf[f];
    nx[(size_t)b * 3 * NP + NP + s] = syf[f];
    nx[(size_t)b * 3 * NP + 2 * NP + s] = szf[f];
  }
}

#define FPS_STEP(V, C, IDXOFF)                                               \
  {                                                                          \
    float dx = __fsub_rn(px##V.C, cx);                                       \
    float dy = __fsub_rn(py##V.C, cy);                                       \
    float dz = __fsub_rn(pz##V.C, cz);                                       \
    float d = fmaf(dz, dz, fmaf(dy, dy, __fmul_rn(dx, dx)));                 \
    float nd = fminf(dd##V.C, d);                                            \
    dd##V.C = nd;                                                            \
    if (nd > bestf) {                                                        \
      bestf = nd; besti = t + (IDXOFF); bx = px##V.C; by = py##V.C; bz = pz##V.C; \
    }                                                                        \
  }

#define FPS_LD4(arr, src, off) \
  arr = make_float4((src)[(off)], (src)[(off) + T], (src)[(off) + 2 * T], (src)[(off) + 3 * T])

template <int N, int NP, int T>
__global__ __launch_bounds__(T, 1) void fps4_kernel(const float* __restrict__ xyz,
                                                    float* __restrict__ nx) {
  static_assert(N == 4 * T, "fps4: need exactly 4 points per thread");
  constexpr int W = T / 64;
  __shared__ float4 sslot[2][W][2];
  __shared__ int fid[NP];
  int b = blockIdx.x, t = threadIdx.x;
  int w = t >> 6;
  const float* base = xyz + (size_t)b * 3 * N;
  float4 px0, py0, pz0, dd0;
  FPS_LD4(px0, base, t);
  FPS_LD4(py0, base + N, t);
  FPS_LD4(pz0, base + 2 * N, t);
  dd0 = make_float4(1e10f, 1e10f, 1e10f, 1e10f);
  if (t == 0) {
    fid[0] = 0;
    unsigned long long k0 = ~0ull;
    sslot[0][0][0] = make_float4(__uint_as_float((unsigned)k0),
                                 __uint_as_float((unsigned)(k0 >> 32)), px0.x, py0.x);
    sslot[0][0][1] = make_float4(pz0.x, 0.0f, 0.0f, 0.0f);
  }
  if (t >= 64 && (t & 63) == 0) {
    sslot[0][w][0] = make_float4(0.0f, 0.0f, 0.0f, 0.0f);
    sslot[0][w][1] = make_float4(0.0f, 0.0f, 0.0f, 0.0f);
  }
  int par = 0;
  __syncthreads();
  for (int it = 1; it < NP; ++it) {
    float4 q0 = sslot[par][0][0];
    float4 q1 = sslot[par][0][1];
    unsigned long long mk =
        ((unsigned long long)__float_as_uint(q0.y) << 32) | __float_as_uint(q0.x);
    float cx = q0.z, cy = q0.w, cz = q1.x;
#pragma unroll
    for (int w2 = 1; w2 < W; ++w2) {
      float4 p0 = sslot[par][w2][0];
      float4 p1 = sslot[par][w2][1];
      unsigned long long k2 =
          ((unsigned long long)__float_as_uint(p0.y) << 32) | __float_as_uint(p0.x);
      if (k2 > mk) { mk = k2; cx = p0.z; cy = p0.w; cz = p1.x; }
    }
    if (t == 0) fid[it - 1] = (int)(~(unsigned)mk);
    float bestf = -1.0f;
    int besti = t;
    float bx = px0.x, by = py0.x, bz = pz0.x;
    FPS_STEP(0, x, 0) FPS_STEP(0, y, T) FPS_STEP(0, z, 2 * T) FPS_STEP(0, w, 3 * T)
    float wmax = wave_max_f32_nonneg(bestf);
    if (fps_pub_lane(bestf, wmax, besti)) {
      unsigned long long key =
          ((unsigned long long)__float_as_uint(wmax) << 32) | (unsigned)(~besti);
      sslot[par ^ 1][w][0] = make_float4(__uint_as_float((unsigned)key),
                                         __uint_as_float((unsigned)(key >> 32)), bx, by);
      sslot[par ^ 1][w][1] = make_float4(bz, 0.0f, 0.0f, 0.0f);
    }
    __syncthreads();
    par ^= 1;
  }
  {
    float4 q0 = sslot[par][0][0];
    unsigned long long mk =
        ((unsigned long long)__float_as_uint(q0.y) << 32) | __float_as_uint(q0.x);
#pragma unroll
    for (int w2 = 1; w2 < W; ++w2) {
      float4 p0 = sslot[par][w2][0];
      unsigned long long k2 =
          ((unsigned long long)__float_as_uint(p0.y) << 32) | __float_as_uint(p0.x);
      if (k2 > mk) mk = k2;
    }
    if (t == 0) fid[NP - 1] = (int)(~(unsigned)mk);
  }
  __syncthreads();
  for (int s = t; s < NP; s += T) {
    int f = fid[s];
    nx[(size_t)b * 3 * NP + s] = base[f];
    nx[(size_t)b * 3 * NP + NP + s] = base[N + f];
    nx[(size_t)b * 3 * NP + 2 * NP + s] = base[2 * N + f];
  }
}

// ---------------- ball query ----------------
template <int NPTS, int NQ, int NS>
__global__ void bq_kernel(const float* __restrict__ pts, const float* __restrict__ qry,
                          float r2, int* __restrict__ gidx) {
  int gw = (blockIdx.x * blockDim.x + threadIdx.x) >> 6;
  int lane = threadIdx.x & 63;
  if (gw >= kB * NQ) return;
  int b = gw / NQ, s = gw - b * NQ;
  const float* pb = pts + (size_t)b * 3 * NPTS;
  float cx = qry[(size_t)b * 3 * NQ + s];
  float cy = qry[(size_t)b * 3 * NQ + NQ + s];
  float cz = qry[(size_t)b * 3 * NQ + 2 * NQ + s];
  float ss = fmaf(cz, cz, fmaf(cy, cy, __fmul_rn(cx, cx)));
  int* out = gidx + (size_t)gw * NS;
  int have = 0, first = 0;
  bool gotfirst = false;
  for (int n0 = 0; n0 < NPTS; n0 += 64) {
    int n = n0 + lane;
    float x = pb[n], y = pb[NPTS + n], z = pb[2 * NPTS + n];
    float dd = fmaf(z, z, fmaf(y, y, __fmul_rn(x, x)));
    float cross = fmaf(cz, z, fmaf(cy, y, __fmul_rn(cx, x)));
    float sqr = __fsub_rn(__fadd_rn(ss, dd), __fmul_rn(2.0f, cross));
    bool pred = !(sqr > r2);
    unsigned long long mask = __ballot(pred);
    if (!gotfirst && mask) { first = n0 + (__ffsll(mask) - 1); gotfirst = true; }
    if (pred) {
      int pos = have + __popcll(mask & ((1ull << lane) - 1ull));
      if (pos < NS) out[pos] = n;
    }
    have += __popcll(mask);
    if (have >= NS) break;
  }
  for (int slot = have + lane; slot < NS; slot += 64) out[slot] = first;
}

// ---------------- SA1 grouped MLP via bf16 MFMA ----------------
#define A1_STR 72
__global__ __launch_bounds__(256) void sa1_mfma_kernel(
    const float* __restrict__ xyz, const float* __restrict__ nx1,
    const int* __restrict__ gidx,
    const float* __restrict__ W0f, const float* __restrict__ bf0,
    const short* __restrict__ Q1, const float* __restrict__ bf1,
    const short* __restrict__ Q2, const float* __restrict__ bf2,
    float* __restrict__ l1_pts) {
  __shared__ short Abf[64 * A1_STR];
  int t = threadIdx.x;
  int lane = t & 63;
  int wg = t >> 6;
  int q0 = blockIdx.x * 2;
  {
    int row = t & 63;
    int q = q0 + (row >> 5);
    int b = q >> 9, s = q & 511;
    int sm = row & 31;
    int idx = gidx[(size_t)q * kNS1 + sm];
    float cx = nx1[b * 1536 + s];
    float cy = nx1[b * 1536 + 512 + s];
    float cz = nx1[b * 1536 + 1024 + s];
    const float* pb = xyz + (size_t)b * 3 * kN1;
    float f0 = pb[idx] - cx, f1 = pb[kN1 + idx] - cy, f2v = pb[2 * kN1 + idx] - cz;
#pragma unroll
    for (int j = 0; j < 16; ++j) {
      int col = wg * 16 + j;
      float4 w = *(const float4*)&W0f[col * 4];
      float v = fmaf(f2v, w.z, fmaf(f1, w.y, fmaf(f0, w.x, bf0[col])));
      Abf[row * A1_STR + col] = f2bf(fmaxf(v, 0.0f));
    }
  }
  __syncthreads();
  int lrow = lane & 15;
  int lgrp = (lane >> 4) * 8;
  {
    bf16x8 B0 = *(const bf16x8*)&Q1[(wg * 2 + 0) * 512 + lane * 8];
    bf16x8 B1 = *(const bf16x8*)&Q1[(wg * 2 + 1) * 512 + lane * 8];
    f32x4 acc[4];
    float bb = bf1[wg * 16 + lrow];
#pragma unroll
    for (int r = 0; r < 4; ++r) acc[r] = (f32x4){bb, bb, bb, bb};
#pragma unroll
    for (int r = 0; r < 4; ++r) {
      bf16x8 a0 = *(const bf16x8*)&Abf[(16 * r + lrow) * A1_STR + lgrp];
      bf16x8 a1 = *(const bf16x8*)&Abf[(16 * r + lrow) * A1_STR + 32 + lgrp];
      acc[r] = __builtin_amdgcn_mfma_f32_16x16x32_bf16(a0, B0, acc[r], 0, 0, 0);
      acc[r] = __builtin_amdgcn_mfma_f32_16x16x32_bf16(a1, B1, acc[r], 0, 0, 0);
    }
    __syncthreads();
#pragma unroll
    for (int r = 0; r < 4; ++r)
#pragma unroll
      for (int i = 0; i < 4; ++i) {
        int row = 16 * r + (lane >> 4) * 4 + i;
        Abf[row * A1_STR + wg * 16 + lrow] = f2bf(fmaxf(acc[r][i], 0.0f));
      }
    __syncthreads();
  }
  {
    bf16x8 B3[2][2];
#pragma unroll
    for (int c = 0; c < 2; ++c)
#pragma unroll
      for (int kt = 0; kt < 2; ++kt)
        B3[c][kt] = *(const bf16x8*)&Q2[((2 * wg + c) * 2 + kt) * 512 + lane * 8];
    f32x4 acc[4][2];
#pragma unroll
    for (int c = 0; c < 2; ++c) {
      float bb = bf2[(2 * wg + c) * 16 + lrow];
#pragma unroll
      for (int r = 0; r < 4; ++r) acc[r][c] = (f32x4){bb, bb, bb, bb};
    }
#pragma unroll
    for (int r = 0; r < 4; ++r) {
      bf16x8 a0 = *(const bf16x8*)&Abf[(16 * r + lrow) * A1_STR + lgrp];
      bf16x8 a1 = *(const bf16x8*)&Abf[(16 * r + lrow) * A1_STR + 32 + lgrp];
#pragma unroll
      for (int c = 0; c < 2; ++c) {
        acc[r][c] = __builtin_amdgcn_mfma_f32_16x16x32_bf16(a0, B3[c][0], acc[r][c], 0, 0, 0);
        acc[r][c] = __builtin_amdgcn_mfma_f32_16x16x32_bf16(a1, B3[c][1], acc[r][c], 0, 0, 0);
      }
    }
#pragma unroll
    for (int c = 0; c < 2; ++c) {
      float m0 = 0.0f, m1 = 0.0f;
#pragma unroll
      for (int i = 0; i < 4; ++i) {
        m0 = fmaxf(m0, fmaxf(acc[0][c][i], acc[1][c][i]));
        m1 = fmaxf(m1, fmaxf(acc[2][c][i], acc[3][c][i]));
      }
      m0 = fmaxf(m0, __shfl_xor(m0, 16, 64));
      m0 = fmaxf(m0, __shfl_xor(m0, 32, 64));
      m1 = fmaxf(m1, __shfl_xor(m1, 16, 64));
      m1 = fmaxf(m1, __shfl_xor(m1, 32, 64));
      int col = (2 * wg + c) * 16 + lrow;
      if (lane < 16) {
        l1_pts[(size_t)q0 * 128 + col] = m0;
        l1_pts[(size_t)(q0 + 1) * 128 + col] = m1;
      }
    }
  }
}

// ---------------- SA2 grouped MLP via bf16 MFMA ----------------
#define A_STR 168
__global__ __launch_bounds__(256) void sa2_mfma_kernel(
    const float* __restrict__ nx1, const float* __restrict__ l1_pts,
    const float* __restrict__ nx2, const int* __restrict__ gidx2,
    const short* __restrict__ P1, const float* __restrict__ bf1,
    const short* __restrict__ P2, const float* __restrict__ bf2,
    const short* __restrict__ P3, const float* __restrict__ bf3,
    float* __restrict__ l2_pts) {
  __shared__ short Abf[64 * A_STR];
  int t = threadIdx.x;
  int lane = t & 63;
  int wg = t >> 6;
  int q = blockIdx.x;
  int b = q >> 7, s = q & 127;
  int idx = gidx2[(size_t)q * kNS2 + lane];
  const float* pr = l1_pts + ((size_t)(b * kS1) + idx) * 128;
#pragma unroll
  for (int i = 0; i < 8; ++i) {
    float4 v = *(const float4*)&pr[wg * 32 + i * 4];
    unsigned lo = (unsigned)(unsigned short)f2bf(v.x) |
                  ((unsigned)(unsigned short)f2bf(v.y) << 16);
    unsigned hi = (unsigned)(unsigned short)f2bf(v.z) |
                  ((unsigned)(unsigned short)f2bf(v.w) << 16);
    *(uint2*)&Abf[lane * A_STR + wg * 32 + i * 4] = make_uint2(lo, hi);
  }
  if (wg == 0) {
    float cx = nx2[b * 384 + s];
    float cy = nx2[b * 384 + 128 + s];
    float cz = nx2[b * 384 + 256 + s];
    float f0 = nx1[b * 1536 + idx] - cx;
    float f1 = nx1[b * 1536 + 512 + idx] - cy;
    float f2v = nx1[b * 1536 + 1024 + idx] - cz;
    unsigned lo = (unsigned)(unsigned short)f2bf(f0) |
                  ((unsigned)(unsigned short)f2bf(f1) << 16);
    unsigned hi = (unsigned)(unsigned short)f2bf(f2v);
    *(uint2*)&Abf[lane * A_STR + 128] = make_uint2(lo, hi);
  }
  if (wg == 1) {
#pragma unroll
    for (int j = 0; j < 7; ++j)
      *(uint2*)&Abf[lane * A_STR + 132 + j * 4] = make_uint2(0u, 0u);
  }
  __syncthreads();
  int lrow = lane & 15;
  int lgrp = (lane >> 4) * 8;
  bf16x8 B1[2][5];
#pragma unroll
  for (int c = 0; c < 2; ++c)
#pragma unroll
    for (int kt = 0; kt < 5; ++kt)
      B1[c][kt] = *(const bf16x8*)&P1[(((2 * wg + c) * 5 + kt) * 512 + lane * 8)];
  f32x4 acc1[4][2];
  {
    float b0 = bf1[(2 * wg + 0) * 16 + lrow];
    float b1v = bf1[(2 * wg + 1) * 16 + lrow];
#pragma unroll
    for (int r = 0; r < 4; ++r) {
      acc1[r][0] = (f32x4){b0, b0, b0, b0};
      acc1[r][1] = (f32x4){b1v, b1v, b1v, b1v};
    }
  }
#pragma unroll
  for (int r = 0; r < 4; ++r) {
    bf16x8 a[5];
#pragma unroll
    for (int kt = 0; kt < 5; ++kt)
      a[kt] = *(const bf16x8*)&Abf[(16 * r + lrow) * A_STR + kt * 32 + lgrp];
#pragma unroll
    for (int kt = 0; kt < 5; ++kt) {
      acc1[r][0] = __builtin_amdgcn_mfma_f32_16x16x32_bf16(a[kt], B1[0][kt], acc1[r][0], 0, 0, 0);
      acc1[r][1] = __builtin_amdgcn_mfma_f32_16x16x32_bf16(a[kt], B1[1][kt], acc1[r][1], 0, 0, 0);
    }
  }
  __syncthreads();
#pragma unroll
  for (int r = 0; r < 4; ++r)
#pragma unroll
    for (int c = 0; c < 2; ++c)
#pragma unroll
      for (int i = 0; i < 4; ++i) {
        int row = 16 * r + (lane >> 4) * 4 + i;
        int col = (2 * wg + c) * 16 + lrow;
        Abf[row * A_STR + col] = f2bf(fmaxf(acc1[r][c][i], 0.0f));
      }
  __syncthreads();
  bf16x8 B2[2][4];
#pragma unroll
  for (int c = 0; c < 2; ++c)
#pragma unroll
    for (int kt = 0; kt < 4; ++kt)
      B2[c][kt] = *(const bf16x8*)&P2[(((2 * wg + c) * 4 + kt) * 512 + lane * 8)];
  f32x4 acc2[4][2];
  {
    float b0 = bf2[(2 * wg + 0) * 16 + lrow];
    float b1v = bf2[(2 * wg + 1) * 16 + lrow];
#pragma unroll
    for (int r = 0; r < 4; ++r) {
      acc2[r][0] = (f32x4){b0, b0, b0, b0};
      acc2[r][1] = (f32x4){b1v, b1v, b1v, b1v};
    }
  }
#pragma unroll
  for (int r = 0; r < 4; ++r) {
    bf16x8 a[4];
#pragma unroll
    for (int kt = 0; kt < 4; ++kt)
      a[kt] = *(const bf16x8*)&Abf[(16 * r + lrow) * A_STR + kt * 32 + lgrp];
#pragma unroll
    for (int kt = 0; kt < 4; ++kt) {
      acc2[r][0] = __builtin_amdgcn_mfma_f32_16x16x32_bf16(a[kt], B2[0][kt], acc2[r][0], 0, 0, 0);
      acc2[r][1] = __builtin_amdgcn_mfma_f32_16x16x32_bf16(a[kt], B2[1][kt], acc2[r][1], 0, 0, 0);
    }
  }
  __syncthreads();
#pragma unroll
  for (int r = 0; r < 4; ++r)
#pragma unroll
    for (int c = 0; c < 2; ++c)
#pragma unroll
      for (int i = 0; i < 4; ++i) {
        int row = 16 * r + (lane >> 4) * 4 + i;
        int col = (2 * wg + c) * 16 + lrow;
        Abf[row * A_STR + col] = f2bf(fmaxf(acc2[r][c][i], 0.0f));
      }
  __syncthreads();
  float* outp = l2_pts + (size_t)q * 256;
#pragma unroll
  for (int h = 0; h < 2; ++h) {
    int tn0 = 4 * wg + 2 * h;
    bf16x8 B3[2][4];
#pragma unroll
    for (int c = 0; c < 2; ++c)
#pragma unroll
      for (int kt = 0; kt < 4; ++kt)
        B3[c][kt] = *(const bf16x8*)&P3[(((tn0 + c) * 4 + kt) * 512 + lane * 8)];
    f32x4 acc3[4][2];
    {
      float b0 = bf3[(tn0 + 0) * 16 + lrow];
      float b1v = bf3[(tn0 + 1) * 16 + lrow];
#pragma unroll
      for (int r = 0; r < 4; ++r) {
        acc3[r][0] = (f32x4){b0, b0, b0, b0};
        acc3[r][1] = (f32x4){b1v, b1v, b1v, b1v};
      }
    }
#pragma unroll
    for (int r = 0; r < 4; ++r) {
      bf16x8 a[4];
#pragma unroll
      for (int kt = 0; kt < 4; ++kt)
        a[kt] = *(const bf16x8*)&Abf[(16 * r + lrow) * A_STR + kt * 32 + lgrp];
#pragma unroll
      for (int kt = 0; kt < 4; ++kt) {
        acc3[r][0] = __builtin_amdgcn_mfma_f32_16x16x32_bf16(a[kt], B3[0][kt], acc3[r][0], 0, 0, 0);
        acc3[r][1] = __builtin_amdgcn_mfma_f32_16x16x32_bf16(a[kt], B3[1][kt], acc3[r][1], 0, 0, 0);
      }
    }
#pragma unroll
    for (int c = 0; c < 2; ++c) {
      float m = 0.0f;
#pragma unroll
      for (int r = 0; r < 4; ++r)
#pragma unroll
        for (int i = 0; i < 4; ++i) m = fmaxf(m, acc3[r][c][i]);
      m = fmaxf(m, __shfl_xor(m, 16, 64));
      m = fmaxf(m, __shfl_xor(m, 32, 64));
      if (lane < 16) outp[(tn0 + c) * 16 + lane] = m;
    }
  }
}

// ---------------- SA3 via bf16 MFMA ----------------
__global__ void concat3bf_kernel(const float* __restrict__ nx2,
                                 const float* __restrict__ l2_pts,
                                 short* __restrict__ F0bf) {
  int i = blockIdx.x * 256 + threadIdx.x;
  if (i >= 4096 * 288) return;
  int row = i / 288, k = i - row * 288;
  int b = row >> 7, s = row & 127;
  float v;
  if (k < 3) v = nx2[b * 384 + k * 128 + s];
  else if (k < 259) v = l2_pts[(size_t)row * 256 + (k - 3)];
  else v = 0.0f;
  F0bf[i] = f2bf(v);
}

template <int KT, int RT, int NTW, bool DOMAX>
__global__ __launch_bounds__(256) void g3_mfma_kernel(
    const short* __restrict__ Xbf, const short* __restrict__ BP,
    const float* __restrict__ bias, short* __restrict__ Ybf,
    float* __restrict__ outp) {
  constexpr int K = KT * 32;
  constexpr int ROWS = RT * 16;
  constexpr int AS = K + 8;
  constexpr int N = 4 * NTW * 16;
  __shared__ short Abf[ROWS * AS];
  int t = threadIdx.x, lane = t & 63, wg = t >> 6;
  int row0 = blockIdx.x * ROWS;
  {
    constexpr int TPR = 256 / ROWS;
    constexpr int CPT = K / TPR;
    int row = t & (ROWS - 1);
    int chunk = t / ROWS;
    const short* src = Xbf + (size_t)(row0 + row) * K + chunk * CPT;
    short* dstp = Abf + row * AS + chunk * CPT;
#pragma unroll
    for (int i = 0; i < CPT / 4; ++i)
      *(uint2*)&dstp[i * 4] = *(const uint2*)&src[i * 4];
  }
  __syncthreads();
  int lrow = lane & 15, lgrp = (lane >> 4) * 8;
  bf16x8 a[RT][KT];
#pragma unroll
  for (int r = 0; r < RT; ++r)
#pragma unroll
    for (int kt = 0; kt < KT; ++kt)
      a[r][kt] = *(const bf16x8*)&Abf[(16 * r + lrow) * AS + kt * 32 + lgrp];
  for (int h = 0; h < NTW; ++h) {
    int nt = wg * NTW + h;
    f32x4 acc[RT];
    float bb = bias[nt * 16 + lrow];
#pragma unroll
    for (int r = 0; r < RT; ++r) acc[r] = (f32x4){bb, bb, bb, bb};
#pragma unroll
    for (int kt = 0; kt < KT; ++kt) {
      bf16x8 Bf = *(const bf16x8*)&BP[((size_t)nt * KT + kt) * 512 + lane * 8];
#pragma unroll
      for (int r = 0; r < RT; ++r)
        acc[r] = __builtin_amdgcn_mfma_f32_16x16x32_bf16(a[r][kt], Bf, acc[r], 0, 0, 0);
    }
    if (!DOMAX) {
#pragma unroll
      for (int r = 0; r < RT; ++r)
#pragma unroll
        for (int i = 0; i < 4; ++i) {
          int row = 16 * r + (lane >> 4) * 4 + i;
          Ybf[(size_t)(row0 + row) * N + nt * 16 + lrow] = f2bf(fmaxf(acc[r][i], 0.0f));
        }
    } else {
      float m = 0.0f;
#pragma unroll
      for (int r = 0; r < RT; ++r)
#pragma unroll
        for (int i = 0; i < 4; ++i) m = fmaxf(m, acc[r][i]);
      m = fmaxf(m, __shfl_xor(m, 16, 64));
      m = fmaxf(m, __shfl_xor(m, 32, 64));
      if (lane < 16) {
        int b = row0 >> 7;
        atomicMax((unsigned*)&outp[(size_t)b * 1024 + nt * 16 + lrow],
                  __float_as_uint(m));
      }
    }
  }
}

// ---------------- launch ----------------
extern "C" void kernel_launch(void* const* d_in, const int* in_sizes, int n_in,
                              void* d_out, int out_size, void* d_ws, size_t ws_size,
                              hipStream_t stream) {
  (void)in_sizes; (void)n_in; (void)out_size; (void)ws_size;
  const float* xyz = (const float*)d_in[0];
  auto WP = [&](int layer, int part) -> const float* {
    return (const float*)d_in[1 + layer * 4 + part];
  };
  float* wsf = (float*)d_ws;
  size_t cur = 0;
  auto alloc = [&](size_t n) { size_t o = cur; cur += (n + 63) & ~(size_t)63; return o; };
  size_t o_nx1 = alloc((size_t)kB * 3 * kS1);
  size_t o_nx2 = alloc((size_t)kB * 3 * kS2);
  size_t o_l1pts = alloc((size_t)kB * kS1 * 128);
  size_t o_l2pts = alloc((size_t)kB * kS2 * 256);
  size_t o_s1w0 = alloc(64 * 4), o_s1b0 = alloc(64);
  size_t o_s1w1 = alloc(64 * 64), o_s1b1 = alloc(64);
  size_t o_s1wt2 = alloc(64 * 128), o_s1b2 = alloc(128);
  size_t o_s2w1 = alloc(132 * 128), o_s2b1 = alloc(128);
  size_t o_s2wt2 = alloc(128 * 128), o_s2b2 = alloc(128);
  size_t o_s2w3 = alloc(128 * 256), o_s2b3 = alloc(256);
  size_t o_s3wtA = alloc(260 * 256), o_s3bA = alloc(256);
  size_t o_s3wtB = alloc(256 * 512), o_s3bB = alloc(512);
  size_t o_s3wtC = alloc(512 * 1024), o_s3bC = alloc(1024);
  size_t o_gidx1 = alloc((size_t)kB * kS1 * kNS1);
  size_t o_gidx2 = alloc((size_t)kB * kS2 * kNS2);
  size_t o_p1 = alloc(10240);
  size_t o_p2 = alloc(8192);
  size_t o_p3 = alloc(16384);
  size_t o_q1 = alloc(2048);
  size_t o_q2 = alloc(4096);
  size_t o_ra = alloc(36864);     // 256*288 shorts
  size_t o_rb = alloc(65536);     // 512*256 shorts
  size_t o_rc = alloc(262144);    // 1024*512 shorts
  size_t o_f0bf = alloc(589824);  // 4096*288 shorts
  size_t o_y1bf = alloc(524288);  // 4096*256 shorts
  size_t o_y2bf = alloc(1048576); // 4096*512 shorts
  int* gidx1 = (int*)(wsf + o_gidx1);
  int* gidx2 = (int*)(wsf + o_gidx2);
  short* P1 = (short*)(wsf + o_p1);
  short* P2 = (short*)(wsf + o_p2);
  short* P3 = (short*)(wsf + o_p3);
  short* Q1 = (short*)(wsf + o_q1);
  short* Q2 = (short*)(wsf + o_q2);
  short* RA = (short*)(wsf + o_ra);
  short* RB = (short*)(wsf + o_rb);
  short* RC = (short*)(wsf + o_rc);
  short* F0bf = (short*)(wsf + o_f0bf);
  short* Y1bf = (short*)(wsf + o_y1bf);
  short* Y2bf = (short*)(wsf + o_y2bf);

  // fused fold of all 9 layers
  FoldPack fp;
  const int OKKp[9][3] = {{64, 3, 4},     {64, 64, 64},   {128, 64, 64},
                          {128, 131, 132}, {128, 128, 128}, {256, 128, 128},
                          {256, 259, 260}, {512, 256, 256}, {1024, 512, 512}};
  float* wouts[9] = {wsf + o_s1w0, wsf + o_s1w1, wsf + o_s1wt2,
                     wsf + o_s2w1, wsf + o_s2wt2, wsf + o_s2w3,
                     wsf + o_s3wtA, wsf + o_s3wtB, wsf + o_s3wtC};
  float* bouts[9] = {wsf + o_s1b0, wsf + o_s1b1, wsf + o_s1b2,
                     wsf + o_s2b1, wsf + o_s2b2, wsf + o_s2b3,
                     wsf + o_s3bA, wsf + o_s3bB, wsf + o_s3bC};
  const int nblk[9] = {1, 4, 8, 17, 16, 32, 65, 128, 512};
  fp.cum[0] = 0;
  for (int L = 0; L < 9; ++L) {
    fp.d[L].W = WP(L, 0);
    fp.d[L].b = WP(L, 1);
    fp.d[L].g = WP(L, 2);
    fp.d[L].bt = WP(L, 3);
    fp.d[L].Wout = wouts[L];
    fp.d[L].bout = bouts[L];
    fp.d[L].O = OKKp[L][0];
    fp.d[L].K = OKKp[L][1];
    fp.d[L].Kp = OKKp[L][2];
    fp.d[L].transposed = (L == 0) ? 0 : 1;
    fp.cum[L + 1] = fp.cum[L] + nblk[L];
  }
  foldall_kernel<<<fp.cum[9], 256, 0, stream>>>(fp);

  // fused pack of all MFMA weight buffers
  PackPack pp;
  const float* psrc[8] = {wsf + o_s1w1, wsf + o_s1wt2, wsf + o_s2w1, wsf + o_s2wt2,
                          wsf + o_s2w3, wsf + o_s3wtA, wsf + o_s3wtB, wsf + o_s3wtC};
  short* pdst[8] = {Q1, Q2, P1, P2, P3, RA, RB, RC};
  const int pO[8] = {64, 128, 128, 128, 256, 256, 512, 1024};
  const int pKp[8] = {64, 64, 160, 128, 128, 288, 256, 512};
  const int pMode[8] = {0, 0, 1, 0, 0, 0, 0, 0};
  const int pKr[8] = {64, 64, 0, 128, 128, 260, 256, 512};
  pp.cum[0] = 0;
  for (int L = 0; L < 8; ++L) {
    pp.j[L].W = psrc[L];
    pp.j[L].dst = pdst[L];
    pp.j[L].O = pO[L];
    pp.j[L].Kpad = pKp[L];
    pp.j[L].mode = pMode[L];
    pp.j[L].Kreal = pKr[L];
    pp.cum[L + 1] = pp.cum[L] + (pO[L] * pKp[L] + 255) / 256;
  }
  packall_kernel<<<pp.cum[8], 256, 0, stream>>>(pp);

  // SA1
  fps16_kernel<kN1, kS1, 256><<<kB, 256, 0, stream>>>(xyz, wsf + o_nx1);
  bq_kernel<kN1, kS1, kNS1><<<(kB * kS1) / 4, 256, 0, stream>>>(xyz, wsf + o_nx1, 0.04f, gidx1);
  sa1_mfma_kernel<<<(kB * kS1) / 2, 256, 0, stream>>>(
      xyz, wsf + o_nx1, gidx1,
      wsf + o_s1w0, wsf + o_s1b0, Q1, wsf + o_s1b1, Q2, wsf + o_s1b2,
      wsf + o_l1pts);

  // SA2
  fps4_kernel<kS1, kS2, 128><<<kB, 128, 0, stream>>>(wsf + o_nx1, wsf + o_nx2);
  bq_kernel<kS1, kS2, kNS2><<<(kB * kS2) / 4, 256, 0, stream>>>(wsf + o_nx1, wsf + o_nx2, 0.16f, gidx2);
  sa2_mfma_kernel<<<kB * kS2, 256, 0, stream>>>(
      wsf + o_nx1, wsf + o_l1pts, wsf + o_nx2, gidx2,
      P1, wsf + o_s2b1, P2, wsf + o_s2b2, P3, wsf + o_s2b3,
      wsf + o_l2pts);

  // SA3 (group all) via MFMA
  concat3bf_kernel<<<4608, 256, 0, stream>>>(wsf + o_nx2, wsf + o_l2pts, F0bf);
  g3_mfma_kernel<9, 4, 4, false><<<64, 256, 0, stream>>>(
      F0bf, RA, wsf + o_s3bA, Y1bf, (float*)nullptr);
  g3_mfma_kernel<8, 4, 8, false><<<64, 256, 0, stream>>>(
      Y1bf, RB, wsf + o_s3bB, Y2bf, (float*)nullptr);
  hipMemsetAsync(d_out, 0, (size_t)kB * 1024 * sizeof(float), stream);
  g3_mfma_kernel<16, 2, 16, true><<<128, 256, 0, stream>>>(
      Y2bf, RC, wsf + o_s3bC, (short*)nullptr, (float*)d_out);
}